// Round 3
// baseline (938.184 us; speedup 1.0000x reference)
//
#include <hip/hip_runtime.h>
#include <hip/hip_bf16.h>
#include <math.h>

#define N_LIGC 1024
#define NTOT 9216
#define KNN 48
#define HID 256
#define DEPTHC 5
#define ETOT (N_LIGC*KNN)

typedef unsigned short u16;
typedef __attribute__((ext_vector_type(8))) short bf16x8;
typedef __attribute__((ext_vector_type(4))) float f32x4;

__device__ __forceinline__ float freq_f(int i){
  double p = (double)(1 << (2*i));
  return (float)((2.0*3.14159265358979323846)*p/15.0);
}
__device__ __forceinline__ float silu_f(float v){ return v/(1.0f+expf(-v)); }
__device__ __forceinline__ u16 f2b(float f){
  union { __hip_bfloat16 h; u16 u; } c; c.h = __float2bfloat16(f); return c.u;
}
__device__ __forceinline__ float b2f(u16 u){
  union { unsigned int i; float f; } c; c.i = ((unsigned int)u)<<16; return c.f;
}

// ---------------- pack fp32 weight [L][K][N] -> bf16 B-frag layout [L][K0][N0][lane][8]
__global__ __launch_bounds__(256) void k_convw(const float* __restrict__ src,
    u16* __restrict__ dst, int K, int Kp, int N, int total)
{
  int idx = blockIdx.x*256 + threadIdx.x;
  if (idx >= total) return;
  int lane = idx & 63;
  int rest = idx >> 6;
  int Nt = N >> 4;
  int n0 = rest % Nt;
  int rest2 = rest / Nt;
  int Kt = Kp >> 5;
  int k0 = rest2 % Kt;
  int layer = rest2 / Kt;
  int kq = lane >> 4, nl = lane & 15;
  int kb = k0*32 + kq*8, n = n0*16 + nl;
  u16 o[8];
  #pragma unroll
  for (int j=0;j<8;j++){
    int k = kb + j;
    float v = (k < K) ? src[((size_t)layer*K + k)*N + n] : 0.f;
    o[j] = f2b(v);
  }
  *(uint4*)(dst + (size_t)idx*8) = *(uint4*)o;
}

// ---------------- feature embedding + coords ----------------
__global__ __launch_bounds__(256) void k_embed(
    const float* __restrict__ protPos, const int* __restrict__ protEle,
    const int* __restrict__ protAA, const int* __restrict__ protBB,
    const float* __restrict__ XtPos, const float* __restrict__ XtFeat,
    const int* __restrict__ tArr, const float* __restrict__ WtTime,
    const float* __restrict__ Wele, const float* __restrict__ Waa,
    const float* __restrict__ Wbb,
    float* __restrict__ feats, float* __restrict__ X0, float* __restrict__ X1)
{
  int i = blockIdx.x*256+threadIdx.x;
  if (i >= NTOT) return;
  float c0,c1,c2;
  float* f = feats + i*40;
  if (i < N_LIGC){
    c0 = XtPos[i*3+0]; c1 = XtPos[i*3+1]; c2 = XtPos[i*3+2];
    #pragma unroll
    for (int k=0;k<32;k++) f[k] = XtFeat[i*32+k];
    int tt = tArr[i];
    #pragma unroll
    for (int k=0;k<8;k++) f[32+k] = WtTime[tt*8+k];
  } else {
    int p = i - N_LIGC;
    c0 = protPos[p*3+0]; c1 = protPos[p*3+1]; c2 = protPos[p*3+2];
    int e = protEle[p], a = protAA[p], b = protBB[p];
    #pragma unroll
    for (int k=0;k<16;k++) f[k] = Wele[e*16+k];
    #pragma unroll
    for (int k=0;k<16;k++) f[16+k] = Waa[a*16+k];
    #pragma unroll
    for (int k=0;k<8;k++) f[32+k] = Wbb[b*8+k];
  }
  X0[i*3+0]=c0; X0[i*3+1]=c1; X0[i*3+2]=c2;
  X1[i*3+0]=c0; X1[i*3+1]=c1; X1[i*3+2]=c2;
}

// ---------------- h = feats @ W_in + b_in (fp32 + bf16 shadow) ----------------
__global__ __launch_bounds__(256) void k_hinit(const float* __restrict__ feats,
    const float* __restrict__ Win, const float* __restrict__ bin,
    float* __restrict__ h, u16* __restrict__ h_bf)
{
  __shared__ float sF[8*40];
  int blk=blockIdx.x, tid=threadIdx.x;
  int n0=blk*8;
  for (int x=tid;x<320;x+=256) sF[x]=feats[n0*40+x];
  __syncthreads();
  float acc[8];
  float b=bin[tid];
  #pragma unroll
  for (int n=0;n<8;n++) acc[n]=b;
  for (int k=0;k<40;k++){
    float w=Win[k*HID+tid];
    #pragma unroll
    for (int n=0;n<8;n++) acc[n]+=sF[n*40+k]*w;
  }
  #pragma unroll
  for (int n=0;n<8;n++){
    h[(size_t)(n0+n)*HID+tid]=acc[n];
    h_bf[(size_t)(n0+n)*HID+tid]=f2b(acc[n]);
  }
}

// ---------------- KNN: hierarchical argmin (per-thread cached local min) ----------------
__global__ __launch_bounds__(256) void k_knn(const float* __restrict__ X,
    int* __restrict__ col, float* __restrict__ emb0)
{
  __shared__ float sd[NTOT];
  __shared__ float lmv[256];
  __shared__ int   lmi[256];
  __shared__ float selD[KNN];
  __shared__ int   sWin;
  int b = blockIdx.x, tid = threadIdx.x;
  float px = X[b*3+0], py = X[b*3+1], pz = X[b*3+2];
  float bv = INFINITY; int bi = 0x7fffffff;
  #pragma unroll 4
  for (int j=0;j<36;j++){
    int i = tid + 256*j;
    float dx = px - X[i*3+0], dy = py - X[i*3+1], dz = pz - X[i*3+2];
    float d2 = dx*dx+dy*dy+dz*dz;
    if (i==b) d2 = INFINITY;
    sd[i] = d2;
    if (d2 < bv){ bv=d2; bi=i; }   // strided ascending i: strict < keeps lowest idx
  }
  lmv[tid]=bv; lmi[tid]=bi;
  __syncthreads();
  for (int it=0; it<KNN; it++){
    if (tid < 64){
      float v = INFINITY; int idx = 0x7fffffff;
      #pragma unroll
      for (int s=0;s<4;s++){
        float vv = lmv[tid+64*s]; int ii = lmi[tid+64*s];
        if (vv < v || (vv==v && ii<idx)){ v=vv; idx=ii; }
      }
      #pragma unroll
      for (int off=32; off>=1; off>>=1){
        float ov = __shfl_down(v, off);
        int   oi = __shfl_down(idx, off);
        if (ov < v || (ov==v && oi<idx)){ v=ov; idx=oi; }
      }
      if (tid==0){
        sWin = idx;
        col[b*KNN+it] = idx;
        selD[it] = v;
        sd[idx] = INFINITY;
      }
    }
    __syncthreads();
    int wi = sWin;
    if (tid == (wi & 255)){
      float v = INFINITY; int idx = 0x7fffffff;
      #pragma unroll 4
      for (int j=0;j<36;j++){
        int i = tid + 256*j;
        float vv = sd[i];
        if (vv < v){ v=vv; idx=i; }
      }
      lmv[tid]=v; lmi[tid]=idx;
    }
    __syncthreads();
  }
  if (tid < KNN){
    float d = sqrtf(selD[tid] + 1e-8f);
    int base = (b*KNN+tid)*12;
    #pragma unroll
    for (int i=0;i<6;i++){
      float fr = freq_f(i);
      emb0[base+i]   = sinf(d*fr);
      emb0[base+6+i] = cosf(d*fr);
    }
  }
}

// ---------------- edge MLP (MFMA): 2 rows/block, M=96, 512 threads ----------------
__global__ __launch_bounds__(512) void k_edge(
    const u16* __restrict__ h_bf, const float* __restrict__ xc,
    const int* __restrict__ colIdx, const float* __restrict__ emb0,
    const u16* __restrict__ W1p, const float* __restrict__ B1,
    const u16* __restrict__ W2p, const float* __restrict__ B2,
    const float* __restrict__ attW, const float* __restrict__ attB,
    u16* __restrict__ agg_bf, int l)
{
  __shared__ __align__(16) u16 sBuf[96*552];      // 105984 B
  u16* sA  = sBuf;                                 // 96 x 552 (stage-1 input)
  u16* sM1 = sBuf;                                 // 96 x 264 bf16 (alias after stage1)
  u16* sM2 = sBuf + 96*264;                        // 96 x 264 bf16
  __shared__ int sCol[96];
  __shared__ float sSig[96];
  __shared__ float sDot[96][4];

  int blk = blockIdx.x, tid = threadIdx.x;
  int lane = tid & 63, wv = tid >> 6;
  int quad = lane >> 4, nl = lane & 15;
  int mh = wv & 1, ng = wv >> 1;                   // m-half (48 rows), n-slice (64 cols)
  int r0 = blk*2;

  if (tid < 96) sCol[tid] = colIdx[(size_t)r0*KNN + tid];
  __syncthreads();
  for (int t = tid; t < 96*64; t += 512) {
    int e = t >> 6, q = t & 63;
    int row = r0 + (e >= 48);
    uint4 v;
    if (q < 32) v = ((const uint4*)(h_bf + (size_t)row*HID))[q];
    else        v = ((const uint4*)(h_bf + (size_t)sCol[e]*HID))[q-32];
    *(uint4*)(sA + e*552 + q*8) = v;
  }
  if (tid < 96) {
    int row = r0 + (tid >= 48);
    int cg = sCol[tid];
    float dx = xc[row*3+0]-xc[cg*3+0];
    float dy = xc[row*3+1]-xc[cg*3+1];
    float dz = xc[row*3+2]-xc[cg*3+2];
    float d = sqrtf(dx*dx+dy*dy+dz*dz + 1e-8f);
    u16* ea = sA + tid*552 + 512;
    #pragma unroll
    for (int i=0;i<6;i++){
      float fr = freq_f(i);
      ea[i]   = f2b(sinf(d*fr));
      ea[6+i] = f2b(cosf(d*fr));
    }
    #pragma unroll
    for (int i=0;i<12;i++) ea[12+i] = f2b(emb0[((size_t)r0*KNN + tid)*12 + i]);
    #pragma unroll
    for (int i=24;i<32;i++) ea[i] = 0;
  }
  __syncthreads();

  f32x4 zero4 = {0.f,0.f,0.f,0.f};
  f32x4 acc[3][4];
  #pragma unroll
  for (int i=0;i<3;i++){ acc[i][0]=zero4; acc[i][1]=zero4; acc[i][2]=zero4; acc[i][3]=zero4; }
  const u16* Wp = W1p + (size_t)l*544*HID;
  // register double-buffer for B-fragments
  const u16* wb0 = Wp + ((size_t)(ng*4)*64 + lane)*8;
  bf16x8 b0 = *(const bf16x8*)(wb0);
  bf16x8 b1 = *(const bf16x8*)(wb0 + 512);
  bf16x8 b2 = *(const bf16x8*)(wb0 + 1024);
  bf16x8 b3 = *(const bf16x8*)(wb0 + 1536);
  #pragma unroll 1
  for (int k0=0;k0<17;k0++){
    bf16x8 c0=b0, c1=b1, c2=b2, c3=b3;
    if (k0 < 16){
      const u16* wn = Wp + ((size_t)((k0+1)*16 + ng*4)*64 + lane)*8;
      b0 = *(const bf16x8*)(wn);
      b1 = *(const bf16x8*)(wn + 512);
      b2 = *(const bf16x8*)(wn + 1024);
      b3 = *(const bf16x8*)(wn + 1536);
    }
    bf16x8 a0 = *(const bf16x8*)(sA + (mh*48 + 0*16 + nl)*552 + k0*32 + quad*8);
    bf16x8 a1 = *(const bf16x8*)(sA + (mh*48 + 1*16 + nl)*552 + k0*32 + quad*8);
    bf16x8 a2 = *(const bf16x8*)(sA + (mh*48 + 2*16 + nl)*552 + k0*32 + quad*8);
    acc[0][0]=__builtin_amdgcn_mfma_f32_16x16x32_bf16(a0,c0,acc[0][0],0,0,0);
    acc[0][1]=__builtin_amdgcn_mfma_f32_16x16x32_bf16(a0,c1,acc[0][1],0,0,0);
    acc[0][2]=__builtin_amdgcn_mfma_f32_16x16x32_bf16(a0,c2,acc[0][2],0,0,0);
    acc[0][3]=__builtin_amdgcn_mfma_f32_16x16x32_bf16(a0,c3,acc[0][3],0,0,0);
    acc[1][0]=__builtin_amdgcn_mfma_f32_16x16x32_bf16(a1,c0,acc[1][0],0,0,0);
    acc[1][1]=__builtin_amdgcn_mfma_f32_16x16x32_bf16(a1,c1,acc[1][1],0,0,0);
    acc[1][2]=__builtin_amdgcn_mfma_f32_16x16x32_bf16(a1,c2,acc[1][2],0,0,0);
    acc[1][3]=__builtin_amdgcn_mfma_f32_16x16x32_bf16(a1,c3,acc[1][3],0,0,0);
    acc[2][0]=__builtin_amdgcn_mfma_f32_16x16x32_bf16(a2,c0,acc[2][0],0,0,0);
    acc[2][1]=__builtin_amdgcn_mfma_f32_16x16x32_bf16(a2,c1,acc[2][1],0,0,0);
    acc[2][2]=__builtin_amdgcn_mfma_f32_16x16x32_bf16(a2,c2,acc[2][2],0,0,0);
    acc[2][3]=__builtin_amdgcn_mfma_f32_16x16x32_bf16(a2,c3,acc[2][3],0,0,0);
  }
  __syncthreads();   // all stage-1 sA reads done before sM1 (alias) writes
  #pragma unroll
  for (int mt=0;mt<3;mt++)
  #pragma unroll
  for (int nt=0;nt<4;nt++){
    int n = ng*64 + nt*16 + nl;
    float bb = B1[l*HID + n];
    #pragma unroll
    for (int r=0;r<4;r++){
      int m = mh*48 + mt*16 + quad*4 + r;
      sM1[m*264 + n] = f2b(silu_f(acc[mt][nt][r] + bb));
    }
  }
  __syncthreads();

  f32x4 acc2[3][4];
  #pragma unroll
  for (int i=0;i<3;i++){ acc2[i][0]=zero4; acc2[i][1]=zero4; acc2[i][2]=zero4; acc2[i][3]=zero4; }
  const u16* W2 = W2p + (size_t)l*HID*HID;
  const u16* vb0 = W2 + ((size_t)(ng*4)*64 + lane)*8;
  b0 = *(const bf16x8*)(vb0);
  b1 = *(const bf16x8*)(vb0 + 512);
  b2 = *(const bf16x8*)(vb0 + 1024);
  b3 = *(const bf16x8*)(vb0 + 1536);
  #pragma unroll 1
  for (int k0=0;k0<8;k0++){
    bf16x8 c0=b0, c1=b1, c2=b2, c3=b3;
    if (k0 < 7){
      const u16* wn = W2 + ((size_t)((k0+1)*16 + ng*4)*64 + lane)*8;
      b0 = *(const bf16x8*)(wn);
      b1 = *(const bf16x8*)(wn + 512);
      b2 = *(const bf16x8*)(wn + 1024);
      b3 = *(const bf16x8*)(wn + 1536);
    }
    bf16x8 a0 = *(const bf16x8*)(sM1 + (mh*48 + 0*16 + nl)*264 + k0*32 + quad*8);
    bf16x8 a1 = *(const bf16x8*)(sM1 + (mh*48 + 1*16 + nl)*264 + k0*32 + quad*8);
    bf16x8 a2 = *(const bf16x8*)(sM1 + (mh*48 + 2*16 + nl)*264 + k0*32 + quad*8);
    acc2[0][0]=__builtin_amdgcn_mfma_f32_16x16x32_bf16(a0,c0,acc2[0][0],0,0,0);
    acc2[0][1]=__builtin_amdgcn_mfma_f32_16x16x32_bf16(a0,c1,acc2[0][1],0,0,0);
    acc2[0][2]=__builtin_amdgcn_mfma_f32_16x16x32_bf16(a0,c2,acc2[0][2],0,0,0);
    acc2[0][3]=__builtin_amdgcn_mfma_f32_16x16x32_bf16(a0,c3,acc2[0][3],0,0,0);
    acc2[1][0]=__builtin_amdgcn_mfma_f32_16x16x32_bf16(a1,c0,acc2[1][0],0,0,0);
    acc2[1][1]=__builtin_amdgcn_mfma_f32_16x16x32_bf16(a1,c1,acc2[1][1],0,0,0);
    acc2[1][2]=__builtin_amdgcn_mfma_f32_16x16x32_bf16(a1,c2,acc2[1][2],0,0,0);
    acc2[1][3]=__builtin_amdgcn_mfma_f32_16x16x32_bf16(a1,c3,acc2[1][3],0,0,0);
    acc2[2][0]=__builtin_amdgcn_mfma_f32_16x16x32_bf16(a2,c0,acc2[2][0],0,0,0);
    acc2[2][1]=__builtin_amdgcn_mfma_f32_16x16x32_bf16(a2,c1,acc2[2][1],0,0,0);
    acc2[2][2]=__builtin_amdgcn_mfma_f32_16x16x32_bf16(a2,c2,acc2[2][2],0,0,0);
    acc2[2][3]=__builtin_amdgcn_mfma_f32_16x16x32_bf16(a2,c3,acc2[2][3],0,0,0);
  }
  // sM2 region (>=96*264) does not overlap sM1 (<96*264): no barrier needed here
  #pragma unroll
  for (int mt=0;mt<3;mt++)
  #pragma unroll
  for (int nt=0;nt<4;nt++){
    int n = ng*64 + nt*16 + nl;
    float bb = B2[l*HID + n];
    #pragma unroll
    for (int r=0;r<4;r++){
      int m = mh*48 + mt*16 + quad*4 + r;
      sM2[m*264 + n] = f2b(silu_f(acc2[mt][nt][r] + bb));
    }
  }
  __syncthreads();
  if (tid < 384){
    int e = tid >> 2, qq = tid & 3;
    float s = 0.f; int nb = qq*64;
    #pragma unroll 4
    for (int n=0;n<64;n++) s += b2f(sM2[e*264 + nb + n])*attW[l*HID + nb + n];
    sDot[e][qq] = s;
  }
  __syncthreads();
  if (tid < 96){
    float s = sDot[tid][0]+sDot[tid][1]+sDot[tid][2]+sDot[tid][3] + attB[l];
    sSig[tid] = 1.f/(1.f+expf(-s));
  }
  __syncthreads();
  {
    int rr = tid >> 8, n = tid & 255;
    float a = 0.f;
    int eb = rr*48;
    #pragma unroll 4
    for (int e=0;e<48;e++) a += b2f(sM2[(eb+e)*264 + n])*sSig[eb+e];
    agg_bf[(size_t)(r0+rr)*HID + n] = f2b(a/5.0f);
  }
}

// ---------------- node MLP (MFMA, residual): 32 nodes/block ----------------
__global__ __launch_bounds__(256) void k_node(
    float* __restrict__ h, u16* __restrict__ h_bf,
    const u16* __restrict__ agg_bf,
    const u16* __restrict__ W1p, const float* __restrict__ B1,
    const u16* __restrict__ W2p, const float* __restrict__ B2, int l)
{
  __shared__ __align__(16) u16 sA[32*520];
  __shared__ __align__(16) u16 sU[32*264];
  int blk=blockIdx.x, tid=threadIdx.x;
  int lane=tid&63, wv=tid>>6, quad=lane>>4, nl=lane&15;
  for (int t=tid; t<32*64; t+=256){
    int i=t>>6, q=t&63;
    int node = blk*32+i;
    uint4 v;
    if (q<32) v = ((const uint4*)(h_bf + (size_t)node*HID))[q];
    else if (node < N_LIGC) v = ((const uint4*)(agg_bf + (size_t)node*HID))[q-32];
    else { v.x=0u; v.y=0u; v.z=0u; v.w=0u; }
    *(uint4*)(sA + i*520 + q*8) = v;
  }
  __syncthreads();
  f32x4 zero4 = {0.f,0.f,0.f,0.f};
  f32x4 acc[2][4];
  #pragma unroll
  for (int i=0;i<2;i++){ acc[i][0]=zero4; acc[i][1]=zero4; acc[i][2]=zero4; acc[i][3]=zero4; }
  const u16* Wp = W1p + (size_t)l*512*HID;
  #pragma unroll 2
  for (int k0=0;k0<16;k0++){
    bf16x8 a0 = *(const bf16x8*)(sA + (0*16+nl)*520 + k0*32 + quad*8);
    bf16x8 a1 = *(const bf16x8*)(sA + (1*16+nl)*520 + k0*32 + quad*8);
    const u16* wb = Wp + ((size_t)(k0*16 + wv*4)*64 + lane)*8;
    bf16x8 b0 = *(const bf16x8*)(wb);
    bf16x8 b1 = *(const bf16x8*)(wb + 512);
    bf16x8 b2 = *(const bf16x8*)(wb + 1024);
    bf16x8 b3 = *(const bf16x8*)(wb + 1536);
    acc[0][0]=__builtin_amdgcn_mfma_f32_16x16x32_bf16(a0,b0,acc[0][0],0,0,0);
    acc[0][1]=__builtin_amdgcn_mfma_f32_16x16x32_bf16(a0,b1,acc[0][1],0,0,0);
    acc[0][2]=__builtin_amdgcn_mfma_f32_16x16x32_bf16(a0,b2,acc[0][2],0,0,0);
    acc[0][3]=__builtin_amdgcn_mfma_f32_16x16x32_bf16(a0,b3,acc[0][3],0,0,0);
    acc[1][0]=__builtin_amdgcn_mfma_f32_16x16x32_bf16(a1,b0,acc[1][0],0,0,0);
    acc[1][1]=__builtin_amdgcn_mfma_f32_16x16x32_bf16(a1,b1,acc[1][1],0,0,0);
    acc[1][2]=__builtin_amdgcn_mfma_f32_16x16x32_bf16(a1,b2,acc[1][2],0,0,0);
    acc[1][3]=__builtin_amdgcn_mfma_f32_16x16x32_bf16(a1,b3,acc[1][3],0,0,0);
  }
  #pragma unroll
  for (int mt=0;mt<2;mt++)
  #pragma unroll
  for (int nt=0;nt<4;nt++){
    int n = wv*64 + nt*16 + nl;
    float bb = B1[l*HID + n];
    #pragma unroll
    for (int r=0;r<4;r++){
      int m = mt*16 + quad*4 + r;
      sU[m*264 + n] = f2b(silu_f(acc[mt][nt][r] + bb));
    }
  }
  __syncthreads();
  f32x4 acc2[2][4];
  #pragma unroll
  for (int i=0;i<2;i++){ acc2[i][0]=zero4; acc2[i][1]=zero4; acc2[i][2]=zero4; acc2[i][3]=zero4; }
  const u16* W2 = W2p + (size_t)l*HID*HID;
  #pragma unroll 2
  for (int k0=0;k0<8;k0++){
    bf16x8 a0 = *(const bf16x8*)(sU + (0*16+nl)*264 + k0*32 + quad*8);
    bf16x8 a1 = *(const bf16x8*)(sU + (1*16+nl)*264 + k0*32 + quad*8);
    const u16* wb = W2 + ((size_t)(k0*16 + wv*4)*64 + lane)*8;
    bf16x8 b0 = *(const bf16x8*)(wb);
    bf16x8 b1 = *(const bf16x8*)(wb + 512);
    bf16x8 b2 = *(const bf16x8*)(wb + 1024);
    bf16x8 b3 = *(const bf16x8*)(wb + 1536);
    acc2[0][0]=__builtin_amdgcn_mfma_f32_16x16x32_bf16(a0,b0,acc2[0][0],0,0,0);
    acc2[0][1]=__builtin_amdgcn_mfma_f32_16x16x32_bf16(a0,b1,acc2[0][1],0,0,0);
    acc2[0][2]=__builtin_amdgcn_mfma_f32_16x16x32_bf16(a0,b2,acc2[0][2],0,0,0);
    acc2[0][3]=__builtin_amdgcn_mfma_f32_16x16x32_bf16(a0,b3,acc2[0][3],0,0,0);
    acc2[1][0]=__builtin_amdgcn_mfma_f32_16x16x32_bf16(a1,b0,acc2[1][0],0,0,0);
    acc2[1][1]=__builtin_amdgcn_mfma_f32_16x16x32_bf16(a1,b1,acc2[1][1],0,0,0);
    acc2[1][2]=__builtin_amdgcn_mfma_f32_16x16x32_bf16(a1,b2,acc2[1][2],0,0,0);
    acc2[1][3]=__builtin_amdgcn_mfma_f32_16x16x32_bf16(a1,b3,acc2[1][3],0,0,0);
  }
  #pragma unroll
  for (int mt=0;mt<2;mt++)
  #pragma unroll
  for (int nt=0;nt<4;nt++){
    int n = wv*64 + nt*16 + nl;
    float bb = B2[l*HID + n];
    #pragma unroll
    for (int r=0;r<4;r++){
      int m = mt*16 + quad*4 + r;
      size_t idx = (size_t)(blk*32+m)*HID + n;
      float v = h[idx] + acc2[mt][nt][r] + bb;
      h[idx] = v;
      h_bf[idx] = f2b(v);
    }
  }
}

// ---------------- coord MLP (MFMA, updated h): 2 rows/block, M=96, 512 threads ----------------
__global__ __launch_bounds__(512) void k_coord(
    const u16* __restrict__ h_bf, const float* __restrict__ xc,
    float* __restrict__ xn,
    const int* __restrict__ colIdx, const float* __restrict__ emb0,
    const u16* __restrict__ W1p, const float* __restrict__ B1,
    const u16* __restrict__ W2p, const float* __restrict__ B2,
    const float* __restrict__ cW3, int l)
{
  __shared__ __align__(16) u16 sBuf[96*552];
  u16* sA  = sBuf;
  u16* sM1 = sBuf;
  u16* sM2 = sBuf + 96*264;
  __shared__ int sCol[96];
  __shared__ float sCd[96*3];
  __shared__ float sS[96];
  __shared__ float sDot[96][4];

  int blk = blockIdx.x, tid = threadIdx.x;
  int lane = tid & 63, wv = tid >> 6;
  int quad = lane >> 4, nl = lane & 15;
  int mh = wv & 1, ng = wv >> 1;
  int r0 = blk*2;

  if (tid < 96) sCol[tid] = colIdx[(size_t)r0*KNN + tid];
  __syncthreads();
  for (int t = tid; t < 96*64; t += 512) {
    int e = t >> 6, q = t & 63;
    int row = r0 + (e >= 48);
    uint4 v;
    if (q < 32) v = ((const uint4*)(h_bf + (size_t)row*HID))[q];
    else        v = ((const uint4*)(h_bf + (size_t)sCol[e]*HID))[q-32];
    *(uint4*)(sA + e*552 + q*8) = v;
  }
  if (tid < 96) {
    int row = r0 + (tid >= 48);
    int cg = sCol[tid];
    float dx = xc[row*3+0]-xc[cg*3+0];
    float dy = xc[row*3+1]-xc[cg*3+1];
    float dz = xc[row*3+2]-xc[cg*3+2];
    float d = sqrtf(dx*dx+dy*dy+dz*dz + 1e-8f);
    float den = d + 1.0f;
    sCd[tid*3+0]=dx/den; sCd[tid*3+1]=dy/den; sCd[tid*3+2]=dz/den;
    u16* ea = sA + tid*552 + 512;
    #pragma unroll
    for (int i=0;i<6;i++){
      float fr = freq_f(i);
      ea[i]   = f2b(sinf(d*fr));
      ea[6+i] = f2b(cosf(d*fr));
    }
    #pragma unroll
    for (int i=0;i<12;i++) ea[12+i] = f2b(emb0[((size_t)r0*KNN + tid)*12 + i]);
    #pragma unroll
    for (int i=24;i<32;i++) ea[i] = 0;
  }
  __syncthreads();

  f32x4 zero4 = {0.f,0.f,0.f,0.f};
  f32x4 acc[3][4];
  #pragma unroll
  for (int i=0;i<3;i++){ acc[i][0]=zero4; acc[i][1]=zero4; acc[i][2]=zero4; acc[i][3]=zero4; }
  const u16* Wp = W1p + (size_t)l*544*HID;
  const u16* wb0 = Wp + ((size_t)(ng*4)*64 + lane)*8;
  bf16x8 b0 = *(const bf16x8*)(wb0);
  bf16x8 b1 = *(const bf16x8*)(wb0 + 512);
  bf16x8 b2 = *(const bf16x8*)(wb0 + 1024);
  bf16x8 b3 = *(const bf16x8*)(wb0 + 1536);
  #pragma unroll 1
  for (int k0=0;k0<17;k0++){
    bf16x8 c0=b0, c1=b1, c2=b2, c3=b3;
    if (k0 < 16){
      const u16* wn = Wp + ((size_t)((k0+1)*16 + ng*4)*64 + lane)*8;
      b0 = *(const bf16x8*)(wn);
      b1 = *(const bf16x8*)(wn + 512);
      b2 = *(const bf16x8*)(wn + 1024);
      b3 = *(const bf16x8*)(wn + 1536);
    }
    bf16x8 a0 = *(const bf16x8*)(sA + (mh*48 + 0*16 + nl)*552 + k0*32 + quad*8);
    bf16x8 a1 = *(const bf16x8*)(sA + (mh*48 + 1*16 + nl)*552 + k0*32 + quad*8);
    bf16x8 a2 = *(const bf16x8*)(sA + (mh*48 + 2*16 + nl)*552 + k0*32 + quad*8);
    acc[0][0]=__builtin_amdgcn_mfma_f32_16x16x32_bf16(a0,c0,acc[0][0],0,0,0);
    acc[0][1]=__builtin_amdgcn_mfma_f32_16x16x32_bf16(a0,c1,acc[0][1],0,0,0);
    acc[0][2]=__builtin_amdgcn_mfma_f32_16x16x32_bf16(a0,c2,acc[0][2],0,0,0);
    acc[0][3]=__builtin_amdgcn_mfma_f32_16x16x32_bf16(a0,c3,acc[0][3],0,0,0);
    acc[1][0]=__builtin_amdgcn_mfma_f32_16x16x32_bf16(a1,c0,acc[1][0],0,0,0);
    acc[1][1]=__builtin_amdgcn_mfma_f32_16x16x32_bf16(a1,c1,acc[1][1],0,0,0);
    acc[1][2]=__builtin_amdgcn_mfma_f32_16x16x32_bf16(a1,c2,acc[1][2],0,0,0);
    acc[1][3]=__builtin_amdgcn_mfma_f32_16x16x32_bf16(a1,c3,acc[1][3],0,0,0);
    acc[2][0]=__builtin_amdgcn_mfma_f32_16x16x32_bf16(a2,c0,acc[2][0],0,0,0);
    acc[2][1]=__builtin_amdgcn_mfma_f32_16x16x32_bf16(a2,c1,acc[2][1],0,0,0);
    acc[2][2]=__builtin_amdgcn_mfma_f32_16x16x32_bf16(a2,c2,acc[2][2],0,0,0);
    acc[2][3]=__builtin_amdgcn_mfma_f32_16x16x32_bf16(a2,c3,acc[2][3],0,0,0);
  }
  __syncthreads();
  #pragma unroll
  for (int mt=0;mt<3;mt++)
  #pragma unroll
  for (int nt=0;nt<4;nt++){
    int n = ng*64 + nt*16 + nl;
    float bb = B1[l*HID + n];
    #pragma unroll
    for (int r=0;r<4;r++){
      int m = mh*48 + mt*16 + quad*4 + r;
      sM1[m*264 + n] = f2b(silu_f(acc[mt][nt][r] + bb));
    }
  }
  __syncthreads();

  f32x4 acc2[3][4];
  #pragma unroll
  for (int i=0;i<3;i++){ acc2[i][0]=zero4; acc2[i][1]=zero4; acc2[i][2]=zero4; acc2[i][3]=zero4; }
  const u16* W2 = W2p + (size_t)l*HID*HID;
  const u16* vb0 = W2 + ((size_t)(ng*4)*64 + lane)*8;
  b0 = *(const bf16x8*)(vb0);
  b1 = *(const bf16x8*)(vb0 + 512);
  b2 = *(const bf16x8*)(vb0 + 1024);
  b3 = *(const bf16x8*)(vb0 + 1536);
  #pragma unroll 1
  for (int k0=0;k0<8;k0++){
    bf16x8 c0=b0, c1=b1, c2=b2, c3=b3;
    if (k0 < 7){
      const u16* wn = W2 + ((size_t)((k0+1)*16 + ng*4)*64 + lane)*8;
      b0 = *(const bf16x8*)(wn);
      b1 = *(const bf16x8*)(wn + 512);
      b2 = *(const bf16x8*)(wn + 1024);
      b3 = *(const bf16x8*)(wn + 1536);
    }
    bf16x8 a0 = *(const bf16x8*)(sM1 + (mh*48 + 0*16 + nl)*264 + k0*32 + quad*8);
    bf16x8 a1 = *(const bf16x8*)(sM1 + (mh*48 + 1*16 + nl)*264 + k0*32 + quad*8);
    bf16x8 a2 = *(const bf16x8*)(sM1 + (mh*48 + 2*16 + nl)*264 + k0*32 + quad*8);
    acc2[0][0]=__builtin_amdgcn_mfma_f32_16x16x32_bf16(a0,c0,acc2[0][0],0,0,0);
    acc2[0][1]=__builtin_amdgcn_mfma_f32_16x16x32_bf16(a0,c1,acc2[0][1],0,0,0);
    acc2[0][2]=__builtin_amdgcn_mfma_f32_16x16x32_bf16(a0,c2,acc2[0][2],0,0,0);
    acc2[0][3]=__builtin_amdgcn_mfma_f32_16x16x32_bf16(a0,c3,acc2[0][3],0,0,0);
    acc2[1][0]=__builtin_amdgcn_mfma_f32_16x16x32_bf16(a1,c0,acc2[1][0],0,0,0);
    acc2[1][1]=__builtin_amdgcn_mfma_f32_16x16x32_bf16(a1,c1,acc2[1][1],0,0,0);
    acc2[1][2]=__builtin_amdgcn_mfma_f32_16x16x32_bf16(a1,c2,acc2[1][2],0,0,0);
    acc2[1][3]=__builtin_amdgcn_mfma_f32_16x16x32_bf16(a1,c3,acc2[1][3],0,0,0);
    acc2[2][0]=__builtin_amdgcn_mfma_f32_16x16x32_bf16(a2,c0,acc2[2][0],0,0,0);
    acc2[2][1]=__builtin_amdgcn_mfma_f32_16x16x32_bf16(a2,c1,acc2[2][1],0,0,0);
    acc2[2][2]=__builtin_amdgcn_mfma_f32_16x16x32_bf16(a2,c2,acc2[2][2],0,0,0);
    acc2[2][3]=__builtin_amdgcn_mfma_f32_16x16x32_bf16(a2,c3,acc2[2][3],0,0,0);
  }
  #pragma unroll
  for (int mt=0;mt<3;mt++)
  #pragma unroll
  for (int nt=0;nt<4;nt++){
    int n = ng*64 + nt*16 + nl;
    float bb = B2[l*HID + n];
    #pragma unroll
    for (int r=0;r<4;r++){
      int m = mh*48 + mt*16 + quad*4 + r;
      sM2[m*264 + n] = f2b(silu_f(acc2[mt][nt][r] + bb));
    }
  }
  __syncthreads();
  if (tid < 384){
    int e = tid >> 2, qq = tid & 3;
    float s = 0.f; int nb = qq*64;
    #pragma unroll 4
    for (int n=0;n<64;n++) s += b2f(sM2[e*264 + nb + n])*cW3[l*HID + nb + n];
    sDot[e][qq] = s;
  }
  __syncthreads();
  if (tid < 96) sS[tid] = sDot[tid][0]+sDot[tid][1]+sDot[tid][2]+sDot[tid][3];
  __syncthreads();
  if (tid < 6){
    int rr = tid/3, c = tid%3;
    float u = 0.f;
    int eb = rr*48;
    #pragma unroll 4
    for (int e=0;e<48;e++) u += sCd[(eb+e)*3+c]*sS[eb+e];
    xn[(r0+rr)*3+c] = xc[(r0+rr)*3+c] + u/5.0f;
  }
}

// ---------------- outputs ----------------
__global__ void k_outx(const float* __restrict__ x, const float* __restrict__ posw,
                       float* __restrict__ out)
{
  int i=blockIdx.x*1024+threadIdx.x;
  if (i<3072) out[i]=x[i]*posw[0];
}

__global__ __launch_bounds__(256) void k_outh(const float* __restrict__ h,
    const float* __restrict__ Wout, const float* __restrict__ bout,
    float* __restrict__ out)
{
  __shared__ float sH[2048];
  int blk=blockIdx.x, tid=threadIdx.x;
  int n0=blk*8;
  for (int x=tid;x<2048;x+=256) sH[x]=h[(size_t)n0*HID+x];
  __syncthreads();
  int nl=tid>>5, j=tid&31;
  float acc=bout[j];
  #pragma unroll 4
  for (int k=0;k<256;k++) acc += sH[nl*HID+k]*Wout[k*32+j];
  out[3072 + (n0+nl)*32 + j]=acc;
}

extern "C" void kernel_launch(void* const* d_in, const int* in_sizes, int n_in,
                              void* d_out, int out_size, void* d_ws, size_t ws_size,
                              hipStream_t stream)
{
  const float* protPos = (const float*)d_in[0];
  const int*   protEle = (const int*)d_in[1];
  const int*   protAA  = (const int*)d_in[2];
  const int*   protBB  = (const int*)d_in[3];
  const float* XtPos   = (const float*)d_in[4];
  const float* XtFeat  = (const float*)d_in[5];
  const int*   tArr    = (const int*)d_in[6];
  const float* WtTime  = (const float*)d_in[7];
  const float* Wele    = (const float*)d_in[8];
  const float* Waa     = (const float*)d_in[9];
  const float* Wbb     = (const float*)d_in[10];
  const float* Win     = (const float*)d_in[11];
  const float* bin     = (const float*)d_in[12];
  const float* Wout    = (const float*)d_in[13];
  const float* bout    = (const float*)d_in[14];
  const float* eW1     = (const float*)d_in[15];
  const float* eB1     = (const float*)d_in[16];
  const float* eW2     = (const float*)d_in[17];
  const float* eB2     = (const float*)d_in[18];
  const float* attW    = (const float*)d_in[19];
  const float* attB    = (const float*)d_in[20];
  const float* nW1     = (const float*)d_in[21];
  const float* nB1     = (const float*)d_in[22];
  const float* nW2     = (const float*)d_in[23];
  const float* nB2     = (const float*)d_in[24];
  const float* cW1     = (const float*)d_in[25];
  const float* cB1     = (const float*)d_in[26];
  const float* cW2     = (const float*)d_in[27];
  const float* cB2     = (const float*)d_in[28];
  const float* cW3     = (const float*)d_in[29];
  const float* posw    = (const float*)d_in[30];

  float* fp = (float*)d_ws;
  float* X0   = fp;               fp += NTOT*3;
  float* X1   = fp;               fp += NTOT*3;
  float* feats= fp;               fp += NTOT*40;
  float* h    = fp;               fp += (size_t)NTOT*HID;
  float* emb0 = fp;               fp += (size_t)ETOT*12;
  int*   col  = (int*)fp;         fp += ETOT;
  u16*   up   = (u16*)fp;
  u16* h_bf   = up;               up += (size_t)NTOT*HID;
  u16* agg_bf = up;               up += (size_t)N_LIGC*HID;
  u16* eW1p   = up;               up += (size_t)DEPTHC*544*HID;
  u16* eW2p   = up;               up += (size_t)DEPTHC*HID*HID;
  u16* nW1p   = up;               up += (size_t)DEPTHC*512*HID;
  u16* nW2p   = up;               up += (size_t)DEPTHC*HID*HID;
  u16* cW1p   = up;               up += (size_t)DEPTHC*544*HID;
  u16* cW2p   = up;               up += (size_t)DEPTHC*HID*HID;

  {
    int t1 = DEPTHC*544*HID/8;
    int t2 = DEPTHC*HID*HID/8;
    int t3 = DEPTHC*512*HID/8;
    k_convw<<<(t1+255)/256,256,0,stream>>>(eW1, eW1p, 536, 544, HID, t1);
    k_convw<<<(t2+255)/256,256,0,stream>>>(eW2, eW2p, 256, 256, HID, t2);
    k_convw<<<(t3+255)/256,256,0,stream>>>(nW1, nW1p, 512, 512, HID, t3);
    k_convw<<<(t2+255)/256,256,0,stream>>>(nW2, nW2p, 256, 256, HID, t2);
    k_convw<<<(t1+255)/256,256,0,stream>>>(cW1, cW1p, 536, 544, HID, t1);
    k_convw<<<(t2+255)/256,256,0,stream>>>(cW2, cW2p, 256, 256, HID, t2);
  }

  k_embed<<<36,256,0,stream>>>(protPos,protEle,protAA,protBB,XtPos,XtFeat,tArr,
                               WtTime,Wele,Waa,Wbb,feats,X0,X1);
  k_hinit<<<NTOT/8,256,0,stream>>>(feats,Win,bin,h,h_bf);
  k_knn<<<N_LIGC,256,0,stream>>>(X0,col,emb0);

  float* xc = X0; float* xn = X1;
  for (int l=0;l<DEPTHC;l++){
    k_edge<<<N_LIGC/2,512,0,stream>>>(h_bf,xc,col,emb0,eW1p,eB1,eW2p,eB2,attW,attB,agg_bf,l);
    k_node<<<NTOT/32,256,0,stream>>>(h,h_bf,agg_bf,nW1p,nB1,nW2p,nB2,l);
    k_coord<<<N_LIGC/2,512,0,stream>>>(h_bf,xc,xn,col,emb0,cW1p,cB1,cW2p,cB2,cW3,l);
    float* t2=xc; xc=xn; xn=t2;
  }
  k_outx<<<3,1024,0,stream>>>(xc,posw,(float*)d_out);
  k_outh<<<N_LIGC/8,256,0,stream>>>(h,Wout,bout,(float*)d_out);
}

// Round 4
// 887.148 us; speedup vs baseline: 1.0575x; 1.0575x over previous
//
#include <hip/hip_runtime.h>
#include <hip/hip_bf16.h>
#include <math.h>

#define N_LIGC 1024
#define NTOT 9216
#define KNN 48
#define HID 256
#define DEPTHC 5
#define ETOT (N_LIGC*KNN)
#define KBINS 4096

typedef unsigned short u16;
typedef __attribute__((ext_vector_type(8))) short bf16x8;
typedef __attribute__((ext_vector_type(4))) float f32x4;

__device__ __forceinline__ float freq_f(int i){
  double p = (double)(1 << (2*i));
  return (float)((2.0*3.14159265358979323846)*p/15.0);
}
__device__ __forceinline__ float silu_f(float v){ return v/(1.0f+expf(-v)); }
__device__ __forceinline__ u16 f2b(float f){
  union { __hip_bfloat16 h; u16 u; } c; c.h = __float2bfloat16(f); return c.u;
}
__device__ __forceinline__ float b2f(u16 u){
  union { unsigned int i; float f; } c; c.i = ((unsigned int)u)<<16; return c.f;
}

// ---- pack fp32 weight rows [kOff, kOff+Keff) of [L][srcK][N] -> bf16 B-frag layout
__global__ __launch_bounds__(256) void k_convw(const float* __restrict__ src,
    u16* __restrict__ dst, int srcK, int kOff, int Keff, int Kp, int N, int total)
{
  int idx = blockIdx.x*256 + threadIdx.x;
  if (idx >= total) return;
  int lane = idx & 63;
  int rest = idx >> 6;
  int Nt = N >> 4;
  int n0 = rest % Nt;
  int rest2 = rest / Nt;
  int Kt = Kp >> 5;
  int k0 = rest2 % Kt;
  int layer = rest2 / Kt;
  int kq = lane >> 4, nl = lane & 15;
  int kb = k0*32 + kq*8, n = n0*16 + nl;
  u16 o[8];
  #pragma unroll
  for (int j=0;j<8;j++){
    int k = kb + j;
    float v = (k < Keff) ? src[((size_t)layer*srcK + kOff + k)*N + n] : 0.f;
    o[j] = f2b(v);
  }
  *(uint4*)(dst + (size_t)idx*8) = *(uint4*)o;
}

// ---- feature embedding + coords ----
__global__ __launch_bounds__(256) void k_embed(
    const float* __restrict__ protPos, const int* __restrict__ protEle,
    const int* __restrict__ protAA, const int* __restrict__ protBB,
    const float* __restrict__ XtPos, const float* __restrict__ XtFeat,
    const int* __restrict__ tArr, const float* __restrict__ WtTime,
    const float* __restrict__ Wele, const float* __restrict__ Waa,
    const float* __restrict__ Wbb,
    float* __restrict__ feats, float* __restrict__ X0, float* __restrict__ X1)
{
  int i = blockIdx.x*256+threadIdx.x;
  if (i >= NTOT) return;
  float c0,c1,c2;
  float* f = feats + i*40;
  if (i < N_LIGC){
    c0 = XtPos[i*3+0]; c1 = XtPos[i*3+1]; c2 = XtPos[i*3+2];
    #pragma unroll
    for (int k=0;k<32;k++) f[k] = XtFeat[i*32+k];
    int tt = tArr[i];
    #pragma unroll
    for (int k=0;k<8;k++) f[32+k] = WtTime[tt*8+k];
  } else {
    int p = i - N_LIGC;
    c0 = protPos[p*3+0]; c1 = protPos[p*3+1]; c2 = protPos[p*3+2];
    int e = protEle[p], a = protAA[p], b = protBB[p];
    #pragma unroll
    for (int k=0;k<16;k++) f[k] = Wele[e*16+k];
    #pragma unroll
    for (int k=0;k<16;k++) f[16+k] = Waa[a*16+k];
    #pragma unroll
    for (int k=0;k<8;k++) f[32+k] = Wbb[b*8+k];
  }
  X0[i*3+0]=c0; X0[i*3+1]=c1; X0[i*3+2]=c2;
  X1[i*3+0]=c0; X1[i*3+1]=c1; X1[i*3+2]=c2;
}

// ---- h = feats @ W_in + b_in (fp32 + bf16 shadow) ----
__global__ __launch_bounds__(256) void k_hinit(const float* __restrict__ feats,
    const float* __restrict__ Win, const float* __restrict__ bin,
    float* __restrict__ h, u16* __restrict__ h_bf)
{
  __shared__ float sF[8*40];
  int blk=blockIdx.x, tid=threadIdx.x;
  int n0=blk*8;
  for (int x=tid;x<320;x+=256) sF[x]=feats[n0*40+x];
  __syncthreads();
  float acc[8];
  float b=bin[tid];
  #pragma unroll
  for (int n=0;n<8;n++) acc[n]=b;
  for (int k=0;k<40;k++){
    float w=Win[k*HID+tid];
    #pragma unroll
    for (int n=0;n<8;n++) acc[n]+=sF[n*40+k]*w;
  }
  #pragma unroll
  for (int n=0;n<8;n++){
    h[(size_t)(n0+n)*HID+tid]=acc[n];
    h_bf[(size_t)(n0+n)*HID+tid]=f2b(acc[n]);
  }
}

// ---- KNN: radix-histogram top-K set selection (one block per ligand) ----
__global__ __launch_bounds__(256) void k_knn(const float* __restrict__ X,
    int* __restrict__ col, float* __restrict__ emb0)
{
  __shared__ float sd[NTOT];
  __shared__ unsigned int hist[KBINS];
  __shared__ unsigned int part[256];
  __shared__ float selD[KNN];
  __shared__ int candI[512];
  __shared__ int sB, sCless, sNeed, sNsel, sNcand;
  int b = blockIdx.x, tid = threadIdx.x;
  for (int i=tid;i<KBINS;i+=256) hist[i]=0u;
  if (tid==0){ sNsel=0; sNcand=0; }
  float px = X[b*3+0], py = X[b*3+1], pz = X[b*3+2];
  __syncthreads();
  #pragma unroll 4
  for (int j=0;j<36;j++){
    int i = tid + 256*j;
    float dx = __fsub_rn(px, X[i*3+0]);
    float dy = __fsub_rn(py, X[i*3+1]);
    float dz = __fsub_rn(pz, X[i*3+2]);
    float d2 = __fadd_rn(__fadd_rn(__fmul_rn(dx,dx),__fmul_rn(dy,dy)),__fmul_rn(dz,dz));
    if (i==b) d2 = INFINITY;
    sd[i] = d2;
    unsigned key = __float_as_uint(d2) >> 19;
    atomicAdd(&hist[key], 1u);
  }
  __syncthreads();
  {
    unsigned s=0;
    #pragma unroll 4
    for (int k=0;k<16;k++) s += hist[tid*16+k];
    part[tid]=s;
  }
  __syncthreads();
  if (tid==0){
    unsigned c=0; int chunk=0;
    for (int t=0;t<256;t++){
      if (c + part[t] >= (unsigned)KNN){ chunk=t; break; }
      c += part[t];
    }
    int bin = chunk*16;
    for (;;bin++){
      unsigned hh = hist[bin];
      if (c + hh >= (unsigned)KNN) break;
      c += hh;
    }
    sB = bin; sCless = (int)c; sNeed = KNN - (int)c;
  }
  __syncthreads();
  int B = sB;
  #pragma unroll 4
  for (int j=0;j<36;j++){
    int i = tid + 256*j;
    float v = sd[i];
    int key = (int)(__float_as_uint(v) >> 19);
    if (key < B){
      int p = atomicAdd(&sNsel, 1);
      col[b*KNN+p] = i; selD[p] = v;
    } else if (key == B){
      int c = atomicAdd(&sNcand, 1);
      if (c < 512) candI[c] = i;
    }
  }
  __syncthreads();
  if (tid < 64){
    int m = sNcand; if (m > 512) m = 512;
    int need = sNeed, base = sCless;
    float cv[8]; int ci[8];
    #pragma unroll
    for (int k=0;k<8;k++){
      int c = tid + 64*k;
      if (c < m){ ci[k]=candI[c]; cv[k]=sd[ci[k]]; }
      else      { ci[k]=0x7fffffff; cv[k]=INFINITY; }
    }
    for (int it=0; it<need; it++){
      float bv=INFINITY; int bi=0x7fffffff; int bk=0;
      #pragma unroll
      for (int k=0;k<8;k++){
        if (cv[k]<bv || (cv[k]==bv && ci[k]<bi)){ bv=cv[k]; bi=ci[k]; bk=k; }
      }
      int bslot = tid + 64*bk;
      #pragma unroll
      for (int off=32; off>=1; off>>=1){
        float ov = __shfl_down(bv, off);
        int   oi = __shfl_down(bi, off);
        int   os = __shfl_down(bslot, off);
        if (ov < bv || (ov==bv && oi<bi)){ bv=ov; bi=oi; bslot=os; }
      }
      int wslot = __shfl(bslot, 0);
      if (tid==0){ col[b*KNN+base+it]=bi; selD[base+it]=bv; }
      if ((wslot & 63) == tid) cv[wslot >> 6] = INFINITY;
    }
  }
  __syncthreads();
  if (tid < KNN){
    float d = sqrtf(selD[tid] + 1e-8f);
    int base = (b*KNN+tid)*12;
    #pragma unroll
    for (int i=0;i<6;i++){
      float fr = freq_f(i);
      emb0[base+i]   = sinf(d*fr);
      emb0[base+6+i] = cosf(d*fr);
    }
  }
}

// ---- k_pq: Q = h @ W1b (all nodes), R = h @ W1a (ligand blocks only) ----
// Wab packed with Kp=512: k0 0..7 = W1a (h[row] part), k0 8..15 = W1b (h[col] part)
__global__ __launch_bounds__(256) void k_pq(const u16* __restrict__ h_bf,
    const u16* __restrict__ Wab, float* __restrict__ R, u16* __restrict__ Qb, int l)
{
  __shared__ __align__(16) u16 sA[32*264];
  int blk=blockIdx.x, tid=threadIdx.x;
  int lane=tid&63, ng=tid>>6, quad=lane>>4, nl=lane&15;
  for (int t=tid; t<32*32; t+=256){
    int i=t>>5, q=t&31;
    uint4 v = ((const uint4*)(h_bf + (size_t)(blk*32+i)*HID))[q];
    *(uint4*)(sA + i*264 + q*8) = v;
  }
  __syncthreads();
  const u16* Wl = Wab + (size_t)l*512*HID;
  f32x4 zero4 = {0.f,0.f,0.f,0.f};
  f32x4 aQ[2][4];
  #pragma unroll
  for (int i=0;i<2;i++){ aQ[i][0]=zero4; aQ[i][1]=zero4; aQ[i][2]=zero4; aQ[i][3]=zero4; }
  #pragma unroll 2
  for (int k0=0;k0<8;k0++){
    bf16x8 a0 = *(const bf16x8*)(sA + (0*16+nl)*264 + k0*32 + quad*8);
    bf16x8 a1 = *(const bf16x8*)(sA + (1*16+nl)*264 + k0*32 + quad*8);
    const u16* wb = Wl + ((size_t)((k0+8)*16 + ng*4)*64 + lane)*8;
    bf16x8 b0 = *(const bf16x8*)(wb);
    bf16x8 b1 = *(const bf16x8*)(wb + 512);
    bf16x8 b2 = *(const bf16x8*)(wb + 1024);
    bf16x8 b3 = *(const bf16x8*)(wb + 1536);
    aQ[0][0]=__builtin_amdgcn_mfma_f32_16x16x32_bf16(a0,b0,aQ[0][0],0,0,0);
    aQ[0][1]=__builtin_amdgcn_mfma_f32_16x16x32_bf16(a0,b1,aQ[0][1],0,0,0);
    aQ[0][2]=__builtin_amdgcn_mfma_f32_16x16x32_bf16(a0,b2,aQ[0][2],0,0,0);
    aQ[0][3]=__builtin_amdgcn_mfma_f32_16x16x32_bf16(a0,b3,aQ[0][3],0,0,0);
    aQ[1][0]=__builtin_amdgcn_mfma_f32_16x16x32_bf16(a1,b0,aQ[1][0],0,0,0);
    aQ[1][1]=__builtin_amdgcn_mfma_f32_16x16x32_bf16(a1,b1,aQ[1][1],0,0,0);
    aQ[1][2]=__builtin_amdgcn_mfma_f32_16x16x32_bf16(a1,b2,aQ[1][2],0,0,0);
    aQ[1][3]=__builtin_amdgcn_mfma_f32_16x16x32_bf16(a1,b3,aQ[1][3],0,0,0);
  }
  #pragma unroll
  for (int mt=0;mt<2;mt++)
  #pragma unroll
  for (int nt=0;nt<4;nt++){
    int n = ng*64 + nt*16 + nl;
    #pragma unroll
    for (int r=0;r<4;r++){
      int node = blk*32 + mt*16 + quad*4 + r;
      Qb[(size_t)node*HID + n] = f2b(aQ[mt][nt][r]);
    }
  }
  if (blk < 32){
    f32x4 aR[2][4];
    #pragma unroll
    for (int i=0;i<2;i++){ aR[i][0]=zero4; aR[i][1]=zero4; aR[i][2]=zero4; aR[i][3]=zero4; }
    #pragma unroll 2
    for (int k0=0;k0<8;k0++){
      bf16x8 a0 = *(const bf16x8*)(sA + (0*16+nl)*264 + k0*32 + quad*8);
      bf16x8 a1 = *(const bf16x8*)(sA + (1*16+nl)*264 + k0*32 + quad*8);
      const u16* wb = Wl + ((size_t)(k0*16 + ng*4)*64 + lane)*8;
      bf16x8 b0 = *(const bf16x8*)(wb);
      bf16x8 b1 = *(const bf16x8*)(wb + 512);
      bf16x8 b2 = *(const bf16x8*)(wb + 1024);
      bf16x8 b3 = *(const bf16x8*)(wb + 1536);
      aR[0][0]=__builtin_amdgcn_mfma_f32_16x16x32_bf16(a0,b0,aR[0][0],0,0,0);
      aR[0][1]=__builtin_amdgcn_mfma_f32_16x16x32_bf16(a0,b1,aR[0][1],0,0,0);
      aR[0][2]=__builtin_amdgcn_mfma_f32_16x16x32_bf16(a0,b2,aR[0][2],0,0,0);
      aR[0][3]=__builtin_amdgcn_mfma_f32_16x16x32_bf16(a0,b3,aR[0][3],0,0,0);
      aR[1][0]=__builtin_amdgcn_mfma_f32_16x16x32_bf16(a1,b0,aR[1][0],0,0,0);
      aR[1][1]=__builtin_amdgcn_mfma_f32_16x16x32_bf16(a1,b1,aR[1][1],0,0,0);
      aR[1][2]=__builtin_amdgcn_mfma_f32_16x16x32_bf16(a1,b2,aR[1][2],0,0,0);
      aR[1][3]=__builtin_amdgcn_mfma_f32_16x16x32_bf16(a1,b3,aR[1][3],0,0,0);
    }
    #pragma unroll
    for (int mt=0;mt<2;mt++)
    #pragma unroll
    for (int nt=0;nt<4;nt++){
      int n = ng*64 + nt*16 + nl;
      #pragma unroll
      for (int r=0;r<4;r++){
        int node = blk*32 + mt*16 + quad*4 + r;
        R[(size_t)node*HID + n] = aR[mt][nt][r];
      }
    }
  }
}

// ---- edge combine: ea-GEMM(K=32) + R/Q add + silu + stage2 GEMM + att + aggregate ----
__global__ __launch_bounds__(256) void k_comb_edge(
    const u16* __restrict__ Qb, const float* __restrict__ R,
    const float* __restrict__ xc,
    const int* __restrict__ colIdx, const float* __restrict__ emb0,
    const u16* __restrict__ W1cP, const float* __restrict__ B1,
    const u16* __restrict__ W2p, const float* __restrict__ B2,
    const float* __restrict__ attW, const float* __restrict__ attB,
    u16* __restrict__ agg_bf, int l)
{
  __shared__ __align__(16) u16 sQ[48*264];    // gathered Q[col]; later aliased as sM2
  __shared__ __align__(16) u16 sEA[48*40];
  __shared__ __align__(16) u16 sM1[48*264];
  __shared__ float sR[256];
  __shared__ int sCol[48];
  __shared__ float sSig[48];
  __shared__ float sDot[48][4];
  u16* sM2 = sQ;

  int row = blockIdx.x, tid = threadIdx.x;
  int lane = tid & 63, ng = tid >> 6;
  int quad = lane >> 4, nl = lane & 15;

  if (tid < 48) sCol[tid] = colIdx[(size_t)row*KNN + tid];
  sR[tid] = R[(size_t)row*HID + tid];
  __syncthreads();
  for (int t = tid; t < 48*32; t += 256){
    int e = t >> 5, q = t & 31;
    uint4 v = ((const uint4*)(Qb + (size_t)sCol[e]*HID))[q];
    *(uint4*)(sQ + e*264 + q*8) = v;
  }
  if (tid < 48){
    int cg = sCol[tid];
    float dx = xc[row*3+0]-xc[cg*3+0];
    float dy = xc[row*3+1]-xc[cg*3+1];
    float dz = xc[row*3+2]-xc[cg*3+2];
    float d = sqrtf(dx*dx+dy*dy+dz*dz + 1e-8f);
    u16* ea = sEA + tid*40;
    #pragma unroll
    for (int i=0;i<6;i++){
      float fr = freq_f(i);
      ea[i]   = f2b(sinf(d*fr));
      ea[6+i] = f2b(cosf(d*fr));
    }
    #pragma unroll
    for (int i=0;i<12;i++) ea[12+i] = f2b(emb0[((size_t)row*KNN + tid)*12 + i]);
    #pragma unroll
    for (int i=24;i<32;i++) ea[i] = 0;
  }
  __syncthreads();

  f32x4 zero4 = {0.f,0.f,0.f,0.f};
  f32x4 acc[3][4];
  #pragma unroll
  for (int i=0;i<3;i++){ acc[i][0]=zero4; acc[i][1]=zero4; acc[i][2]=zero4; acc[i][3]=zero4; }
  {
    const u16* Wc = W1cP + (size_t)l*32*HID;
    const u16* wb = Wc + ((size_t)(ng*4)*64 + lane)*8;
    bf16x8 b0 = *(const bf16x8*)(wb);
    bf16x8 b1 = *(const bf16x8*)(wb + 512);
    bf16x8 b2 = *(const bf16x8*)(wb + 1024);
    bf16x8 b3 = *(const bf16x8*)(wb + 1536);
    bf16x8 a0 = *(const bf16x8*)(sEA + (0*16+nl)*40 + quad*8);
    bf16x8 a1 = *(const bf16x8*)(sEA + (1*16+nl)*40 + quad*8);
    bf16x8 a2 = *(const bf16x8*)(sEA + (2*16+nl)*40 + quad*8);
    acc[0][0]=__builtin_amdgcn_mfma_f32_16x16x32_bf16(a0,b0,acc[0][0],0,0,0);
    acc[0][1]=__builtin_amdgcn_mfma_f32_16x16x32_bf16(a0,b1,acc[0][1],0,0,0);
    acc[0][2]=__builtin_amdgcn_mfma_f32_16x16x32_bf16(a0,b2,acc[0][2],0,0,0);
    acc[0][3]=__builtin_amdgcn_mfma_f32_16x16x32_bf16(a0,b3,acc[0][3],0,0,0);
    acc[1][0]=__builtin_amdgcn_mfma_f32_16x16x32_bf16(a1,b0,acc[1][0],0,0,0);
    acc[1][1]=__builtin_amdgcn_mfma_f32_16x16x32_bf16(a1,b1,acc[1][1],0,0,0);
    acc[1][2]=__builtin_amdgcn_mfma_f32_16x16x32_bf16(a1,b2,acc[1][2],0,0,0);
    acc[1][3]=__builtin_amdgcn_mfma_f32_16x16x32_bf16(a1,b3,acc[1][3],0,0,0);
    acc[2][0]=__builtin_amdgcn_mfma_f32_16x16x32_bf16(a2,b0,acc[2][0],0,0,0);
    acc[2][1]=__builtin_amdgcn_mfma_f32_16x16x32_bf16(a2,b1,acc[2][1],0,0,0);
    acc[2][2]=__builtin_amdgcn_mfma_f32_16x16x32_bf16(a2,b2,acc[2][2],0,0,0);
    acc[2][3]=__builtin_amdgcn_mfma_f32_16x16x32_bf16(a2,b3,acc[2][3],0,0,0);
  }
  #pragma unroll
  for (int mt=0;mt<3;mt++)
  #pragma unroll
  for (int nt=0;nt<4;nt++){
    int n = ng*64 + nt*16 + nl;
    float bb = B1[l*HID + n] + sR[n];
    #pragma unroll
    for (int r=0;r<4;r++){
      int m = mt*16 + quad*4 + r;
      float v = acc[mt][nt][r] + bb + b2f(sQ[m*264 + n]);
      sM1[m*264 + n] = f2b(silu_f(v));
    }
  }
  __syncthreads();

  f32x4 acc2[3][4];
  #pragma unroll
  for (int i=0;i<3;i++){ acc2[i][0]=zero4; acc2[i][1]=zero4; acc2[i][2]=zero4; acc2[i][3]=zero4; }
  const u16* W2 = W2p + (size_t)l*HID*HID;
  #pragma unroll 2
  for (int k0=0;k0<8;k0++){
    bf16x8 a0 = *(const bf16x8*)(sM1 + (0*16+nl)*264 + k0*32 + quad*8);
    bf16x8 a1 = *(const bf16x8*)(sM1 + (1*16+nl)*264 + k0*32 + quad*8);
    bf16x8 a2 = *(const bf16x8*)(sM1 + (2*16+nl)*264 + k0*32 + quad*8);
    const u16* wb = W2 + ((size_t)(k0*16 + ng*4)*64 + lane)*8;
    bf16x8 b0 = *(const bf16x8*)(wb);
    bf16x8 b1 = *(const bf16x8*)(wb + 512);
    bf16x8 b2 = *(const bf16x8*)(wb + 1024);
    bf16x8 b3 = *(const bf16x8*)(wb + 1536);
    acc2[0][0]=__builtin_amdgcn_mfma_f32_16x16x32_bf16(a0,b0,acc2[0][0],0,0,0);
    acc2[0][1]=__builtin_amdgcn_mfma_f32_16x16x32_bf16(a0,b1,acc2[0][1],0,0,0);
    acc2[0][2]=__builtin_amdgcn_mfma_f32_16x16x32_bf16(a0,b2,acc2[0][2],0,0,0);
    acc2[0][3]=__builtin_amdgcn_mfma_f32_16x16x32_bf16(a0,b3,acc2[0][3],0,0,0);
    acc2[1][0]=__builtin_amdgcn_mfma_f32_16x16x32_bf16(a1,b0,acc2[1][0],0,0,0);
    acc2[1][1]=__builtin_amdgcn_mfma_f32_16x16x32_bf16(a1,b1,acc2[1][1],0,0,0);
    acc2[1][2]=__builtin_amdgcn_mfma_f32_16x16x32_bf16(a1,b2,acc2[1][2],0,0,0);
    acc2[1][3]=__builtin_amdgcn_mfma_f32_16x16x32_bf16(a1,b3,acc2[1][3],0,0,0);
    acc2[2][0]=__builtin_amdgcn_mfma_f32_16x16x32_bf16(a2,b0,acc2[2][0],0,0,0);
    acc2[2][1]=__builtin_amdgcn_mfma_f32_16x16x32_bf16(a2,b1,acc2[2][1],0,0,0);
    acc2[2][2]=__builtin_amdgcn_mfma_f32_16x16x32_bf16(a2,b2,acc2[2][2],0,0,0);
    acc2[2][3]=__builtin_amdgcn_mfma_f32_16x16x32_bf16(a2,b3,acc2[2][3],0,0,0);
  }
  // sM2 aliases sQ; all sQ reads completed before the barrier above
  #pragma unroll
  for (int mt=0;mt<3;mt++)
  #pragma unroll
  for (int nt=0;nt<4;nt++){
    int n = ng*64 + nt*16 + nl;
    float bb = B2[l*HID + n];
    #pragma unroll
    for (int r=0;r<4;r++){
      int m = mt*16 + quad*4 + r;
      sM2[m*264 + n] = f2b(silu_f(acc2[mt][nt][r] + bb));
    }
  }
  __syncthreads();
  if (tid < 192){
    int e = tid >> 2, qq = tid & 3;
    float s = 0.f; int nb = qq*64;
    #pragma unroll 4
    for (int n=0;n<64;n++) s += b2f(sM2[e*264 + nb + n])*attW[l*HID + nb + n];
    sDot[e][qq] = s;
  }
  __syncthreads();
  if (tid < 48){
    float s = sDot[tid][0]+sDot[tid][1]+sDot[tid][2]+sDot[tid][3] + attB[l];
    sSig[tid] = 1.f/(1.f+expf(-s));
  }
  __syncthreads();
  {
    float a = 0.f;
    #pragma unroll 4
    for (int e=0;e<48;e++) a += b2f(sM2[e*264 + tid])*sSig[e];
    agg_bf[(size_t)row*HID + tid] = f2b(a/5.0f);
  }
}

// ---- node MLP (MFMA, residual): 32 nodes/block ----
__global__ __launch_bounds__(256) void k_node(
    float* __restrict__ h, u16* __restrict__ h_bf,
    const u16* __restrict__ agg_bf,
    const u16* __restrict__ W1p, const float* __restrict__ B1,
    const u16* __restrict__ W2p, const float* __restrict__ B2, int l)
{
  __shared__ __align__(16) u16 sA[32*520];
  __shared__ __align__(16) u16 sU[32*264];
  int blk=blockIdx.x, tid=threadIdx.x;
  int lane=tid&63, wv=tid>>6, quad=lane>>4, nl=lane&15;
  for (int t=tid; t<32*64; t+=256){
    int i=t>>6, q=t&63;
    int node = blk*32+i;
    uint4 v;
    if (q<32) v = ((const uint4*)(h_bf + (size_t)node*HID))[q];
    else if (node < N_LIGC) v = ((const uint4*)(agg_bf + (size_t)node*HID))[q-32];
    else { v.x=0u; v.y=0u; v.z=0u; v.w=0u; }
    *(uint4*)(sA + i*520 + q*8) = v;
  }
  __syncthreads();
  f32x4 zero4 = {0.f,0.f,0.f,0.f};
  f32x4 acc[2][4];
  #pragma unroll
  for (int i=0;i<2;i++){ acc[i][0]=zero4; acc[i][1]=zero4; acc[i][2]=zero4; acc[i][3]=zero4; }
  const u16* Wp = W1p + (size_t)l*512*HID;
  #pragma unroll 2
  for (int k0=0;k0<16;k0++){
    bf16x8 a0 = *(const bf16x8*)(sA + (0*16+nl)*520 + k0*32 + quad*8);
    bf16x8 a1 = *(const bf16x8*)(sA + (1*16+nl)*520 + k0*32 + quad*8);
    const u16* wb = Wp + ((size_t)(k0*16 + wv*4)*64 + lane)*8;
    bf16x8 b0 = *(const bf16x8*)(wb);
    bf16x8 b1 = *(const bf16x8*)(wb + 512);
    bf16x8 b2 = *(const bf16x8*)(wb + 1024);
    bf16x8 b3 = *(const bf16x8*)(wb + 1536);
    acc[0][0]=__builtin_amdgcn_mfma_f32_16x16x32_bf16(a0,b0,acc[0][0],0,0,0);
    acc[0][1]=__builtin_amdgcn_mfma_f32_16x16x32_bf16(a0,b1,acc[0][1],0,0,0);
    acc[0][2]=__builtin_amdgcn_mfma_f32_16x16x32_bf16(a0,b2,acc[0][2],0,0,0);
    acc[0][3]=__builtin_amdgcn_mfma_f32_16x16x32_bf16(a0,b3,acc[0][3],0,0,0);
    acc[1][0]=__builtin_amdgcn_mfma_f32_16x16x32_bf16(a1,b0,acc[1][0],0,0,0);
    acc[1][1]=__builtin_amdgcn_mfma_f32_16x16x32_bf16(a1,b1,acc[1][1],0,0,0);
    acc[1][2]=__builtin_amdgcn_mfma_f32_16x16x32_bf16(a1,b2,acc[1][2],0,0,0);
    acc[1][3]=__builtin_amdgcn_mfma_f32_16x16x32_bf16(a1,b3,acc[1][3],0,0,0);
  }
  #pragma unroll
  for (int mt=0;mt<2;mt++)
  #pragma unroll
  for (int nt=0;nt<4;nt++){
    int n = wv*64 + nt*16 + nl;
    float bb = B1[l*HID + n];
    #pragma unroll
    for (int r=0;r<4;r++){
      int m = mt*16 + quad*4 + r;
      sU[m*264 + n] = f2b(silu_f(acc[mt][nt][r] + bb));
    }
  }
  __syncthreads();
  f32x4 acc2[2][4];
  #pragma unroll
  for (int i=0;i<2;i++){ acc2[i][0]=zero4; acc2[i][1]=zero4; acc2[i][2]=zero4; acc2[i][3]=zero4; }
  const u16* W2 = W2p + (size_t)l*HID*HID;
  #pragma unroll 2
  for (int k0=0;k0<8;k0++){
    bf16x8 a0 = *(const bf16x8*)(sU + (0*16+nl)*264 + k0*32 + quad*8);
    bf16x8 a1 = *(const bf16x8*)(sU + (1*16+nl)*264 + k0*32 + quad*8);
    const u16* wb = W2 + ((size_t)(k0*16 + wv*4)*64 + lane)*8;
    bf16x8 b0 = *(const bf16x8*)(wb);
    bf16x8 b1 = *(const bf16x8*)(wb + 512);
    bf16x8 b2 = *(const bf16x8*)(wb + 1024);
    bf16x8 b3 = *(const bf16x8*)(wb + 1536);
    acc2[0][0]=__builtin_amdgcn_mfma_f32_16x16x32_bf16(a0,b0,acc2[0][0],0,0,0);
    acc2[0][1]=__builtin_amdgcn_mfma_f32_16x16x32_bf16(a0,b1,acc2[0][1],0,0,0);
    acc2[0][2]=__builtin_amdgcn_mfma_f32_16x16x32_bf16(a0,b2,acc2[0][2],0,0,0);
    acc2[0][3]=__builtin_amdgcn_mfma_f32_16x16x32_bf16(a0,b3,acc2[0][3],0,0,0);
    acc2[1][0]=__builtin_amdgcn_mfma_f32_16x16x32_bf16(a1,b0,acc2[1][0],0,0,0);
    acc2[1][1]=__builtin_amdgcn_mfma_f32_16x16x32_bf16(a1,b1,acc2[1][1],0,0,0);
    acc2[1][2]=__builtin_amdgcn_mfma_f32_16x16x32_bf16(a1,b2,acc2[1][2],0,0,0);
    acc2[1][3]=__builtin_amdgcn_mfma_f32_16x16x32_bf16(a1,b3,acc2[1][3],0,0,0);
  }
  #pragma unroll
  for (int mt=0;mt<2;mt++)
  #pragma unroll
  for (int nt=0;nt<4;nt++){
    int n = wv*64 + nt*16 + nl;
    float bb = B2[l*HID + n];
    #pragma unroll
    for (int r=0;r<4;r++){
      int m = mt*16 + quad*4 + r;
      size_t idx = (size_t)(blk*32+m)*HID + n;
      float v = h[idx] + acc2[mt][nt][r] + bb;
      h[idx] = v;
      h_bf[idx] = f2b(v);
    }
  }
}

// ---- coord combine: ea-GEMM + R/Q add + silu + stage2 + W3 dot + x update ----
__global__ __launch_bounds__(256) void k_comb_coord(
    const u16* __restrict__ Qb, const float* __restrict__ R,
    const float* __restrict__ xc, float* __restrict__ xn,
    const int* __restrict__ colIdx, const float* __restrict__ emb0,
    const u16* __restrict__ W1cP, const float* __restrict__ B1,
    const u16* __restrict__ W2p, const float* __restrict__ B2,
    const float* __restrict__ cW3, int l)
{
  __shared__ __align__(16) u16 sQ[48*264];
  __shared__ __align__(16) u16 sEA[48*40];
  __shared__ __align__(16) u16 sM1[48*264];
  __shared__ float sR[256];
  __shared__ int sCol[48];
  __shared__ float sCd[48*3];
  __shared__ float sS[48];
  __shared__ float sDot[48][4];
  u16* sM2 = sQ;

  int row = blockIdx.x, tid = threadIdx.x;
  int lane = tid & 63, ng = tid >> 6;
  int quad = lane >> 4, nl = lane & 15;

  if (tid < 48) sCol[tid] = colIdx[(size_t)row*KNN + tid];
  sR[tid] = R[(size_t)row*HID + tid];
  __syncthreads();
  for (int t = tid; t < 48*32; t += 256){
    int e = t >> 5, q = t & 31;
    uint4 v = ((const uint4*)(Qb + (size_t)sCol[e]*HID))[q];
    *(uint4*)(sQ + e*264 + q*8) = v;
  }
  if (tid < 48){
    int cg = sCol[tid];
    float dx = xc[row*3+0]-xc[cg*3+0];
    float dy = xc[row*3+1]-xc[cg*3+1];
    float dz = xc[row*3+2]-xc[cg*3+2];
    float d = sqrtf(dx*dx+dy*dy+dz*dz + 1e-8f);
    float den = d + 1.0f;
    sCd[tid*3+0]=dx/den; sCd[tid*3+1]=dy/den; sCd[tid*3+2]=dz/den;
    u16* ea = sEA + tid*40;
    #pragma unroll
    for (int i=0;i<6;i++){
      float fr = freq_f(i);
      ea[i]   = f2b(sinf(d*fr));
      ea[6+i] = f2b(cosf(d*fr));
    }
    #pragma unroll
    for (int i=0;i<12;i++) ea[12+i] = f2b(emb0[((size_t)row*KNN + tid)*12 + i]);
    #pragma unroll
    for (int i=24;i<32;i++) ea[i] = 0;
  }
  __syncthreads();

  f32x4 zero4 = {0.f,0.f,0.f,0.f};
  f32x4 acc[3][4];
  #pragma unroll
  for (int i=0;i<3;i++){ acc[i][0]=zero4; acc[i][1]=zero4; acc[i][2]=zero4; acc[i][3]=zero4; }
  {
    const u16* Wc = W1cP + (size_t)l*32*HID;
    const u16* wb = Wc + ((size_t)(ng*4)*64 + lane)*8;
    bf16x8 b0 = *(const bf16x8*)(wb);
    bf16x8 b1 = *(const bf16x8*)(wb + 512);
    bf16x8 b2 = *(const bf16x8*)(wb + 1024);
    bf16x8 b3 = *(const bf16x8*)(wb + 1536);
    bf16x8 a0 = *(const bf16x8*)(sEA + (0*16+nl)*40 + quad*8);
    bf16x8 a1 = *(const bf16x8*)(sEA + (1*16+nl)*40 + quad*8);
    bf16x8 a2 = *(const bf16x8*)(sEA + (2*16+nl)*40 + quad*8);
    acc[0][0]=__builtin_amdgcn_mfma_f32_16x16x32_bf16(a0,b0,acc[0][0],0,0,0);
    acc[0][1]=__builtin_amdgcn_mfma_f32_16x16x32_bf16(a0,b1,acc[0][1],0,0,0);
    acc[0][2]=__builtin_amdgcn_mfma_f32_16x16x32_bf16(a0,b2,acc[0][2],0,0,0);
    acc[0][3]=__builtin_amdgcn_mfma_f32_16x16x32_bf16(a0,b3,acc[0][3],0,0,0);
    acc[1][0]=__builtin_amdgcn_mfma_f32_16x16x32_bf16(a1,b0,acc[1][0],0,0,0);
    acc[1][1]=__builtin_amdgcn_mfma_f32_16x16x32_bf16(a1,b1,acc[1][1],0,0,0);
    acc[1][2]=__builtin_amdgcn_mfma_f32_16x16x32_bf16(a1,b2,acc[1][2],0,0,0);
    acc[1][3]=__builtin_amdgcn_mfma_f32_16x16x32_bf16(a1,b3,acc[1][3],0,0,0);
    acc[2][0]=__builtin_amdgcn_mfma_f32_16x16x32_bf16(a2,b0,acc[2][0],0,0,0);
    acc[2][1]=__builtin_amdgcn_mfma_f32_16x16x32_bf16(a2,b1,acc[2][1],0,0,0);
    acc[2][2]=__builtin_amdgcn_mfma_f32_16x16x32_bf16(a2,b2,acc[2][2],0,0,0);
    acc[2][3]=__builtin_amdgcn_mfma_f32_16x16x32_bf16(a2,b3,acc[2][3],0,0,0);
  }
  #pragma unroll
  for (int mt=0;mt<3;mt++)
  #pragma unroll
  for (int nt=0;nt<4;nt++){
    int n = ng*64 + nt*16 + nl;
    float bb = B1[l*HID + n] + sR[n];
    #pragma unroll
    for (int r=0;r<4;r++){
      int m = mt*16 + quad*4 + r;
      float v = acc[mt][nt][r] + bb + b2f(sQ[m*264 + n]);
      sM1[m*264 + n] = f2b(silu_f(v));
    }
  }
  __syncthreads();

  f32x4 acc2[3][4];
  #pragma unroll
  for (int i=0;i<3;i++){ acc2[i][0]=zero4; acc2[i][1]=zero4; acc2[i][2]=zero4; acc2[i][3]=zero4; }
  const u16* W2 = W2p + (size_t)l*HID*HID;
  #pragma unroll 2
  for (int k0=0;k0<8;k0++){
    bf16x8 a0 = *(const bf16x8*)(sM1 + (0*16+nl)*264 + k0*32 + quad*8);
    bf16x8 a1 = *(const bf16x8*)(sM1 + (1*16+nl)*264 + k0*32 + quad*8);
    bf16x8 a2 = *(const bf16x8*)(sM1 + (2*16+nl)*264 + k0*32 + quad*8);
    const u16* wb = W2 + ((size_t)(k0*16 + ng*4)*64 + lane)*8;
    bf16x8 b0 = *(const bf16x8*)(wb);
    bf16x8 b1 = *(const bf16x8*)(wb + 512);
    bf16x8 b2 = *(const bf16x8*)(wb + 1024);
    bf16x8 b3 = *(const bf16x8*)(wb + 1536);
    acc2[0][0]=__builtin_amdgcn_mfma_f32_16x16x32_bf16(a0,b0,acc2[0][0],0,0,0);
    acc2[0][1]=__builtin_amdgcn_mfma_f32_16x16x32_bf16(a0,b1,acc2[0][1],0,0,0);
    acc2[0][2]=__builtin_amdgcn_mfma_f32_16x16x32_bf16(a0,b2,acc2[0][2],0,0,0);
    acc2[0][3]=__builtin_amdgcn_mfma_f32_16x16x32_bf16(a0,b3,acc2[0][3],0,0,0);
    acc2[1][0]=__builtin_amdgcn_mfma_f32_16x16x32_bf16(a1,b0,acc2[1][0],0,0,0);
    acc2[1][1]=__builtin_amdgcn_mfma_f32_16x16x32_bf16(a1,b1,acc2[1][1],0,0,0);
    acc2[1][2]=__builtin_amdgcn_mfma_f32_16x16x32_bf16(a1,b2,acc2[1][2],0,0,0);
    acc2[1][3]=__builtin_amdgcn_mfma_f32_16x16x32_bf16(a1,b3,acc2[1][3],0,0,0);
    acc2[2][0]=__builtin_amdgcn_mfma_f32_16x16x32_bf16(a2,b0,acc2[2][0],0,0,0);
    acc2[2][1]=__builtin_amdgcn_mfma_f32_16x16x32_bf16(a2,b1,acc2[2][1],0,0,0);
    acc2[2][2]=__builtin_amdgcn_mfma_f32_16x16x32_bf16(a2,b2,acc2[2][2],0,0,0);
    acc2[2][3]=__builtin_amdgcn_mfma_f32_16x16x32_bf16(a2,b3,acc2[2][3],0,0,0);
  }
  #pragma unroll
  for (int mt=0;mt<3;mt++)
  #pragma unroll
  for (int nt=0;nt<4;nt++){
    int n = ng*64 + nt*16 + nl;
    float bb = B2[l*HID + n];
    #pragma unroll
    for (int r=0;r<4;r++){
      int m = mt*16 + quad*4 + r;
      sM2[m*264 + n] = f2b(silu_f(acc2[mt][nt][r] + bb));
    }
  }
  __syncthreads();
  if (tid < 192){
    int e = tid >> 2, qq = tid & 3;
    float s = 0.f; int nb = qq*64;
    #pragma unroll 4
    for (int n=0;n<64;n++) s += b2f(sM2[e*264 + nb + n])*cW3[l*HID + nb + n];
    sDot[e][qq] = s;
  }
  __syncthreads();
  if (tid < 48) sS[tid] = sDot[tid][0]+sDot[tid][1]+sDot[tid][2]+sDot[tid][3];
  __syncthreads();
  if (tid < 3){
    float u = 0.f;
    #pragma unroll 4
    for (int e=0;e<48;e++) u += sCd[e*3+tid]*sS[e];
    xn[row*3+tid] = xc[row*3+tid] + u/5.0f;
  }
}

// ---- outputs ----
__global__ void k_outx(const float* __restrict__ x, const float* __restrict__ posw,
                       float* __restrict__ out)
{
  int i=blockIdx.x*1024+threadIdx.x;
  if (i<3072) out[i]=x[i]*posw[0];
}

__global__ __launch_bounds__(256) void k_outh(const float* __restrict__ h,
    const float* __restrict__ Wout, const float* __restrict__ bout,
    float* __restrict__ out)
{
  __shared__ float sH[2048];
  int blk=blockIdx.x, tid=threadIdx.x;
  int n0=blk*8;
  for (int x=tid;x<2048;x+=256) sH[x]=h[(size_t)n0*HID+x];
  __syncthreads();
  int nl=tid>>5, j=tid&31;
  float acc=bout[j];
  #pragma unroll 4
  for (int k=0;k<256;k++) acc += sH[nl*HID+k]*Wout[k*32+j];
  out[3072 + (n0+nl)*32 + j]=acc;
}

extern "C" void kernel_launch(void* const* d_in, const int* in_sizes, int n_in,
                              void* d_out, int out_size, void* d_ws, size_t ws_size,
                              hipStream_t stream)
{
  const float* protPos = (const float*)d_in[0];
  const int*   protEle = (const int*)d_in[1];
  const int*   protAA  = (const int*)d_in[2];
  const int*   protBB  = (const int*)d_in[3];
  const float* XtPos   = (const float*)d_in[4];
  const float* XtFeat  = (const float*)d_in[5];
  const int*   tArr    = (const int*)d_in[6];
  const float* WtTime  = (const float*)d_in[7];
  const float* Wele    = (const float*)d_in[8];
  const float* Waa     = (const float*)d_in[9];
  const float* Wbb     = (const float*)d_in[10];
  const float* Win     = (const float*)d_in[11];
  const float* bin     = (const float*)d_in[12];
  const float* Wout    = (const float*)d_in[13];
  const float* bout    = (const float*)d_in[14];
  const float* eW1     = (const float*)d_in[15];
  const float* eB1     = (const float*)d_in[16];
  const float* eW2     = (const float*)d_in[17];
  const float* eB2     = (const float*)d_in[18];
  const float* attW    = (const float*)d_in[19];
  const float* attB    = (const float*)d_in[20];
  const float* nW1     = (const float*)d_in[21];
  const float* nB1     = (const float*)d_in[22];
  const float* nW2     = (const float*)d_in[23];
  const float* nB2     = (const float*)d_in[24];
  const float* cW1     = (const float*)d_in[25];
  const float* cB1     = (const float*)d_in[26];
  const float* cW2     = (const float*)d_in[27];
  const float* cB2     = (const float*)d_in[28];
  const float* cW3     = (const float*)d_in[29];
  const float* posw    = (const float*)d_in[30];

  float* fp = (float*)d_ws;
  float* X0   = fp;               fp += NTOT*3;
  float* X1   = fp;               fp += NTOT*3;
  float* feats= fp;               fp += NTOT*40;
  float* h    = fp;               fp += (size_t)NTOT*HID;
  float* emb0 = fp;               fp += (size_t)ETOT*12;
  float* R    = fp;               fp += (size_t)N_LIGC*HID;
  int*   col  = (int*)fp;         fp += ETOT;
  u16*   up   = (u16*)fp;
  u16* h_bf   = up;               up += (size_t)NTOT*HID;
  u16* agg_bf = up;               up += (size_t)N_LIGC*HID;
  u16* Qb     = up;               up += (size_t)NTOT*HID;
  u16* eW1abP = up;               up += (size_t)DEPTHC*512*HID;
  u16* eW1cP  = up;               up += (size_t)DEPTHC*32*HID;
  u16* eW2p   = up;               up += (size_t)DEPTHC*HID*HID;
  u16* nW1p   = up;               up += (size_t)DEPTHC*512*HID;
  u16* nW2p   = up;               up += (size_t)DEPTHC*HID*HID;
  u16* cW1abP = up;               up += (size_t)DEPTHC*512*HID;
  u16* cW1cP  = up;               up += (size_t)DEPTHC*32*HID;
  u16* cW2p   = up;               up += (size_t)DEPTHC*HID*HID;

  {
    int tab = DEPTHC*512*HID/8;   // 81920
    int tc  = DEPTHC*32*HID/8;    // 5120
    int t2  = DEPTHC*HID*HID/8;   // 40960
    k_convw<<<(tab+255)/256,256,0,stream>>>(eW1, eW1abP, 536, 0, 512, 512, HID, tab);
    k_convw<<<(tc +255)/256,256,0,stream>>>(eW1, eW1cP,  536, 512, 24, 32, HID, tc);
    k_convw<<<(t2 +255)/256,256,0,stream>>>(eW2, eW2p,   256, 0, 256, 256, HID, t2);
    k_convw<<<(tab+255)/256,256,0,stream>>>(nW1, nW1p,   512, 0, 512, 512, HID, tab);
    k_convw<<<(t2 +255)/256,256,0,stream>>>(nW2, nW2p,   256, 0, 256, 256, HID, t2);
    k_convw<<<(tab+255)/256,256,0,stream>>>(cW1, cW1abP, 536, 0, 512, 512, HID, tab);
    k_convw<<<(tc +255)/256,256,0,stream>>>(cW1, cW1cP,  536, 512, 24, 32, HID, tc);
    k_convw<<<(t2 +255)/256,256,0,stream>>>(cW2, cW2p,   256, 0, 256, 256, HID, t2);
  }

  k_embed<<<36,256,0,stream>>>(protPos,protEle,protAA,protBB,XtPos,XtFeat,tArr,
                               WtTime,Wele,Waa,Wbb,feats,X0,X1);
  k_hinit<<<NTOT/8,256,0,stream>>>(feats,Win,bin,h,h_bf);
  k_knn<<<N_LIGC,256,0,stream>>>(X0,col,emb0);

  float* xc = X0; float* xn = X1;
  for (int l=0;l<DEPTHC;l++){
    k_pq<<<NTOT/32,256,0,stream>>>(h_bf,eW1abP,R,Qb,l);
    k_comb_edge<<<N_LIGC,256,0,stream>>>(Qb,R,xc,col,emb0,eW1cP,eB1,eW2p,eB2,attW,attB,agg_bf,l);
    k_node<<<NTOT/32,256,0,stream>>>(h,h_bf,agg_bf,nW1p,nB1,nW2p,nB2,l);
    k_pq<<<NTOT/32,256,0,stream>>>(h_bf,cW1abP,R,Qb,l);
    k_comb_coord<<<N_LIGC,256,0,stream>>>(Qb,R,xc,xn,col,emb0,cW1cP,cB1,cW2p,cB2,cW3,l);
    float* t2=xc; xc=xn; xn=t2;
  }
  k_outx<<<3,1024,0,stream>>>(xc,posw,(float*)d_out);
  k_outh<<<N_LIGC/8,256,0,stream>>>(h,Wout,bout,(float*)d_out);
}

// Round 5
// 800.127 us; speedup vs baseline: 1.1725x; 1.1088x over previous
//
#include <hip/hip_runtime.h>
#include <hip/hip_bf16.h>
#include <math.h>

#define N_LIGC 1024
#define NTOT 9216
#define KNN 48
#define HID 256
#define DEPTHC 5
#define ETOT (N_LIGC*KNN)
#define KBINS 4096

typedef unsigned short u16;
typedef __attribute__((ext_vector_type(8))) short bf16x8;
typedef __attribute__((ext_vector_type(4))) float f32x4;

__device__ __forceinline__ float freq_f(int i){
  double p = (double)(1 << (2*i));
  return (float)((2.0*3.14159265358979323846)*p/15.0);
}
__device__ __forceinline__ float silu_f(float v){ return v/(1.0f+expf(-v)); }
__device__ __forceinline__ u16 f2b(float f){
  union { __hip_bfloat16 h; u16 u; } c; c.h = __float2bfloat16(f); return c.u;
}
__device__ __forceinline__ float b2f(u16 u){
  union { unsigned int i; float f; } c; c.i = ((unsigned int)u)<<16; return c.f;
}

// ---- pack helper: fp32 [L][srcK][N] rows [kOff,kOff+Keff) -> bf16 B-frag layout
__device__ __forceinline__ void pack_one(const float* __restrict__ src,
    u16* __restrict__ dst, int srcK, int kOff, int Keff, int Kp, int N, int idx)
{
  int lane = idx & 63;
  int rest = idx >> 6;
  int Nt = N >> 4;
  int n0 = rest % Nt;
  int rest2 = rest / Nt;
  int Kt = Kp >> 5;
  int k0 = rest2 % Kt;
  int layer = rest2 / Kt;
  int kq = lane >> 4, nl = lane & 15;
  int kb = k0*32 + kq*8, n = n0*16 + nl;
  u16 o[8];
  #pragma unroll
  for (int j=0;j<8;j++){
    int k = kb + j;
    float v = (k < Keff) ? src[((size_t)layer*srcK + kOff + k)*N + n] : 0.f;
    o[j] = f2b(v);
  }
  *(uint4*)(dst + (size_t)idx*8) = *(uint4*)o;
}

// one kernel packs everything (segments laid out back to back)
__global__ __launch_bounds__(256) void k_packall(
    const float* eW1, const float* eW2, const float* nW1, const float* nW2,
    const float* cW1, const float* cW2, const float* Wout,
    u16* eW1abP, u16* eW1cP, u16* eW2p, u16* nW1p, u16* nW2p,
    u16* cW1abP, u16* cW1cP, u16* cW2p, u16* WoutP)
{
  int idx = blockIdx.x*256 + threadIdx.x;
  if (idx < 81920){ pack_one(eW1, eW1abP, 536, 0,   512, 512, 256, idx); return; } idx -= 81920;
  if (idx < 5120 ){ pack_one(eW1, eW1cP,  536, 512, 24,  32,  256, idx); return; } idx -= 5120;
  if (idx < 40960){ pack_one(eW2, eW2p,   256, 0,   256, 256, 256, idx); return; } idx -= 40960;
  if (idx < 81920){ pack_one(nW1, nW1p,   512, 0,   512, 512, 256, idx); return; } idx -= 81920;
  if (idx < 40960){ pack_one(nW2, nW2p,   256, 0,   256, 256, 256, idx); return; } idx -= 40960;
  if (idx < 81920){ pack_one(cW1, cW1abP, 536, 0,   512, 512, 256, idx); return; } idx -= 81920;
  if (idx < 5120 ){ pack_one(cW1, cW1cP,  536, 512, 24,  32,  256, idx); return; } idx -= 5120;
  if (idx < 40960){ pack_one(cW2, cW2p,   256, 0,   256, 256, 256, idx); return; } idx -= 40960;
  if (idx < 1024 ){ pack_one(Wout, WoutP, 256, 0,   256, 256, 32,  idx); return; }
}

// ---- fused embed + h-init (8 nodes/block) ----
__global__ __launch_bounds__(256) void k_embed_hinit(
    const float* __restrict__ protPos, const int* __restrict__ protEle,
    const int* __restrict__ protAA, const int* __restrict__ protBB,
    const float* __restrict__ XtPos, const float* __restrict__ XtFeat,
    const int* __restrict__ tArr, const float* __restrict__ WtTime,
    const float* __restrict__ Wele, const float* __restrict__ Waa,
    const float* __restrict__ Wbb,
    const float* __restrict__ Win, const float* __restrict__ bin,
    float* __restrict__ X0, float* __restrict__ X1,
    float* __restrict__ h, u16* __restrict__ h_bf)
{
  __shared__ float sF[8*40];
  int blk=blockIdx.x, tid=threadIdx.x;
  int n0=blk*8;
  for (int x=tid; x<344; x+=256){
    if (x < 320){
      int n = x/40, k = x%40;
      int node = n0+n;
      float v;
      if (node < N_LIGC){
        if (k < 32) v = XtFeat[node*32+k];
        else        v = WtTime[tArr[node]*8 + (k-32)];
      } else {
        int p = node - N_LIGC;
        if (k < 16)      v = Wele[protEle[p]*16 + k];
        else if (k < 32) v = Waa[protAA[p]*16 + (k-16)];
        else             v = Wbb[protBB[p]*8 + (k-32)];
      }
      sF[n*40+k] = v;
    } else {
      int r = x-320; int n = r/3, c = r%3;
      int node = n0+n;
      float v = (node < N_LIGC) ? XtPos[node*3+c] : protPos[(node-N_LIGC)*3+c];
      X0[node*3+c] = v; X1[node*3+c] = v;
    }
  }
  __syncthreads();
  float acc[8];
  float b=bin[tid];
  #pragma unroll
  for (int n=0;n<8;n++) acc[n]=b;
  for (int k=0;k<40;k++){
    float w=Win[k*HID+tid];
    #pragma unroll
    for (int n=0;n<8;n++) acc[n]+=sF[n*40+k]*w;
  }
  #pragma unroll
  for (int n=0;n<8;n++){
    h[(size_t)(n0+n)*HID+tid]=acc[n];
    h_bf[(size_t)(n0+n)*HID+tid]=f2b(acc[n]);
  }
}

// ---- KNN: radix-histogram top-K, LDS-light (recompute d2 in pass 2) ----
__global__ __launch_bounds__(256) void k_knn(const float* __restrict__ X,
    int* __restrict__ col, float* __restrict__ emb0)
{
  __shared__ unsigned int hist[KBINS];
  __shared__ unsigned int part[256];
  __shared__ float selD[KNN];
  __shared__ int   candI[512];
  __shared__ float candV[512];
  __shared__ int sB, sCless, sNeed, sNsel, sNcand;
  int b = blockIdx.x, tid = threadIdx.x;
  for (int i=tid;i<KBINS;i+=256) hist[i]=0u;
  if (tid==0){ sNsel=0; sNcand=0; }
  float px = X[b*3+0], py = X[b*3+1], pz = X[b*3+2];
  __syncthreads();
  #pragma unroll 4
  for (int j=0;j<36;j++){
    int i = tid + 256*j;
    float dx = __fsub_rn(px, X[i*3+0]);
    float dy = __fsub_rn(py, X[i*3+1]);
    float dz = __fsub_rn(pz, X[i*3+2]);
    float d2 = __fadd_rn(__fadd_rn(__fmul_rn(dx,dx),__fmul_rn(dy,dy)),__fmul_rn(dz,dz));
    if (i==b) d2 = INFINITY;
    unsigned key = __float_as_uint(d2) >> 19;
    atomicAdd(&hist[key], 1u);
  }
  __syncthreads();
  {
    unsigned s=0;
    #pragma unroll 4
    for (int k=0;k<16;k++) s += hist[tid*16+k];
    part[tid]=s;
  }
  __syncthreads();
  if (tid==0){
    unsigned c=0; int chunk=0;
    for (int t=0;t<256;t++){
      if (c + part[t] >= (unsigned)KNN){ chunk=t; break; }
      c += part[t];
    }
    int bin = chunk*16;
    for (;;bin++){
      unsigned hh = hist[bin];
      if (c + hh >= (unsigned)KNN) break;
      c += hh;
    }
    sB = bin; sCless = (int)c; sNeed = KNN - (int)c;
  }
  __syncthreads();
  int B = sB;
  #pragma unroll 4
  for (int j=0;j<36;j++){
    int i = tid + 256*j;
    float dx = __fsub_rn(px, X[i*3+0]);
    float dy = __fsub_rn(py, X[i*3+1]);
    float dz = __fsub_rn(pz, X[i*3+2]);
    float d2 = __fadd_rn(__fadd_rn(__fmul_rn(dx,dx),__fmul_rn(dy,dy)),__fmul_rn(dz,dz));
    if (i==b) d2 = INFINITY;
    int key = (int)(__float_as_uint(d2) >> 19);
    if (key < B){
      int p = atomicAdd(&sNsel, 1);
      col[b*KNN+p] = i; selD[p] = d2;
    } else if (key == B){
      int c = atomicAdd(&sNcand, 1);
      if (c < 512){ candI[c] = i; candV[c] = d2; }
    }
  }
  __syncthreads();
  if (tid < 64){
    int m = sNcand; if (m > 512) m = 512;
    int need = sNeed, base = sCless;
    float cv[8]; int ci[8];
    #pragma unroll
    for (int k=0;k<8;k++){
      int c = tid + 64*k;
      if (c < m){ ci[k]=candI[c]; cv[k]=candV[c]; }
      else      { ci[k]=0x7fffffff; cv[k]=INFINITY; }
    }
    for (int it=0; it<need; it++){
      float bv=INFINITY; int bi=0x7fffffff; int bk=0;
      #pragma unroll
      for (int k=0;k<8;k++){
        if (cv[k]<bv || (cv[k]==bv && ci[k]<bi)){ bv=cv[k]; bi=ci[k]; bk=k; }
      }
      int bslot = tid + 64*bk;
      #pragma unroll
      for (int off=32; off>=1; off>>=1){
        float ov = __shfl_down(bv, off);
        int   oi = __shfl_down(bi, off);
        int   os = __shfl_down(bslot, off);
        if (ov < bv || (ov==bv && oi<bi)){ bv=ov; bi=oi; bslot=os; }
      }
      int wslot = __shfl(bslot, 0);
      if (tid==0){ col[b*KNN+base+it]=bi; selD[base+it]=bv; }
      if ((wslot & 63) == tid) cv[wslot >> 6] = INFINITY;
    }
  }
  __syncthreads();
  if (tid < KNN){
    float d = sqrtf(selD[tid] + 1e-8f);
    int base = (b*KNN+tid)*12;
    #pragma unroll
    for (int i=0;i<6;i++){
      float fr = freq_f(i);
      emb0[base+i]   = sinf(d*fr);
      emb0[base+6+i] = cosf(d*fr);
    }
  }
}

// ---- k_pq: initial Q/R for layer 0 edge stage ----
__global__ __launch_bounds__(256) void k_pq(const u16* __restrict__ h_bf,
    const u16* __restrict__ Wab, float* __restrict__ R, u16* __restrict__ Qb, int l)
{
  __shared__ __align__(16) u16 sA[32*264];
  int blk=blockIdx.x, tid=threadIdx.x;
  int lane=tid&63, ng=tid>>6, quad=lane>>4, nl=lane&15;
  for (int t=tid; t<32*32; t+=256){
    int i=t>>5, q=t&31;
    uint4 v = ((const uint4*)(h_bf + (size_t)(blk*32+i)*HID))[q];
    *(uint4*)(sA + i*264 + q*8) = v;
  }
  __syncthreads();
  const u16* Wl = Wab + (size_t)l*512*HID;
  f32x4 zero4 = {0.f,0.f,0.f,0.f};
  f32x4 aQ[2][4];
  #pragma unroll
  for (int i=0;i<2;i++){ aQ[i][0]=zero4; aQ[i][1]=zero4; aQ[i][2]=zero4; aQ[i][3]=zero4; }
  #pragma unroll 2
  for (int k0=0;k0<8;k0++){
    bf16x8 a0 = *(const bf16x8*)(sA + (0*16+nl)*264 + k0*32 + quad*8);
    bf16x8 a1 = *(const bf16x8*)(sA + (1*16+nl)*264 + k0*32 + quad*8);
    const u16* wb = Wl + ((size_t)((k0+8)*16 + ng*4)*64 + lane)*8;
    bf16x8 b0 = *(const bf16x8*)(wb);
    bf16x8 b1 = *(const bf16x8*)(wb + 512);
    bf16x8 b2 = *(const bf16x8*)(wb + 1024);
    bf16x8 b3 = *(const bf16x8*)(wb + 1536);
    aQ[0][0]=__builtin_amdgcn_mfma_f32_16x16x32_bf16(a0,b0,aQ[0][0],0,0,0);
    aQ[0][1]=__builtin_amdgcn_mfma_f32_16x16x32_bf16(a0,b1,aQ[0][1],0,0,0);
    aQ[0][2]=__builtin_amdgcn_mfma_f32_16x16x32_bf16(a0,b2,aQ[0][2],0,0,0);
    aQ[0][3]=__builtin_amdgcn_mfma_f32_16x16x32_bf16(a0,b3,aQ[0][3],0,0,0);
    aQ[1][0]=__builtin_amdgcn_mfma_f32_16x16x32_bf16(a1,b0,aQ[1][0],0,0,0);
    aQ[1][1]=__builtin_amdgcn_mfma_f32_16x16x32_bf16(a1,b1,aQ[1][1],0,0,0);
    aQ[1][2]=__builtin_amdgcn_mfma_f32_16x16x32_bf16(a1,b2,aQ[1][2],0,0,0);
    aQ[1][3]=__builtin_amdgcn_mfma_f32_16x16x32_bf16(a1,b3,aQ[1][3],0,0,0);
  }
  #pragma unroll
  for (int mt=0;mt<2;mt++)
  #pragma unroll
  for (int nt=0;nt<4;nt++){
    int n = ng*64 + nt*16 + nl;
    #pragma unroll
    for (int r=0;r<4;r++){
      int node = blk*32 + mt*16 + quad*4 + r;
      Qb[(size_t)node*HID + n] = f2b(aQ[mt][nt][r]);
    }
  }
  if (blk < 32){
    f32x4 aR[2][4];
    #pragma unroll
    for (int i=0;i<2;i++){ aR[i][0]=zero4; aR[i][1]=zero4; aR[i][2]=zero4; aR[i][3]=zero4; }
    #pragma unroll 2
    for (int k0=0;k0<8;k0++){
      bf16x8 a0 = *(const bf16x8*)(sA + (0*16+nl)*264 + k0*32 + quad*8);
      bf16x8 a1 = *(const bf16x8*)(sA + (1*16+nl)*264 + k0*32 + quad*8);
      const u16* wb = Wl + ((size_t)(k0*16 + ng*4)*64 + lane)*8;
      bf16x8 b0 = *(const bf16x8*)(wb);
      bf16x8 b1 = *(const bf16x8*)(wb + 512);
      bf16x8 b2 = *(const bf16x8*)(wb + 1024);
      bf16x8 b3 = *(const bf16x8*)(wb + 1536);
      aR[0][0]=__builtin_amdgcn_mfma_f32_16x16x32_bf16(a0,b0,aR[0][0],0,0,0);
      aR[0][1]=__builtin_amdgcn_mfma_f32_16x16x32_bf16(a0,b1,aR[0][1],0,0,0);
      aR[0][2]=__builtin_amdgcn_mfma_f32_16x16x32_bf16(a0,b2,aR[0][2],0,0,0);
      aR[0][3]=__builtin_amdgcn_mfma_f32_16x16x32_bf16(a0,b3,aR[0][3],0,0,0);
      aR[1][0]=__builtin_amdgcn_mfma_f32_16x16x32_bf16(a1,b0,aR[1][0],0,0,0);
      aR[1][1]=__builtin_amdgcn_mfma_f32_16x16x32_bf16(a1,b1,aR[1][1],0,0,0);
      aR[1][2]=__builtin_amdgcn_mfma_f32_16x16x32_bf16(a1,b2,aR[1][2],0,0,0);
      aR[1][3]=__builtin_amdgcn_mfma_f32_16x16x32_bf16(a1,b3,aR[1][3],0,0,0);
    }
    #pragma unroll
    for (int mt=0;mt<2;mt++)
    #pragma unroll
    for (int nt=0;nt<4;nt++){
      int n = ng*64 + nt*16 + nl;
      #pragma unroll
      for (int r=0;r<4;r++){
        int node = blk*32 + mt*16 + quad*4 + r;
        R[(size_t)node*HID + n] = aR[mt][nt][r];
      }
    }
  }
}

// ---- edge combine ----
__global__ __launch_bounds__(256) void k_comb_edge(
    const u16* __restrict__ Qb, const float* __restrict__ R,
    const float* __restrict__ xc,
    const int* __restrict__ colIdx, const float* __restrict__ emb0,
    const u16* __restrict__ W1cP, const float* __restrict__ B1,
    const u16* __restrict__ W2p, const float* __restrict__ B2,
    const float* __restrict__ attW, const float* __restrict__ attB,
    u16* __restrict__ agg_bf, int l)
{
  __shared__ __align__(16) u16 sQ[48*264];
  __shared__ __align__(16) u16 sEA[48*40];
  __shared__ __align__(16) u16 sM1[48*264];
  __shared__ float sR[256];
  __shared__ int sCol[48];
  __shared__ float sSig[48];
  __shared__ float sDot[48][4];
  u16* sM2 = sQ;

  int row = blockIdx.x, tid = threadIdx.x;
  int lane = tid & 63, ng = tid >> 6;
  int quad = lane >> 4, nl = lane & 15;

  if (tid < 48) sCol[tid] = colIdx[(size_t)row*KNN + tid];
  sR[tid] = R[(size_t)row*HID + tid];
  __syncthreads();
  for (int t = tid; t < 48*32; t += 256){
    int e = t >> 5, q = t & 31;
    uint4 v = ((const uint4*)(Qb + (size_t)sCol[e]*HID))[q];
    *(uint4*)(sQ + e*264 + q*8) = v;
  }
  if (tid < 48){
    int cg = sCol[tid];
    float dx = xc[row*3+0]-xc[cg*3+0];
    float dy = xc[row*3+1]-xc[cg*3+1];
    float dz = xc[row*3+2]-xc[cg*3+2];
    float d = sqrtf(dx*dx+dy*dy+dz*dz + 1e-8f);
    u16* ea = sEA + tid*40;
    #pragma unroll
    for (int i=0;i<6;i++){
      float fr = freq_f(i);
      ea[i]   = f2b(sinf(d*fr));
      ea[6+i] = f2b(cosf(d*fr));
    }
    #pragma unroll
    for (int i=0;i<12;i++) ea[12+i] = f2b(emb0[((size_t)row*KNN + tid)*12 + i]);
    #pragma unroll
    for (int i=24;i<32;i++) ea[i] = 0;
  }
  __syncthreads();

  f32x4 zero4 = {0.f,0.f,0.f,0.f};
  f32x4 acc[3][4];
  #pragma unroll
  for (int i=0;i<3;i++){ acc[i][0]=zero4; acc[i][1]=zero4; acc[i][2]=zero4; acc[i][3]=zero4; }
  {
    const u16* Wc = W1cP + (size_t)l*32*HID;
    const u16* wb = Wc + ((size_t)(ng*4)*64 + lane)*8;
    bf16x8 b0 = *(const bf16x8*)(wb);
    bf16x8 b1 = *(const bf16x8*)(wb + 512);
    bf16x8 b2 = *(const bf16x8*)(wb + 1024);
    bf16x8 b3 = *(const bf16x8*)(wb + 1536);
    bf16x8 a0 = *(const bf16x8*)(sEA + (0*16+nl)*40 + quad*8);
    bf16x8 a1 = *(const bf16x8*)(sEA + (1*16+nl)*40 + quad*8);
    bf16x8 a2 = *(const bf16x8*)(sEA + (2*16+nl)*40 + quad*8);
    acc[0][0]=__builtin_amdgcn_mfma_f32_16x16x32_bf16(a0,b0,acc[0][0],0,0,0);
    acc[0][1]=__builtin_amdgcn_mfma_f32_16x16x32_bf16(a0,b1,acc[0][1],0,0,0);
    acc[0][2]=__builtin_amdgcn_mfma_f32_16x16x32_bf16(a0,b2,acc[0][2],0,0,0);
    acc[0][3]=__builtin_amdgcn_mfma_f32_16x16x32_bf16(a0,b3,acc[0][3],0,0,0);
    acc[1][0]=__builtin_amdgcn_mfma_f32_16x16x32_bf16(a1,b0,acc[1][0],0,0,0);
    acc[1][1]=__builtin_amdgcn_mfma_f32_16x16x32_bf16(a1,b1,acc[1][1],0,0,0);
    acc[1][2]=__builtin_amdgcn_mfma_f32_16x16x32_bf16(a1,b2,acc[1][2],0,0,0);
    acc[1][3]=__builtin_amdgcn_mfma_f32_16x16x32_bf16(a1,b3,acc[1][3],0,0,0);
    acc[2][0]=__builtin_amdgcn_mfma_f32_16x16x32_bf16(a2,b0,acc[2][0],0,0,0);
    acc[2][1]=__builtin_amdgcn_mfma_f32_16x16x32_bf16(a2,b1,acc[2][1],0,0,0);
    acc[2][2]=__builtin_amdgcn_mfma_f32_16x16x32_bf16(a2,b2,acc[2][2],0,0,0);
    acc[2][3]=__builtin_amdgcn_mfma_f32_16x16x32_bf16(a2,b3,acc[2][3],0,0,0);
  }
  #pragma unroll
  for (int mt=0;mt<3;mt++)
  #pragma unroll
  for (int nt=0;nt<4;nt++){
    int n = ng*64 + nt*16 + nl;
    float bb = B1[l*HID + n] + sR[n];
    #pragma unroll
    for (int r=0;r<4;r++){
      int m = mt*16 + quad*4 + r;
      float v = acc[mt][nt][r] + bb + b2f(sQ[m*264 + n]);
      sM1[m*264 + n] = f2b(silu_f(v));
    }
  }
  __syncthreads();

  f32x4 acc2[3][4];
  #pragma unroll
  for (int i=0;i<3;i++){ acc2[i][0]=zero4; acc2[i][1]=zero4; acc2[i][2]=zero4; acc2[i][3]=zero4; }
  const u16* W2 = W2p + (size_t)l*HID*HID;
  #pragma unroll 2
  for (int k0=0;k0<8;k0++){
    bf16x8 a0 = *(const bf16x8*)(sM1 + (0*16+nl)*264 + k0*32 + quad*8);
    bf16x8 a1 = *(const bf16x8*)(sM1 + (1*16+nl)*264 + k0*32 + quad*8);
    bf16x8 a2 = *(const bf16x8*)(sM1 + (2*16+nl)*264 + k0*32 + quad*8);
    const u16* wb = W2 + ((size_t)(k0*16 + ng*4)*64 + lane)*8;
    bf16x8 b0 = *(const bf16x8*)(wb);
    bf16x8 b1 = *(const bf16x8*)(wb + 512);
    bf16x8 b2 = *(const bf16x8*)(wb + 1024);
    bf16x8 b3 = *(const bf16x8*)(wb + 1536);
    acc2[0][0]=__builtin_amdgcn_mfma_f32_16x16x32_bf16(a0,b0,acc2[0][0],0,0,0);
    acc2[0][1]=__builtin_amdgcn_mfma_f32_16x16x32_bf16(a0,b1,acc2[0][1],0,0,0);
    acc2[0][2]=__builtin_amdgcn_mfma_f32_16x16x32_bf16(a0,b2,acc2[0][2],0,0,0);
    acc2[0][3]=__builtin_amdgcn_mfma_f32_16x16x32_bf16(a0,b3,acc2[0][3],0,0,0);
    acc2[1][0]=__builtin_amdgcn_mfma_f32_16x16x32_bf16(a1,b0,acc2[1][0],0,0,0);
    acc2[1][1]=__builtin_amdgcn_mfma_f32_16x16x32_bf16(a1,b1,acc2[1][1],0,0,0);
    acc2[1][2]=__builtin_amdgcn_mfma_f32_16x16x32_bf16(a1,b2,acc2[1][2],0,0,0);
    acc2[1][3]=__builtin_amdgcn_mfma_f32_16x16x32_bf16(a1,b3,acc2[1][3],0,0,0);
    acc2[2][0]=__builtin_amdgcn_mfma_f32_16x16x32_bf16(a2,b0,acc2[2][0],0,0,0);
    acc2[2][1]=__builtin_amdgcn_mfma_f32_16x16x32_bf16(a2,b1,acc2[2][1],0,0,0);
    acc2[2][2]=__builtin_amdgcn_mfma_f32_16x16x32_bf16(a2,b2,acc2[2][2],0,0,0);
    acc2[2][3]=__builtin_amdgcn_mfma_f32_16x16x32_bf16(a2,b3,acc2[2][3],0,0,0);
  }
  #pragma unroll
  for (int mt=0;mt<3;mt++)
  #pragma unroll
  for (int nt=0;nt<4;nt++){
    int n = ng*64 + nt*16 + nl;
    float bb = B2[l*HID + n];
    #pragma unroll
    for (int r=0;r<4;r++){
      int m = mt*16 + quad*4 + r;
      sM2[m*264 + n] = f2b(silu_f(acc2[mt][nt][r] + bb));
    }
  }
  __syncthreads();
  if (tid < 192){
    int e = tid >> 2, qq = tid & 3;
    float s = 0.f; int nb = qq*64;
    #pragma unroll 4
    for (int n=0;n<64;n++){
      int nn = nb + ((n + e) & 63);
      s += b2f(sM2[e*264 + nn])*attW[l*HID + nn];
    }
    sDot[e][qq] = s;
  }
  __syncthreads();
  if (tid < 48){
    float s = sDot[tid][0]+sDot[tid][1]+sDot[tid][2]+sDot[tid][3] + attB[l];
    sSig[tid] = 1.f/(1.f+expf(-s));
  }
  __syncthreads();
  {
    float a = 0.f;
    #pragma unroll 4
    for (int e=0;e<48;e++) a += b2f(sM2[e*264 + tid])*sSig[e];
    agg_bf[(size_t)row*HID + tid] = f2b(a/5.0f);
  }
}

// ---- node MLP + residual + QC/RC (this layer coord) + QE/RE (next layer edge) + final outh ----
__global__ __launch_bounds__(256) void k_node(
    float* __restrict__ h, u16* __restrict__ h_bf,
    const u16* __restrict__ agg_bf,
    const u16* __restrict__ W1p, const float* __restrict__ B1,
    const u16* __restrict__ W2p, const float* __restrict__ B2,
    const u16* __restrict__ cWab, u16* __restrict__ QbC, float* __restrict__ RC,
    const u16* __restrict__ eWabN, u16* __restrict__ QbE, float* __restrict__ RE, int doE,
    const u16* __restrict__ WoutP, const float* __restrict__ bout,
    float* __restrict__ outH, int doOut, int l)
{
  __shared__ __align__(16) u16 sA[32*520];
  __shared__ __align__(16) u16 sU[32*264];
  u16* sH = sA;  // updated-h bf16 tile (32x264), reuses sA after stage-1
  int blk=blockIdx.x, tid=threadIdx.x;
  int lane=tid&63, wv=tid>>6, quad=lane>>4, nl=lane&15;
  for (int t=tid; t<32*64; t+=256){
    int i=t>>6, q=t&63;
    int node = blk*32+i;
    uint4 v;
    if (q<32) v = ((const uint4*)(h_bf + (size_t)node*HID))[q];
    else if (node < N_LIGC) v = ((const uint4*)(agg_bf + (size_t)node*HID))[q-32];
    else { v.x=0u; v.y=0u; v.z=0u; v.w=0u; }
    *(uint4*)(sA + i*520 + q*8) = v;
  }
  __syncthreads();
  f32x4 zero4 = {0.f,0.f,0.f,0.f};
  f32x4 acc[2][4];
  #pragma unroll
  for (int i=0;i<2;i++){ acc[i][0]=zero4; acc[i][1]=zero4; acc[i][2]=zero4; acc[i][3]=zero4; }
  const u16* Wp = W1p + (size_t)l*512*HID;
  #pragma unroll 2
  for (int k0=0;k0<16;k0++){
    bf16x8 a0 = *(const bf16x8*)(sA + (0*16+nl)*520 + k0*32 + quad*8);
    bf16x8 a1 = *(const bf16x8*)(sA + (1*16+nl)*520 + k0*32 + quad*8);
    const u16* wb = Wp + ((size_t)(k0*16 + wv*4)*64 + lane)*8;
    bf16x8 b0 = *(const bf16x8*)(wb);
    bf16x8 b1 = *(const bf16x8*)(wb + 512);
    bf16x8 b2 = *(const bf16x8*)(wb + 1024);
    bf16x8 b3 = *(const bf16x8*)(wb + 1536);
    acc[0][0]=__builtin_amdgcn_mfma_f32_16x16x32_bf16(a0,b0,acc[0][0],0,0,0);
    acc[0][1]=__builtin_amdgcn_mfma_f32_16x16x32_bf16(a0,b1,acc[0][1],0,0,0);
    acc[0][2]=__builtin_amdgcn_mfma_f32_16x16x32_bf16(a0,b2,acc[0][2],0,0,0);
    acc[0][3]=__builtin_amdgcn_mfma_f32_16x16x32_bf16(a0,b3,acc[0][3],0,0,0);
    acc[1][0]=__builtin_amdgcn_mfma_f32_16x16x32_bf16(a1,b0,acc[1][0],0,0,0);
    acc[1][1]=__builtin_amdgcn_mfma_f32_16x16x32_bf16(a1,b1,acc[1][1],0,0,0);
    acc[1][2]=__builtin_amdgcn_mfma_f32_16x16x32_bf16(a1,b2,acc[1][2],0,0,0);
    acc[1][3]=__builtin_amdgcn_mfma_f32_16x16x32_bf16(a1,b3,acc[1][3],0,0,0);
  }
  #pragma unroll
  for (int mt=0;mt<2;mt++)
  #pragma unroll
  for (int nt=0;nt<4;nt++){
    int n = wv*64 + nt*16 + nl;
    float bb = B1[l*HID + n];
    #pragma unroll
    for (int r=0;r<4;r++){
      int m = mt*16 + quad*4 + r;
      sU[m*264 + n] = f2b(silu_f(acc[mt][nt][r] + bb));
    }
  }
  __syncthreads();   // sU ready; sA now dead (stage-1 reads all done)
  f32x4 acc2[2][4];
  #pragma unroll
  for (int i=0;i<2;i++){ acc2[i][0]=zero4; acc2[i][1]=zero4; acc2[i][2]=zero4; acc2[i][3]=zero4; }
  const u16* W2 = W2p + (size_t)l*HID*HID;
  #pragma unroll 2
  for (int k0=0;k0<8;k0++){
    bf16x8 a0 = *(const bf16x8*)(sU + (0*16+nl)*264 + k0*32 + quad*8);
    bf16x8 a1 = *(const bf16x8*)(sU + (1*16+nl)*264 + k0*32 + quad*8);
    const u16* wb = W2 + ((size_t)(k0*16 + wv*4)*64 + lane)*8;
    bf16x8 b0 = *(const bf16x8*)(wb);
    bf16x8 b1 = *(const bf16x8*)(wb + 512);
    bf16x8 b2 = *(const bf16x8*)(wb + 1024);
    bf16x8 b3 = *(const bf16x8*)(wb + 1536);
    acc2[0][0]=__builtin_amdgcn_mfma_f32_16x16x32_bf16(a0,b0,acc2[0][0],0,0,0);
    acc2[0][1]=__builtin_amdgcn_mfma_f32_16x16x32_bf16(a0,b1,acc2[0][1],0,0,0);
    acc2[0][2]=__builtin_amdgcn_mfma_f32_16x16x32_bf16(a0,b2,acc2[0][2],0,0,0);
    acc2[0][3]=__builtin_amdgcn_mfma_f32_16x16x32_bf16(a0,b3,acc2[0][3],0,0,0);
    acc2[1][0]=__builtin_amdgcn_mfma_f32_16x16x32_bf16(a1,b0,acc2[1][0],0,0,0);
    acc2[1][1]=__builtin_amdgcn_mfma_f32_16x16x32_bf16(a1,b1,acc2[1][1],0,0,0);
    acc2[1][2]=__builtin_amdgcn_mfma_f32_16x16x32_bf16(a1,b2,acc2[1][2],0,0,0);
    acc2[1][3]=__builtin_amdgcn_mfma_f32_16x16x32_bf16(a1,b3,acc2[1][3],0,0,0);
  }
  // h update epilogue: write fp32 h, bf16 h_bf (global) and sH (LDS, for Q/R GEMMs)
  #pragma unroll
  for (int mt=0;mt<2;mt++)
  #pragma unroll
  for (int nt=0;nt<4;nt++){
    int n = wv*64 + nt*16 + nl;
    float bb = B2[l*HID + n];
    #pragma unroll
    for (int r=0;r<4;r++){
      int m = mt*16 + quad*4 + r;
      size_t idx = (size_t)(blk*32+m)*HID + n;
      float v = h[idx] + acc2[mt][nt][r] + bb;
      h[idx] = v;
      u16 bv = f2b(v);
      h_bf[idx] = bv;
      sH[m*264 + n] = bv;
    }
  }
  __syncthreads();

  // ---- QC = h_new @ cW1b ; RC (ligand) = h_new @ cW1a ----
  const u16* Wl = cWab + (size_t)l*512*HID;
  f32x4 q[2][4];
  #pragma unroll
  for (int i=0;i<2;i++){ q[i][0]=zero4; q[i][1]=zero4; q[i][2]=zero4; q[i][3]=zero4; }
  #pragma unroll 2
  for (int k0=0;k0<8;k0++){
    bf16x8 a0 = *(const bf16x8*)(sH + (0*16+nl)*264 + k0*32 + quad*8);
    bf16x8 a1 = *(const bf16x8*)(sH + (1*16+nl)*264 + k0*32 + quad*8);
    const u16* wb = Wl + ((size_t)((k0+8)*16 + wv*4)*64 + lane)*8;
    bf16x8 b0 = *(const bf16x8*)(wb);
    bf16x8 b1 = *(const bf16x8*)(wb + 512);
    bf16x8 b2 = *(const bf16x8*)(wb + 1024);
    bf16x8 b3 = *(const bf16x8*)(wb + 1536);
    q[0][0]=__builtin_amdgcn_mfma_f32_16x16x32_bf16(a0,b0,q[0][0],0,0,0);
    q[0][1]=__builtin_amdgcn_mfma_f32_16x16x32_bf16(a0,b1,q[0][1],0,0,0);
    q[0][2]=__builtin_amdgcn_mfma_f32_16x16x32_bf16(a0,b2,q[0][2],0,0,0);
    q[0][3]=__builtin_amdgcn_mfma_f32_16x16x32_bf16(a0,b3,q[0][3],0,0,0);
    q[1][0]=__builtin_amdgcn_mfma_f32_16x16x32_bf16(a1,b0,q[1][0],0,0,0);
    q[1][1]=__builtin_amdgcn_mfma_f32_16x16x32_bf16(a1,b1,q[1][1],0,0,0);
    q[1][2]=__builtin_amdgcn_mfma_f32_16x16x32_bf16(a1,b2,q[1][2],0,0,0);
    q[1][3]=__builtin_amdgcn_mfma_f32_16x16x32_bf16(a1,b3,q[1][3],0,0,0);
  }
  #pragma unroll
  for (int mt=0;mt<2;mt++)
  #pragma unroll
  for (int nt=0;nt<4;nt++){
    int n = wv*64 + nt*16 + nl;
    #pragma unroll
    for (int r=0;r<4;r++){
      int node = blk*32 + mt*16 + quad*4 + r;
      QbC[(size_t)node*HID + n] = f2b(q[mt][nt][r]);
    }
  }
  if (blk < 32){
    #pragma unroll
    for (int i=0;i<2;i++){ q[i][0]=zero4; q[i][1]=zero4; q[i][2]=zero4; q[i][3]=zero4; }
    #pragma unroll 2
    for (int k0=0;k0<8;k0++){
      bf16x8 a0 = *(const bf16x8*)(sH + (0*16+nl)*264 + k0*32 + quad*8);
      bf16x8 a1 = *(const bf16x8*)(sH + (1*16+nl)*264 + k0*32 + quad*8);
      const u16* wb = Wl + ((size_t)(k0*16 + wv*4)*64 + lane)*8;
      bf16x8 b0 = *(const bf16x8*)(wb);
      bf16x8 b1 = *(const bf16x8*)(wb + 512);
      bf16x8 b2 = *(const bf16x8*)(wb + 1024);
      bf16x8 b3 = *(const bf16x8*)(wb + 1536);
      q[0][0]=__builtin_amdgcn_mfma_f32_16x16x32_bf16(a0,b0,q[0][0],0,0,0);
      q[0][1]=__builtin_amdgcn_mfma_f32_16x16x32_bf16(a0,b1,q[0][1],0,0,0);
      q[0][2]=__builtin_amdgcn_mfma_f32_16x16x32_bf16(a0,b2,q[0][2],0,0,0);
      q[0][3]=__builtin_amdgcn_mfma_f32_16x16x32_bf16(a0,b3,q[0][3],0,0,0);
      q[1][0]=__builtin_amdgcn_mfma_f32_16x16x32_bf16(a1,b0,q[1][0],0,0,0);
      q[1][1]=__builtin_amdgcn_mfma_f32_16x16x32_bf16(a1,b1,q[1][1],0,0,0);
      q[1][2]=__builtin_amdgcn_mfma_f32_16x16x32_bf16(a1,b2,q[1][2],0,0,0);
      q[1][3]=__builtin_amdgcn_mfma_f32_16x16x32_bf16(a1,b3,q[1][3],0,0,0);
    }
    #pragma unroll
    for (int mt=0;mt<2;mt++)
    #pragma unroll
    for (int nt=0;nt<4;nt++){
      int n = wv*64 + nt*16 + nl;
      #pragma unroll
      for (int r=0;r<4;r++){
        int node = blk*32 + mt*16 + quad*4 + r;
        RC[(size_t)node*HID + n] = q[mt][nt][r];
      }
    }
  }
  // ---- QE/RE for next layer's edge stage ----
  if (doE){
    #pragma unroll
    for (int i=0;i<2;i++){ q[i][0]=zero4; q[i][1]=zero4; q[i][2]=zero4; q[i][3]=zero4; }
    #pragma unroll 2
    for (int k0=0;k0<8;k0++){
      bf16x8 a0 = *(const bf16x8*)(sH + (0*16+nl)*264 + k0*32 + quad*8);
      bf16x8 a1 = *(const bf16x8*)(sH + (1*16+nl)*264 + k0*32 + quad*8);
      const u16* wb = eWabN + ((size_t)((k0+8)*16 + wv*4)*64 + lane)*8;
      bf16x8 b0 = *(const bf16x8*)(wb);
      bf16x8 b1 = *(const bf16x8*)(wb + 512);
      bf16x8 b2 = *(const bf16x8*)(wb + 1024);
      bf16x8 b3 = *(const bf16x8*)(wb + 1536);
      q[0][0]=__builtin_amdgcn_mfma_f32_16x16x32_bf16(a0,b0,q[0][0],0,0,0);
      q[0][1]=__builtin_amdgcn_mfma_f32_16x16x32_bf16(a0,b1,q[0][1],0,0,0);
      q[0][2]=__builtin_amdgcn_mfma_f32_16x16x32_bf16(a0,b2,q[0][2],0,0,0);
      q[0][3]=__builtin_amdgcn_mfma_f32_16x16x32_bf16(a0,b3,q[0][3],0,0,0);
      q[1][0]=__builtin_amdgcn_mfma_f32_16x16x32_bf16(a1,b0,q[1][0],0,0,0);
      q[1][1]=__builtin_amdgcn_mfma_f32_16x16x32_bf16(a1,b1,q[1][1],0,0,0);
      q[1][2]=__builtin_amdgcn_mfma_f32_16x16x32_bf16(a1,b2,q[1][2],0,0,0);
      q[1][3]=__builtin_amdgcn_mfma_f32_16x16x32_bf16(a1,b3,q[1][3],0,0,0);
    }
    #pragma unroll
    for (int mt=0;mt<2;mt++)
    #pragma unroll
    for (int nt=0;nt<4;nt++){
      int n = wv*64 + nt*16 + nl;
      #pragma unroll
      for (int r=0;r<4;r++){
        int node = blk*32 + mt*16 + quad*4 + r;
        QbE[(size_t)node*HID + n] = f2b(q[mt][nt][r]);
      }
    }
    if (blk < 32){
      #pragma unroll
      for (int i=0;i<2;i++){ q[i][0]=zero4; q[i][1]=zero4; q[i][2]=zero4; q[i][3]=zero4; }
      #pragma unroll 2
      for (int k0=0;k0<8;k0++){
        bf16x8 a0 = *(const bf16x8*)(sH + (0*16+nl)*264 + k0*32 + quad*8);
        bf16x8 a1 = *(const bf16x8*)(sH + (1*16+nl)*264 + k0*32 + quad*8);
        const u16* wb = eWabN + ((size_t)(k0*16 + wv*4)*64 + lane)*8;
        bf16x8 b0 = *(const bf16x8*)(wb);
        bf16x8 b1 = *(const bf16x8*)(wb + 512);
        bf16x8 b2 = *(const bf16x8*)(wb + 1024);
        bf16x8 b3 = *(const bf16x8*)(wb + 1536);
        q[0][0]=__builtin_amdgcn_mfma_f32_16x16x32_bf16(a0,b0,q[0][0],0,0,0);
        q[0][1]=__builtin_amdgcn_mfma_f32_16x16x32_bf16(a0,b1,q[0][1],0,0,0);
        q[0][2]=__builtin_amdgcn_mfma_f32_16x16x32_bf16(a0,b2,q[0][2],0,0,0);
        q[0][3]=__builtin_amdgcn_mfma_f32_16x16x32_bf16(a0,b3,q[0][3],0,0,0);
        q[1][0]=__builtin_amdgcn_mfma_f32_16x16x32_bf16(a1,b0,q[1][0],0,0,0);
        q[1][1]=__builtin_amdgcn_mfma_f32_16x16x32_bf16(a1,b1,q[1][1],0,0,0);
        q[1][2]=__builtin_amdgcn_mfma_f32_16x16x32_bf16(a1,b2,q[1][2],0,0,0);
        q[1][3]=__builtin_amdgcn_mfma_f32_16x16x32_bf16(a1,b3,q[1][3],0,0,0);
      }
      #pragma unroll
      for (int mt=0;mt<2;mt++)
      #pragma unroll
      for (int nt=0;nt<4;nt++){
        int n = wv*64 + nt*16 + nl;
        #pragma unroll
        for (int r=0;r<4;r++){
          int node = blk*32 + mt*16 + quad*4 + r;
          RE[(size_t)node*HID + n] = q[mt][nt][r];
        }
      }
    }
  }
  // ---- final layer: out_h = h_new @ W_out + b_out (ligand only) ----
  if (doOut && blk < 32){
    int mt = wv >> 1, ntw = wv & 1;
    f32x4 o = zero4;
    #pragma unroll 2
    for (int k0=0;k0<8;k0++){
      bf16x8 a = *(const bf16x8*)(sH + (mt*16+nl)*264 + k0*32 + quad*8);
      bf16x8 b = *(const bf16x8*)(WoutP + ((size_t)(k0*2 + ntw)*64 + lane)*8);
      o = __builtin_amdgcn_mfma_f32_16x16x32_bf16(a,b,o,0,0,0);
    }
    int n = ntw*16 + nl;
    float bb = bout[n];
    #pragma unroll
    for (int r=0;r<4;r++){
      int m = mt*16 + quad*4 + r;
      outH[(size_t)(blk*32+m)*32 + n] = o[r] + bb;
    }
  }
}

// ---- coord combine (+ fused x output on last layer) ----
__global__ __launch_bounds__(256) void k_comb_coord(
    const u16* __restrict__ Qb, const float* __restrict__ R,
    const float* __restrict__ xc, float* __restrict__ xn,
    const int* __restrict__ colIdx, const float* __restrict__ emb0,
    const u16* __restrict__ W1cP, const float* __restrict__ B1,
    const u16* __restrict__ W2p, const float* __restrict__ B2,
    const float* __restrict__ cW3,
    const float* __restrict__ posw, float* __restrict__ outX, int doOut, int l)
{
  __shared__ __align__(16) u16 sQ[48*264];
  __shared__ __align__(16) u16 sEA[48*40];
  __shared__ __align__(16) u16 sM1[48*264];
  __shared__ float sR[256];
  __shared__ int sCol[48];
  __shared__ float sCd[48*3];
  __shared__ float sS[48];
  __shared__ float sDot[48][4];
  u16* sM2 = sQ;

  int row = blockIdx.x, tid = threadIdx.x;
  int lane = tid & 63, ng = tid >> 6;
  int quad = lane >> 4, nl = lane & 15;

  if (tid < 48) sCol[tid] = colIdx[(size_t)row*KNN + tid];
  sR[tid] = R[(size_t)row*HID + tid];
  __syncthreads();
  for (int t = tid; t < 48*32; t += 256){
    int e = t >> 5, q = t & 31;
    uint4 v = ((const uint4*)(Qb + (size_t)sCol[e]*HID))[q];
    *(uint4*)(sQ + e*264 + q*8) = v;
  }
  if (tid < 48){
    int cg = sCol[tid];
    float dx = xc[row*3+0]-xc[cg*3+0];
    float dy = xc[row*3+1]-xc[cg*3+1];
    float dz = xc[row*3+2]-xc[cg*3+2];
    float d = sqrtf(dx*dx+dy*dy+dz*dz + 1e-8f);
    float den = d + 1.0f;
    sCd[tid*3+0]=dx/den; sCd[tid*3+1]=dy/den; sCd[tid*3+2]=dz/den;
    u16* ea = sEA + tid*40;
    #pragma unroll
    for (int i=0;i<6;i++){
      float fr = freq_f(i);
      ea[i]   = f2b(sinf(d*fr));
      ea[6+i] = f2b(cosf(d*fr));
    }
    #pragma unroll
    for (int i=0;i<12;i++) ea[12+i] = f2b(emb0[((size_t)row*KNN + tid)*12 + i]);
    #pragma unroll
    for (int i=24;i<32;i++) ea[i] = 0;
  }
  __syncthreads();

  f32x4 zero4 = {0.f,0.f,0.f,0.f};
  f32x4 acc[3][4];
  #pragma unroll
  for (int i=0;i<3;i++){ acc[i][0]=zero4; acc[i][1]=zero4; acc[i][2]=zero4; acc[i][3]=zero4; }
  {
    const u16* Wc = W1cP + (size_t)l*32*HID;
    const u16* wb = Wc + ((size_t)(ng*4)*64 + lane)*8;
    bf16x8 b0 = *(const bf16x8*)(wb);
    bf16x8 b1 = *(const bf16x8*)(wb + 512);
    bf16x8 b2 = *(const bf16x8*)(wb + 1024);
    bf16x8 b3 = *(const bf16x8*)(wb + 1536);
    bf16x8 a0 = *(const bf16x8*)(sEA + (0*16+nl)*40 + quad*8);
    bf16x8 a1 = *(const bf16x8*)(sEA + (1*16+nl)*40 + quad*8);
    bf16x8 a2 = *(const bf16x8*)(sEA + (2*16+nl)*40 + quad*8);
    acc[0][0]=__builtin_amdgcn_mfma_f32_16x16x32_bf16(a0,b0,acc[0][0],0,0,0);
    acc[0][1]=__builtin_amdgcn_mfma_f32_16x16x32_bf16(a0,b1,acc[0][1],0,0,0);
    acc[0][2]=__builtin_amdgcn_mfma_f32_16x16x32_bf16(a0,b2,acc[0][2],0,0,0);
    acc[0][3]=__builtin_amdgcn_mfma_f32_16x16x32_bf16(a0,b3,acc[0][3],0,0,0);
    acc[1][0]=__builtin_amdgcn_mfma_f32_16x16x32_bf16(a1,b0,acc[1][0],0,0,0);
    acc[1][1]=__builtin_amdgcn_mfma_f32_16x16x32_bf16(a1,b1,acc[1][1],0,0,0);
    acc[1][2]=__builtin_amdgcn_mfma_f32_16x16x32_bf16(a1,b2,acc[1][2],0,0,0);
    acc[1][3]=__builtin_amdgcn_mfma_f32_16x16x32_bf16(a1,b3,acc[1][3],0,0,0);
    acc[2][0]=__builtin_amdgcn_mfma_f32_16x16x32_bf16(a2,b0,acc[2][0],0,0,0);
    acc[2][1]=__builtin_amdgcn_mfma_f32_16x16x32_bf16(a2,b1,acc[2][1],0,0,0);
    acc[2][2]=__builtin_amdgcn_mfma_f32_16x16x32_bf16(a2,b2,acc[2][2],0,0,0);
    acc[2][3]=__builtin_amdgcn_mfma_f32_16x16x32_bf16(a2,b3,acc[2][3],0,0,0);
  }
  #pragma unroll
  for (int mt=0;mt<3;mt++)
  #pragma unroll
  for (int nt=0;nt<4;nt++){
    int n = ng*64 + nt*16 + nl;
    float bb = B1[l*HID + n] + sR[n];
    #pragma unroll
    for (int r=0;r<4;r++){
      int m = mt*16 + quad*4 + r;
      float v = acc[mt][nt][r] + bb + b2f(sQ[m*264 + n]);
      sM1[m*264 + n] = f2b(silu_f(v));
    }
  }
  __syncthreads();

  f32x4 acc2[3][4];
  #pragma unroll
  for (int i=0;i<3;i++){ acc2[i][0]=zero4; acc2[i][1]=zero4; acc2[i][2]=zero4; acc2[i][3]=zero4; }
  const u16* W2 = W2p + (size_t)l*HID*HID;
  #pragma unroll 2
  for (int k0=0;k0<8;k0++){
    bf16x8 a0 = *(const bf16x8*)(sM1 + (0*16+nl)*264 + k0*32 + quad*8);
    bf16x8 a1 = *(const bf16x8*)(sM1 + (1*16+nl)*264 + k0*32 + quad*8);
    bf16x8 a2 = *(const bf16x8*)(sM1 + (2*16+nl)*264 + k0*32 + quad*8);
    const u16* wb = W2 + ((size_t)(k0*16 + ng*4)*64 + lane)*8;
    bf16x8 b0 = *(const bf16x8*)(wb);
    bf16x8 b1 = *(const bf16x8*)(wb + 512);
    bf16x8 b2 = *(const bf16x8*)(wb + 1024);
    bf16x8 b3 = *(const bf16x8*)(wb + 1536);
    acc2[0][0]=__builtin_amdgcn_mfma_f32_16x16x32_bf16(a0,b0,acc2[0][0],0,0,0);
    acc2[0][1]=__builtin_amdgcn_mfma_f32_16x16x32_bf16(a0,b1,acc2[0][1],0,0,0);
    acc2[0][2]=__builtin_amdgcn_mfma_f32_16x16x32_bf16(a0,b2,acc2[0][2],0,0,0);
    acc2[0][3]=__builtin_amdgcn_mfma_f32_16x16x32_bf16(a0,b3,acc2[0][3],0,0,0);
    acc2[1][0]=__builtin_amdgcn_mfma_f32_16x16x32_bf16(a1,b0,acc2[1][0],0,0,0);
    acc2[1][1]=__builtin_amdgcn_mfma_f32_16x16x32_bf16(a1,b1,acc2[1][1],0,0,0);
    acc2[1][2]=__builtin_amdgcn_mfma_f32_16x16x32_bf16(a1,b2,acc2[1][2],0,0,0);
    acc2[1][3]=__builtin_amdgcn_mfma_f32_16x16x32_bf16(a1,b3,acc2[1][3],0,0,0);
    acc2[2][0]=__builtin_amdgcn_mfma_f32_16x16x32_bf16(a2,b0,acc2[2][0],0,0,0);
    acc2[2][1]=__builtin_amdgcn_mfma_f32_16x16x32_bf16(a2,b1,acc2[2][1],0,0,0);
    acc2[2][2]=__builtin_amdgcn_mfma_f32_16x16x32_bf16(a2,b2,acc2[2][2],0,0,0);
    acc2[2][3]=__builtin_amdgcn_mfma_f32_16x16x32_bf16(a2,b3,acc2[2][3],0,0,0);
  }
  #pragma unroll
  for (int mt=0;mt<3;mt++)
  #pragma unroll
  for (int nt=0;nt<4;nt++){
    int n = ng*64 + nt*16 + nl;
    float bb = B2[l*HID + n];
    #pragma unroll
    for (int r=0;r<4;r++){
      int m = mt*16 + quad*4 + r;
      sM2[m*264 + n] = f2b(silu_f(acc2[mt][nt][r] + bb));
    }
  }
  __syncthreads();
  if (tid < 192){
    int e = tid >> 2, qq = tid & 3;
    float s = 0.f; int nb = qq*64;
    #pragma unroll 4
    for (int n=0;n<64;n++){
      int nn = nb + ((n + e) & 63);
      s += b2f(sM2[e*264 + nn])*cW3[l*HID + nn];
    }
    sDot[e][qq] = s;
  }
  __syncthreads();
  if (tid < 48) sS[tid] = sDot[tid][0]+sDot[tid][1]+sDot[tid][2]+sDot[tid][3];
  __syncthreads();
  if (tid < 3){
    float u = 0.f;
    #pragma unroll 4
    for (int e=0;e<48;e++) u += sCd[e*3+tid]*sS[e];
    float nv = xc[row*3+tid] + u/5.0f;
    xn[row*3+tid] = nv;
    if (doOut) outX[row*3+tid] = nv*posw[0];
  }
}

extern "C" void kernel_launch(void* const* d_in, const int* in_sizes, int n_in,
                              void* d_out, int out_size, void* d_ws, size_t ws_size,
                              hipStream_t stream)
{
  const float* protPos = (const float*)d_in[0];
  const int*   protEle = (const int*)d_in[1];
  const int*   protAA  = (const int*)d_in[2];
  const int*   protBB  = (const int*)d_in[3];
  const float* XtPos   = (const float*)d_in[4];
  const float* XtFeat  = (const float*)d_in[5];
  const int*   tArr    = (const int*)d_in[6];
  const float* WtTime  = (const float*)d_in[7];
  const float* Wele    = (const float*)d_in[8];
  const float* Waa     = (const float*)d_in[9];
  const float* Wbb     = (const float*)d_in[10];
  const float* Win     = (const float*)d_in[11];
  const float* bin     = (const float*)d_in[12];
  const float* Wout    = (const float*)d_in[13];
  const float* bout    = (const float*)d_in[14];
  const float* eW1     = (const float*)d_in[15];
  const float* eB1     = (const float*)d_in[16];
  const float* eW2     = (const float*)d_in[17];
  const float* eB2     = (const float*)d_in[18];
  const float* attW    = (const float*)d_in[19];
  const float* attB    = (const float*)d_in[20];
  const float* nW1     = (const float*)d_in[21];
  const float* nB1     = (const float*)d_in[22];
  const float* nW2     = (const float*)d_in[23];
  const float* nB2     = (const float*)d_in[24];
  const float* cW1     = (const float*)d_in[25];
  const float* cB1     = (const float*)d_in[26];
  const float* cW2     = (const float*)d_in[27];
  const float* cB2     = (const float*)d_in[28];
  const float* cW3     = (const float*)d_in[29];
  const float* posw    = (const float*)d_in[30];

  float* fp = (float*)d_ws;
  float* X0   = fp;               fp += NTOT*3;
  float* X1   = fp;               fp += NTOT*3;
  float* h    = fp;               fp += (size_t)NTOT*HID;
  float* emb0 = fp;               fp += (size_t)ETOT*12;
  float* RC   = fp;               fp += (size_t)N_LIGC*HID;
  float* RE   = fp;               fp += (size_t)N_LIGC*HID;
  int*   col  = (int*)fp;         fp += ETOT;
  u16*   up   = (u16*)fp;
  u16* h_bf   = up;               up += (size_t)NTOT*HID;
  u16* agg_bf = up;               up += (size_t)N_LIGC*HID;
  u16* QbE    = up;               up += (size_t)NTOT*HID;
  u16* QbC    = up;               up += (size_t)NTOT*HID;
  u16* eW1abP = up;               up += (size_t)DEPTHC*512*HID;
  u16* eW1cP  = up;               up += (size_t)DEPTHC*32*HID;
  u16* eW2p   = up;               up += (size_t)DEPTHC*HID*HID;
  u16* nW1p   = up;               up += (size_t)DEPTHC*512*HID;
  u16* nW2p   = up;               up += (size_t)DEPTHC*HID*HID;
  u16* cW1abP = up;               up += (size_t)DEPTHC*512*HID;
  u16* cW1cP  = up;               up += (size_t)DEPTHC*32*HID;
  u16* cW2p   = up;               up += (size_t)DEPTHC*HID*HID;
  u16* WoutP  = up;               up += (size_t)256*32;

  // total pack idx units = 379904 -> 1484 blocks
  k_packall<<<1484,256,0,stream>>>(eW1,eW2,nW1,nW2,cW1,cW2,Wout,
      eW1abP,eW1cP,eW2p,nW1p,nW2p,cW1abP,cW1cP,cW2p,WoutP);
  k_embed_hinit<<<NTOT/8,256,0,stream>>>(protPos,protEle,protAA,protBB,XtPos,XtFeat,
      tArr,WtTime,Wele,Waa,Wbb,Win,bin,X0,X1,h,h_bf);
  k_knn<<<N_LIGC,256,0,stream>>>(X0,col,emb0);
  k_pq<<<NTOT/32,256,0,stream>>>(h_bf,eW1abP,RE,QbE,0);

  float* xc = X0; float* xn = X1;
  float* outF = (float*)d_out;
  for (int l=0;l<DEPTHC;l++){
    k_comb_edge<<<N_LIGC,256,0,stream>>>(QbE,RE,xc,col,emb0,eW1cP,eB1,eW2p,eB2,attW,attB,agg_bf,l);
    const u16* eNext = eW1abP + (size_t)((l+1)%DEPTHC)*512*HID;
    k_node<<<NTOT/32,256,0,stream>>>(h,h_bf,agg_bf,nW1p,nB1,nW2p,nB2,
        cW1abP,QbC,RC, eNext,QbE,RE,(l<DEPTHC-1)?1:0,
        WoutP,bout, outF+3072, (l==DEPTHC-1)?1:0, l);
    k_comb_coord<<<N_LIGC,256,0,stream>>>(QbC,RC,xc,xn,col,emb0,cW1cP,cB1,cW2p,cB2,cW3,
        posw, outF, (l==DEPTHC-1)?1:0, l);
    float* t2=xc; xc=xn; xn=t2;
  }
}

// Round 6
// 683.698 us; speedup vs baseline: 1.3722x; 1.1703x over previous
//
#include <hip/hip_runtime.h>
#include <hip/hip_bf16.h>
#include <math.h>

#define N_LIGC 1024
#define NTOT 9216
#define KNN 48
#define HID 256
#define DEPTHC 5
#define ETOT (N_LIGC*KNN)
#define KBINS 4096

typedef unsigned short u16;
typedef __attribute__((ext_vector_type(8))) short bf16x8;
typedef __attribute__((ext_vector_type(4))) float f32x4;

__device__ __forceinline__ float freq_f(int i){
  double p = (double)(1 << (2*i));
  return (float)((2.0*3.14159265358979323846)*p/15.0);
}
// fast silu: native v_exp_f32 path (args are moderate; error << bf16 rounding)
__device__ __forceinline__ float silu_f(float v){ return v/(1.0f+__expf(-v)); }
__device__ __forceinline__ float sigm_f(float v){ return 1.0f/(1.0f+__expf(-v)); }
__device__ __forceinline__ u16 f2b(float f){
  union { __hip_bfloat16 h; u16 u; } c; c.h = __float2bfloat16(f); return c.u;
}
__device__ __forceinline__ float b2f(u16 u){
  union { unsigned int i; float f; } c; c.i = ((unsigned int)u)<<16; return c.f;
}

// ---- pack helper: fp32 [L][srcK][N] rows [kOff,kOff+Keff) -> bf16 B-frag layout
__device__ __forceinline__ void pack_one(const float* __restrict__ src,
    u16* __restrict__ dst, int srcK, int kOff, int Keff, int Kp, int N, int idx)
{
  int lane = idx & 63;
  int rest = idx >> 6;
  int Nt = N >> 4;
  int n0 = rest % Nt;
  int rest2 = rest / Nt;
  int Kt = Kp >> 5;
  int k0 = rest2 % Kt;
  int layer = rest2 / Kt;
  int kq = lane >> 4, nl = lane & 15;
  int kb = k0*32 + kq*8, n = n0*16 + nl;
  u16 o[8];
  #pragma unroll
  for (int j=0;j<8;j++){
    int k = kb + j;
    float v = (k < Keff) ? src[((size_t)layer*srcK + kOff + k)*N + n] : 0.f;
    o[j] = f2b(v);
  }
  *(uint4*)(dst + (size_t)idx*8) = *(uint4*)o;
}

__global__ __launch_bounds__(256) void k_packall(
    const float* eW1, const float* eW2, const float* nW1, const float* nW2,
    const float* cW1, const float* cW2, const float* Wout,
    u16* eW1abP, u16* eW1cP, u16* eW2p, u16* nW1p, u16* nW2p,
    u16* cW1abP, u16* cW1cP, u16* cW2p, u16* WoutP)
{
  int idx = blockIdx.x*256 + threadIdx.x;
  if (idx < 81920){ pack_one(eW1, eW1abP, 536, 0,   512, 512, 256, idx); return; } idx -= 81920;
  if (idx < 5120 ){ pack_one(eW1, eW1cP,  536, 512, 24,  32,  256, idx); return; } idx -= 5120;
  if (idx < 40960){ pack_one(eW2, eW2p,   256, 0,   256, 256, 256, idx); return; } idx -= 40960;
  if (idx < 81920){ pack_one(nW1, nW1p,   512, 0,   512, 512, 256, idx); return; } idx -= 81920;
  if (idx < 40960){ pack_one(nW2, nW2p,   256, 0,   256, 256, 256, idx); return; } idx -= 40960;
  if (idx < 81920){ pack_one(cW1, cW1abP, 536, 0,   512, 512, 256, idx); return; } idx -= 81920;
  if (idx < 5120 ){ pack_one(cW1, cW1cP,  536, 512, 24,  32,  256, idx); return; } idx -= 5120;
  if (idx < 40960){ pack_one(cW2, cW2p,   256, 0,   256, 256, 256, idx); return; } idx -= 40960;
  if (idx < 1024 ){ pack_one(Wout, WoutP, 256, 0,   256, 256, 32,  idx); return; }
}

// ---- fused embed + h-init (8 nodes/block) ----
__global__ __launch_bounds__(256) void k_embed_hinit(
    const float* __restrict__ protPos, const int* __restrict__ protEle,
    const int* __restrict__ protAA, const int* __restrict__ protBB,
    const float* __restrict__ XtPos, const float* __restrict__ XtFeat,
    const int* __restrict__ tArr, const float* __restrict__ WtTime,
    const float* __restrict__ Wele, const float* __restrict__ Waa,
    const float* __restrict__ Wbb,
    const float* __restrict__ Win, const float* __restrict__ bin,
    float* __restrict__ X0, float* __restrict__ X1,
    float* __restrict__ h, u16* __restrict__ h_bf)
{
  __shared__ float sF[8*40];
  int blk=blockIdx.x, tid=threadIdx.x;
  int n0=blk*8;
  for (int x=tid; x<344; x+=256){
    if (x < 320){
      int n = x/40, k = x%40;
      int node = n0+n;
      float v;
      if (node < N_LIGC){
        if (k < 32) v = XtFeat[node*32+k];
        else        v = WtTime[tArr[node]*8 + (k-32)];
      } else {
        int p = node - N_LIGC;
        if (k < 16)      v = Wele[protEle[p]*16 + k];
        else if (k < 32) v = Waa[protAA[p]*16 + (k-16)];
        else             v = Wbb[protBB[p]*8 + (k-32)];
      }
      sF[n*40+k] = v;
    } else {
      int r = x-320; int n = r/3, c = r%3;
      int node = n0+n;
      float v = (node < N_LIGC) ? XtPos[node*3+c] : protPos[(node-N_LIGC)*3+c];
      X0[node*3+c] = v; X1[node*3+c] = v;
    }
  }
  __syncthreads();
  float acc[8];
  float b=bin[tid];
  #pragma unroll
  for (int n=0;n<8;n++) acc[n]=b;
  for (int k=0;k<40;k++){
    float w=Win[k*HID+tid];
    #pragma unroll
    for (int n=0;n<8;n++) acc[n]+=sF[n*40+k]*w;
  }
  #pragma unroll
  for (int n=0;n<8;n++){
    h[(size_t)(n0+n)*HID+tid]=acc[n];
    h_bf[(size_t)(n0+n)*HID+tid]=f2b(acc[n]);
  }
}

// ---- KNN: radix-histogram top-K, LDS-light ----
__global__ __launch_bounds__(256) void k_knn(const float* __restrict__ X,
    int* __restrict__ col, float* __restrict__ emb0)
{
  __shared__ unsigned int hist[KBINS];
  __shared__ unsigned int part[256];
  __shared__ float selD[KNN];
  __shared__ int   candI[512];
  __shared__ float candV[512];
  __shared__ int sB, sCless, sNeed, sNsel, sNcand;
  int b = blockIdx.x, tid = threadIdx.x;
  for (int i=tid;i<KBINS;i+=256) hist[i]=0u;
  if (tid==0){ sNsel=0; sNcand=0; }
  float px = X[b*3+0], py = X[b*3+1], pz = X[b*3+2];
  __syncthreads();
  #pragma unroll 4
  for (int j=0;j<36;j++){
    int i = tid + 256*j;
    float dx = __fsub_rn(px, X[i*3+0]);
    float dy = __fsub_rn(py, X[i*3+1]);
    float dz = __fsub_rn(pz, X[i*3+2]);
    float d2 = __fadd_rn(__fadd_rn(__fmul_rn(dx,dx),__fmul_rn(dy,dy)),__fmul_rn(dz,dz));
    if (i==b) d2 = INFINITY;
    unsigned key = __float_as_uint(d2) >> 19;
    atomicAdd(&hist[key], 1u);
  }
  __syncthreads();
  {
    unsigned s=0;
    #pragma unroll 4
    for (int k=0;k<16;k++) s += hist[tid*16+k];
    part[tid]=s;
  }
  __syncthreads();
  if (tid==0){
    unsigned c=0; int chunk=0;
    for (int t=0;t<256;t++){
      if (c + part[t] >= (unsigned)KNN){ chunk=t; break; }
      c += part[t];
    }
    int bin = chunk*16;
    for (;;bin++){
      unsigned hh = hist[bin];
      if (c + hh >= (unsigned)KNN) break;
      c += hh;
    }
    sB = bin; sCless = (int)c; sNeed = KNN - (int)c;
  }
  __syncthreads();
  int B = sB;
  #pragma unroll 4
  for (int j=0;j<36;j++){
    int i = tid + 256*j;
    float dx = __fsub_rn(px, X[i*3+0]);
    float dy = __fsub_rn(py, X[i*3+1]);
    float dz = __fsub_rn(pz, X[i*3+2]);
    float d2 = __fadd_rn(__fadd_rn(__fmul_rn(dx,dx),__fmul_rn(dy,dy)),__fmul_rn(dz,dz));
    if (i==b) d2 = INFINITY;
    int key = (int)(__float_as_uint(d2) >> 19);
    if (key < B){
      int p = atomicAdd(&sNsel, 1);
      col[b*KNN+p] = i; selD[p] = d2;
    } else if (key == B){
      int c = atomicAdd(&sNcand, 1);
      if (c < 512){ candI[c] = i; candV[c] = d2; }
    }
  }
  __syncthreads();
  if (tid < 64){
    int m = sNcand; if (m > 512) m = 512;
    int need = sNeed, base = sCless;
    float cv[8]; int ci[8];
    #pragma unroll
    for (int k=0;k<8;k++){
      int c = tid + 64*k;
      if (c < m){ ci[k]=candI[c]; cv[k]=candV[c]; }
      else      { ci[k]=0x7fffffff; cv[k]=INFINITY; }
    }
    for (int it=0; it<need; it++){
      float bv=INFINITY; int bi=0x7fffffff; int bk=0;
      #pragma unroll
      for (int k=0;k<8;k++){
        if (cv[k]<bv || (cv[k]==bv && ci[k]<bi)){ bv=cv[k]; bi=ci[k]; bk=k; }
      }
      int bslot = tid + 64*bk;
      #pragma unroll
      for (int off=32; off>=1; off>>=1){
        float ov = __shfl_down(bv, off);
        int   oi = __shfl_down(bi, off);
        int   os = __shfl_down(bslot, off);
        if (ov < bv || (ov==bv && oi<bi)){ bv=ov; bi=oi; bslot=os; }
      }
      int wslot = __shfl(bslot, 0);
      if (tid==0){ col[b*KNN+base+it]=bi; selD[base+it]=bv; }
      if ((wslot & 63) == tid) cv[wslot >> 6] = INFINITY;
    }
  }
  __syncthreads();
  if (tid < KNN){
    float d = sqrtf(selD[tid] + 1e-8f);
    int base = (b*KNN+tid)*12;
    #pragma unroll
    for (int i=0;i<6;i++){
      float fr = freq_f(i);
      emb0[base+i]   = sinf(d*fr);
      emb0[base+6+i] = cosf(d*fr);
    }
  }
}

// ---- k_pq: initial Q/R for layer 0 edge stage ----
__global__ __launch_bounds__(256) void k_pq(const u16* __restrict__ h_bf,
    const u16* __restrict__ Wab, float* __restrict__ R, u16* __restrict__ Qb, int l)
{
  __shared__ __align__(16) u16 sA[32*264];
  int blk=blockIdx.x, tid=threadIdx.x;
  int lane=tid&63, ng=tid>>6, quad=lane>>4, nl=lane&15;
  for (int t=tid; t<32*32; t+=256){
    int i=t>>5, q=t&31;
    uint4 v = ((const uint4*)(h_bf + (size_t)(blk*32+i)*HID))[q];
    *(uint4*)(sA + i*264 + q*8) = v;
  }
  __syncthreads();
  const u16* Wl = Wab + (size_t)l*512*HID;
  f32x4 zero4 = {0.f,0.f,0.f,0.f};
  f32x4 aQ[2][4];
  #pragma unroll
  for (int i=0;i<2;i++){ aQ[i][0]=zero4; aQ[i][1]=zero4; aQ[i][2]=zero4; aQ[i][3]=zero4; }
  #pragma unroll 2
  for (int k0=0;k0<8;k0++){
    bf16x8 a0 = *(const bf16x8*)(sA + (0*16+nl)*264 + k0*32 + quad*8);
    bf16x8 a1 = *(const bf16x8*)(sA + (1*16+nl)*264 + k0*32 + quad*8);
    const u16* wb = Wl + ((size_t)((k0+8)*16 + ng*4)*64 + lane)*8;
    bf16x8 b0 = *(const bf16x8*)(wb);
    bf16x8 b1 = *(const bf16x8*)(wb + 512);
    bf16x8 b2 = *(const bf16x8*)(wb + 1024);
    bf16x8 b3 = *(const bf16x8*)(wb + 1536);
    aQ[0][0]=__builtin_amdgcn_mfma_f32_16x16x32_bf16(a0,b0,aQ[0][0],0,0,0);
    aQ[0][1]=__builtin_amdgcn_mfma_f32_16x16x32_bf16(a0,b1,aQ[0][1],0,0,0);
    aQ[0][2]=__builtin_amdgcn_mfma_f32_16x16x32_bf16(a0,b2,aQ[0][2],0,0,0);
    aQ[0][3]=__builtin_amdgcn_mfma_f32_16x16x32_bf16(a0,b3,aQ[0][3],0,0,0);
    aQ[1][0]=__builtin_amdgcn_mfma_f32_16x16x32_bf16(a1,b0,aQ[1][0],0,0,0);
    aQ[1][1]=__builtin_amdgcn_mfma_f32_16x16x32_bf16(a1,b1,aQ[1][1],0,0,0);
    aQ[1][2]=__builtin_amdgcn_mfma_f32_16x16x32_bf16(a1,b2,aQ[1][2],0,0,0);
    aQ[1][3]=__builtin_amdgcn_mfma_f32_16x16x32_bf16(a1,b3,aQ[1][3],0,0,0);
  }
  #pragma unroll
  for (int mt=0;mt<2;mt++)
  #pragma unroll
  for (int nt=0;nt<4;nt++){
    int n = ng*64 + nt*16 + nl;
    #pragma unroll
    for (int r=0;r<4;r++){
      int node = blk*32 + mt*16 + quad*4 + r;
      Qb[(size_t)node*HID + n] = f2b(aQ[mt][nt][r]);
    }
  }
  if (blk < 32){
    f32x4 aR[2][4];
    #pragma unroll
    for (int i=0;i<2;i++){ aR[i][0]=zero4; aR[i][1]=zero4; aR[i][2]=zero4; aR[i][3]=zero4; }
    #pragma unroll 2
    for (int k0=0;k0<8;k0++){
      bf16x8 a0 = *(const bf16x8*)(sA + (0*16+nl)*264 + k0*32 + quad*8);
      bf16x8 a1 = *(const bf16x8*)(sA + (1*16+nl)*264 + k0*32 + quad*8);
      const u16* wb = Wl + ((size_t)(k0*16 + ng*4)*64 + lane)*8;
      bf16x8 b0 = *(const bf16x8*)(wb);
      bf16x8 b1 = *(const bf16x8*)(wb + 512);
      bf16x8 b2 = *(const bf16x8*)(wb + 1024);
      bf16x8 b3 = *(const bf16x8*)(wb + 1536);
      aR[0][0]=__builtin_amdgcn_mfma_f32_16x16x32_bf16(a0,b0,aR[0][0],0,0,0);
      aR[0][1]=__builtin_amdgcn_mfma_f32_16x16x32_bf16(a0,b1,aR[0][1],0,0,0);
      aR[0][2]=__builtin_amdgcn_mfma_f32_16x16x32_bf16(a0,b2,aR[0][2],0,0,0);
      aR[0][3]=__builtin_amdgcn_mfma_f32_16x16x32_bf16(a0,b3,aR[0][3],0,0,0);
      aR[1][0]=__builtin_amdgcn_mfma_f32_16x16x32_bf16(a1,b0,aR[1][0],0,0,0);
      aR[1][1]=__builtin_amdgcn_mfma_f32_16x16x32_bf16(a1,b1,aR[1][1],0,0,0);
      aR[1][2]=__builtin_amdgcn_mfma_f32_16x16x32_bf16(a1,b2,aR[1][2],0,0,0);
      aR[1][3]=__builtin_amdgcn_mfma_f32_16x16x32_bf16(a1,b3,aR[1][3],0,0,0);
    }
    #pragma unroll
    for (int mt=0;mt<2;mt++)
    #pragma unroll
    for (int nt=0;nt<4;nt++){
      int n = ng*64 + nt*16 + nl;
      #pragma unroll
      for (int r=0;r<4;r++){
        int node = blk*32 + mt*16 + quad*4 + r;
        R[(size_t)node*HID + n] = aR[mt][nt][r];
      }
    }
  }
}

// ---- edge combine (sEA aliased into sM1 region; 3 blocks/CU) ----
__global__ __launch_bounds__(256) void k_comb_edge(
    const u16* __restrict__ Qb, const float* __restrict__ R,
    const float* __restrict__ xc,
    const int* __restrict__ colIdx, const float* __restrict__ emb0,
    const u16* __restrict__ W1cP, const float* __restrict__ B1,
    const u16* __restrict__ W2p, const float* __restrict__ B2,
    const float* __restrict__ attW, const float* __restrict__ attB,
    u16* __restrict__ agg_bf, int l)
{
  __shared__ __align__(16) u16 sQ[48*264];
  __shared__ __align__(16) u16 sM1[48*264];
  __shared__ float sR[256];
  __shared__ int sCol[48];
  __shared__ float sSig[48];
  __shared__ float sDot[48][4];
  u16* sM2 = sQ;
  u16* sEA = sM1;   // alias: ea staged in sM1 region, consumed by GEMM1, then overwritten

  int row = blockIdx.x, tid = threadIdx.x;
  int lane = tid & 63, ng = tid >> 6;
  int quad = lane >> 4, nl = lane & 15;

  if (tid < 48) sCol[tid] = colIdx[(size_t)row*KNN + tid];
  sR[tid] = R[(size_t)row*HID + tid];
  __syncthreads();
  for (int t = tid; t < 48*32; t += 256){
    int e = t >> 5, q = t & 31;
    uint4 v = ((const uint4*)(Qb + (size_t)sCol[e]*HID))[q];
    *(uint4*)(sQ + e*264 + q*8) = v;
  }
  if (tid < 48){
    int cg = sCol[tid];
    float dx = xc[row*3+0]-xc[cg*3+0];
    float dy = xc[row*3+1]-xc[cg*3+1];
    float dz = xc[row*3+2]-xc[cg*3+2];
    float d = sqrtf(dx*dx+dy*dy+dz*dz + 1e-8f);
    u16* ea = sEA + tid*40;
    #pragma unroll
    for (int i=0;i<6;i++){
      float fr = freq_f(i);
      ea[i]   = f2b(sinf(d*fr));
      ea[6+i] = f2b(cosf(d*fr));
    }
    #pragma unroll
    for (int i=0;i<12;i++) ea[12+i] = f2b(emb0[((size_t)row*KNN + tid)*12 + i]);
    #pragma unroll
    for (int i=24;i<32;i++) ea[i] = 0;
  }
  __syncthreads();

  f32x4 zero4 = {0.f,0.f,0.f,0.f};
  f32x4 acc[3][4];
  #pragma unroll
  for (int i=0;i<3;i++){ acc[i][0]=zero4; acc[i][1]=zero4; acc[i][2]=zero4; acc[i][3]=zero4; }
  {
    const u16* Wc = W1cP + (size_t)l*32*HID;
    const u16* wb = Wc + ((size_t)(ng*4)*64 + lane)*8;
    bf16x8 b0 = *(const bf16x8*)(wb);
    bf16x8 b1 = *(const bf16x8*)(wb + 512);
    bf16x8 b2 = *(const bf16x8*)(wb + 1024);
    bf16x8 b3 = *(const bf16x8*)(wb + 1536);
    bf16x8 a0 = *(const bf16x8*)(sEA + (0*16+nl)*40 + quad*8);
    bf16x8 a1 = *(const bf16x8*)(sEA + (1*16+nl)*40 + quad*8);
    bf16x8 a2 = *(const bf16x8*)(sEA + (2*16+nl)*40 + quad*8);
    acc[0][0]=__builtin_amdgcn_mfma_f32_16x16x32_bf16(a0,b0,acc[0][0],0,0,0);
    acc[0][1]=__builtin_amdgcn_mfma_f32_16x16x32_bf16(a0,b1,acc[0][1],0,0,0);
    acc[0][2]=__builtin_amdgcn_mfma_f32_16x16x32_bf16(a0,b2,acc[0][2],0,0,0);
    acc[0][3]=__builtin_amdgcn_mfma_f32_16x16x32_bf16(a0,b3,acc[0][3],0,0,0);
    acc[1][0]=__builtin_amdgcn_mfma_f32_16x16x32_bf16(a1,b0,acc[1][0],0,0,0);
    acc[1][1]=__builtin_amdgcn_mfma_f32_16x16x32_bf16(a1,b1,acc[1][1],0,0,0);
    acc[1][2]=__builtin_amdgcn_mfma_f32_16x16x32_bf16(a1,b2,acc[1][2],0,0,0);
    acc[1][3]=__builtin_amdgcn_mfma_f32_16x16x32_bf16(a1,b3,acc[1][3],0,0,0);
    acc[2][0]=__builtin_amdgcn_mfma_f32_16x16x32_bf16(a2,b0,acc[2][0],0,0,0);
    acc[2][1]=__builtin_amdgcn_mfma_f32_16x16x32_bf16(a2,b1,acc[2][1],0,0,0);
    acc[2][2]=__builtin_amdgcn_mfma_f32_16x16x32_bf16(a2,b2,acc[2][2],0,0,0);
    acc[2][3]=__builtin_amdgcn_mfma_f32_16x16x32_bf16(a2,b3,acc[2][3],0,0,0);
  }
  __syncthreads();   // all sEA reads done before sM1 writes (alias)
  #pragma unroll
  for (int mt=0;mt<3;mt++)
  #pragma unroll
  for (int nt=0;nt<4;nt++){
    int n = ng*64 + nt*16 + nl;
    float bb = B1[l*HID + n] + sR[n];
    #pragma unroll
    for (int r=0;r<4;r++){
      int m = mt*16 + quad*4 + r;
      float v = acc[mt][nt][r] + bb + b2f(sQ[m*264 + n]);
      sM1[m*264 + n] = f2b(silu_f(v));
    }
  }
  __syncthreads();

  f32x4 acc2[3][4];
  #pragma unroll
  for (int i=0;i<3;i++){ acc2[i][0]=zero4; acc2[i][1]=zero4; acc2[i][2]=zero4; acc2[i][3]=zero4; }
  const u16* W2 = W2p + (size_t)l*HID*HID;
  #pragma unroll 2
  for (int k0=0;k0<8;k0++){
    bf16x8 a0 = *(const bf16x8*)(sM1 + (0*16+nl)*264 + k0*32 + quad*8);
    bf16x8 a1 = *(const bf16x8*)(sM1 + (1*16+nl)*264 + k0*32 + quad*8);
    bf16x8 a2 = *(const bf16x8*)(sM1 + (2*16+nl)*264 + k0*32 + quad*8);
    const u16* wb = W2 + ((size_t)(k0*16 + ng*4)*64 + lane)*8;
    bf16x8 b0 = *(const bf16x8*)(wb);
    bf16x8 b1 = *(const bf16x8*)(wb + 512);
    bf16x8 b2 = *(const bf16x8*)(wb + 1024);
    bf16x8 b3 = *(const bf16x8*)(wb + 1536);
    acc2[0][0]=__builtin_amdgcn_mfma_f32_16x16x32_bf16(a0,b0,acc2[0][0],0,0,0);
    acc2[0][1]=__builtin_amdgcn_mfma_f32_16x16x32_bf16(a0,b1,acc2[0][1],0,0,0);
    acc2[0][2]=__builtin_amdgcn_mfma_f32_16x16x32_bf16(a0,b2,acc2[0][2],0,0,0);
    acc2[0][3]=__builtin_amdgcn_mfma_f32_16x16x32_bf16(a0,b3,acc2[0][3],0,0,0);
    acc2[1][0]=__builtin_amdgcn_mfma_f32_16x16x32_bf16(a1,b0,acc2[1][0],0,0,0);
    acc2[1][1]=__builtin_amdgcn_mfma_f32_16x16x32_bf16(a1,b1,acc2[1][1],0,0,0);
    acc2[1][2]=__builtin_amdgcn_mfma_f32_16x16x32_bf16(a1,b2,acc2[1][2],0,0,0);
    acc2[1][3]=__builtin_amdgcn_mfma_f32_16x16x32_bf16(a1,b3,acc2[1][3],0,0,0);
    acc2[2][0]=__builtin_amdgcn_mfma_f32_16x16x32_bf16(a2,b0,acc2[2][0],0,0,0);
    acc2[2][1]=__builtin_amdgcn_mfma_f32_16x16x32_bf16(a2,b1,acc2[2][1],0,0,0);
    acc2[2][2]=__builtin_amdgcn_mfma_f32_16x16x32_bf16(a2,b2,acc2[2][2],0,0,0);
    acc2[2][3]=__builtin_amdgcn_mfma_f32_16x16x32_bf16(a2,b3,acc2[2][3],0,0,0);
  }
  #pragma unroll
  for (int mt=0;mt<3;mt++)
  #pragma unroll
  for (int nt=0;nt<4;nt++){
    int n = ng*64 + nt*16 + nl;
    float bb = B2[l*HID + n];
    #pragma unroll
    for (int r=0;r<4;r++){
      int m = mt*16 + quad*4 + r;
      sM2[m*264 + n] = f2b(silu_f(acc2[mt][nt][r] + bb));
    }
  }
  __syncthreads();
  if (tid < 192){
    int e = tid >> 2, qq = tid & 3;
    float s = 0.f; int nb = qq*64;
    #pragma unroll 4
    for (int n=0;n<64;n++){
      int nn = nb + ((n + e) & 63);
      s += b2f(sM2[e*264 + nn])*attW[l*HID + nn];
    }
    sDot[e][qq] = s;
  }
  __syncthreads();
  if (tid < 48){
    float s = sDot[tid][0]+sDot[tid][1]+sDot[tid][2]+sDot[tid][3] + attB[l];
    sSig[tid] = sigm_f(s);
  }
  __syncthreads();
  {
    float a = 0.f;
    #pragma unroll 4
    for (int e=0;e<48;e++) a += b2f(sM2[e*264 + tid])*sSig[e];
    agg_bf[(size_t)row*HID + tid] = f2b(a/5.0f);
  }
}

// ---- node MLP + residual + QC/RC + QE/RE + final outh ----
__global__ __launch_bounds__(256) void k_node(
    float* __restrict__ h, u16* __restrict__ h_bf,
    const u16* __restrict__ agg_bf,
    const u16* __restrict__ W1p, const float* __restrict__ B1,
    const u16* __restrict__ W2p, const float* __restrict__ B2,
    const u16* __restrict__ cWab, u16* __restrict__ QbC, float* __restrict__ RC,
    const u16* __restrict__ eWabN, u16* __restrict__ QbE, float* __restrict__ RE, int doE,
    const u16* __restrict__ WoutP, const float* __restrict__ bout,
    float* __restrict__ outH, int doOut, int l)
{
  __shared__ __align__(16) u16 sA[32*520];
  __shared__ __align__(16) u16 sU[32*264];
  u16* sH = sA;
  int blk=blockIdx.x, tid=threadIdx.x;
  int lane=tid&63, wv=tid>>6, quad=lane>>4, nl=lane&15;
  for (int t=tid; t<32*64; t+=256){
    int i=t>>6, q=t&63;
    int node = blk*32+i;
    uint4 v;
    if (q<32) v = ((const uint4*)(h_bf + (size_t)node*HID))[q];
    else if (node < N_LIGC) v = ((const uint4*)(agg_bf + (size_t)node*HID))[q-32];
    else { v.x=0u; v.y=0u; v.z=0u; v.w=0u; }
    *(uint4*)(sA + i*520 + q*8) = v;
  }
  __syncthreads();
  f32x4 zero4 = {0.f,0.f,0.f,0.f};
  f32x4 acc[2][4];
  #pragma unroll
  for (int i=0;i<2;i++){ acc[i][0]=zero4; acc[i][1]=zero4; acc[i][2]=zero4; acc[i][3]=zero4; }
  const u16* Wp = W1p + (size_t)l*512*HID;
  #pragma unroll 2
  for (int k0=0;k0<16;k0++){
    bf16x8 a0 = *(const bf16x8*)(sA + (0*16+nl)*520 + k0*32 + quad*8);
    bf16x8 a1 = *(const bf16x8*)(sA + (1*16+nl)*520 + k0*32 + quad*8);
    const u16* wb = Wp + ((size_t)(k0*16 + wv*4)*64 + lane)*8;
    bf16x8 b0 = *(const bf16x8*)(wb);
    bf16x8 b1 = *(const bf16x8*)(wb + 512);
    bf16x8 b2 = *(const bf16x8*)(wb + 1024);
    bf16x8 b3 = *(const bf16x8*)(wb + 1536);
    acc[0][0]=__builtin_amdgcn_mfma_f32_16x16x32_bf16(a0,b0,acc[0][0],0,0,0);
    acc[0][1]=__builtin_amdgcn_mfma_f32_16x16x32_bf16(a0,b1,acc[0][1],0,0,0);
    acc[0][2]=__builtin_amdgcn_mfma_f32_16x16x32_bf16(a0,b2,acc[0][2],0,0,0);
    acc[0][3]=__builtin_amdgcn_mfma_f32_16x16x32_bf16(a0,b3,acc[0][3],0,0,0);
    acc[1][0]=__builtin_amdgcn_mfma_f32_16x16x32_bf16(a1,b0,acc[1][0],0,0,0);
    acc[1][1]=__builtin_amdgcn_mfma_f32_16x16x32_bf16(a1,b1,acc[1][1],0,0,0);
    acc[1][2]=__builtin_amdgcn_mfma_f32_16x16x32_bf16(a1,b2,acc[1][2],0,0,0);
    acc[1][3]=__builtin_amdgcn_mfma_f32_16x16x32_bf16(a1,b3,acc[1][3],0,0,0);
  }
  #pragma unroll
  for (int mt=0;mt<2;mt++)
  #pragma unroll
  for (int nt=0;nt<4;nt++){
    int n = wv*64 + nt*16 + nl;
    float bb = B1[l*HID + n];
    #pragma unroll
    for (int r=0;r<4;r++){
      int m = mt*16 + quad*4 + r;
      sU[m*264 + n] = f2b(silu_f(acc[mt][nt][r] + bb));
    }
  }
  __syncthreads();
  f32x4 acc2[2][4];
  #pragma unroll
  for (int i=0;i<2;i++){ acc2[i][0]=zero4; acc2[i][1]=zero4; acc2[i][2]=zero4; acc2[i][3]=zero4; }
  const u16* W2 = W2p + (size_t)l*HID*HID;
  #pragma unroll 2
  for (int k0=0;k0<8;k0++){
    bf16x8 a0 = *(const bf16x8*)(sU + (0*16+nl)*264 + k0*32 + quad*8);
    bf16x8 a1 = *(const bf16x8*)(sU + (1*16+nl)*264 + k0*32 + quad*8);
    const u16* wb = W2 + ((size_t)(k0*16 + wv*4)*64 + lane)*8;
    bf16x8 b0 = *(const bf16x8*)(wb);
    bf16x8 b1 = *(const bf16x8*)(wb + 512);
    bf16x8 b2 = *(const bf16x8*)(wb + 1024);
    bf16x8 b3 = *(const bf16x8*)(wb + 1536);
    acc2[0][0]=__builtin_amdgcn_mfma_f32_16x16x32_bf16(a0,b0,acc2[0][0],0,0,0);
    acc2[0][1]=__builtin_amdgcn_mfma_f32_16x16x32_bf16(a0,b1,acc2[0][1],0,0,0);
    acc2[0][2]=__builtin_amdgcn_mfma_f32_16x16x32_bf16(a0,b2,acc2[0][2],0,0,0);
    acc2[0][3]=__builtin_amdgcn_mfma_f32_16x16x32_bf16(a0,b3,acc2[0][3],0,0,0);
    acc2[1][0]=__builtin_amdgcn_mfma_f32_16x16x32_bf16(a1,b0,acc2[1][0],0,0,0);
    acc2[1][1]=__builtin_amdgcn_mfma_f32_16x16x32_bf16(a1,b1,acc2[1][1],0,0,0);
    acc2[1][2]=__builtin_amdgcn_mfma_f32_16x16x32_bf16(a1,b2,acc2[1][2],0,0,0);
    acc2[1][3]=__builtin_amdgcn_mfma_f32_16x16x32_bf16(a1,b3,acc2[1][3],0,0,0);
  }
  #pragma unroll
  for (int mt=0;mt<2;mt++)
  #pragma unroll
  for (int nt=0;nt<4;nt++){
    int n = wv*64 + nt*16 + nl;
    float bb = B2[l*HID + n];
    #pragma unroll
    for (int r=0;r<4;r++){
      int m = mt*16 + quad*4 + r;
      size_t idx = (size_t)(blk*32+m)*HID + n;
      float v = h[idx] + acc2[mt][nt][r] + bb;
      h[idx] = v;
      u16 bv = f2b(v);
      h_bf[idx] = bv;
      sH[m*264 + n] = bv;
    }
  }
  __syncthreads();

  const u16* Wl = cWab + (size_t)l*512*HID;
  f32x4 q[2][4];
  #pragma unroll
  for (int i=0;i<2;i++){ q[i][0]=zero4; q[i][1]=zero4; q[i][2]=zero4; q[i][3]=zero4; }
  #pragma unroll 2
  for (int k0=0;k0<8;k0++){
    bf16x8 a0 = *(const bf16x8*)(sH + (0*16+nl)*264 + k0*32 + quad*8);
    bf16x8 a1 = *(const bf16x8*)(sH + (1*16+nl)*264 + k0*32 + quad*8);
    const u16* wb = Wl + ((size_t)((k0+8)*16 + wv*4)*64 + lane)*8;
    bf16x8 b0 = *(const bf16x8*)(wb);
    bf16x8 b1 = *(const bf16x8*)(wb + 512);
    bf16x8 b2 = *(const bf16x8*)(wb + 1024);
    bf16x8 b3 = *(const bf16x8*)(wb + 1536);
    q[0][0]=__builtin_amdgcn_mfma_f32_16x16x32_bf16(a0,b0,q[0][0],0,0,0);
    q[0][1]=__builtin_amdgcn_mfma_f32_16x16x32_bf16(a0,b1,q[0][1],0,0,0);
    q[0][2]=__builtin_amdgcn_mfma_f32_16x16x32_bf16(a0,b2,q[0][2],0,0,0);
    q[0][3]=__builtin_amdgcn_mfma_f32_16x16x32_bf16(a0,b3,q[0][3],0,0,0);
    q[1][0]=__builtin_amdgcn_mfma_f32_16x16x32_bf16(a1,b0,q[1][0],0,0,0);
    q[1][1]=__builtin_amdgcn_mfma_f32_16x16x32_bf16(a1,b1,q[1][1],0,0,0);
    q[1][2]=__builtin_amdgcn_mfma_f32_16x16x32_bf16(a1,b2,q[1][2],0,0,0);
    q[1][3]=__builtin_amdgcn_mfma_f32_16x16x32_bf16(a1,b3,q[1][3],0,0,0);
  }
  #pragma unroll
  for (int mt=0;mt<2;mt++)
  #pragma unroll
  for (int nt=0;nt<4;nt++){
    int n = wv*64 + nt*16 + nl;
    #pragma unroll
    for (int r=0;r<4;r++){
      int node = blk*32 + mt*16 + quad*4 + r;
      QbC[(size_t)node*HID + n] = f2b(q[mt][nt][r]);
    }
  }
  if (blk < 32){
    #pragma unroll
    for (int i=0;i<2;i++){ q[i][0]=zero4; q[i][1]=zero4; q[i][2]=zero4; q[i][3]=zero4; }
    #pragma unroll 2
    for (int k0=0;k0<8;k0++){
      bf16x8 a0 = *(const bf16x8*)(sH + (0*16+nl)*264 + k0*32 + quad*8);
      bf16x8 a1 = *(const bf16x8*)(sH + (1*16+nl)*264 + k0*32 + quad*8);
      const u16* wb = Wl + ((size_t)(k0*16 + wv*4)*64 + lane)*8;
      bf16x8 b0 = *(const bf16x8*)(wb);
      bf16x8 b1 = *(const bf16x8*)(wb + 512);
      bf16x8 b2 = *(const bf16x8*)(wb + 1024);
      bf16x8 b3 = *(const bf16x8*)(wb + 1536);
      q[0][0]=__builtin_amdgcn_mfma_f32_16x16x32_bf16(a0,b0,q[0][0],0,0,0);
      q[0][1]=__builtin_amdgcn_mfma_f32_16x16x32_bf16(a0,b1,q[0][1],0,0,0);
      q[0][2]=__builtin_amdgcn_mfma_f32_16x16x32_bf16(a0,b2,q[0][2],0,0,0);
      q[0][3]=__builtin_amdgcn_mfma_f32_16x16x32_bf16(a0,b3,q[0][3],0,0,0);
      q[1][0]=__builtin_amdgcn_mfma_f32_16x16x32_bf16(a1,b0,q[1][0],0,0,0);
      q[1][1]=__builtin_amdgcn_mfma_f32_16x16x32_bf16(a1,b1,q[1][1],0,0,0);
      q[1][2]=__builtin_amdgcn_mfma_f32_16x16x32_bf16(a1,b2,q[1][2],0,0,0);
      q[1][3]=__builtin_amdgcn_mfma_f32_16x16x32_bf16(a1,b3,q[1][3],0,0,0);
    }
    #pragma unroll
    for (int mt=0;mt<2;mt++)
    #pragma unroll
    for (int nt=0;nt<4;nt++){
      int n = wv*64 + nt*16 + nl;
      #pragma unroll
      for (int r=0;r<4;r++){
        int node = blk*32 + mt*16 + quad*4 + r;
        RC[(size_t)node*HID + n] = q[mt][nt][r];
      }
    }
  }
  if (doE){
    #pragma unroll
    for (int i=0;i<2;i++){ q[i][0]=zero4; q[i][1]=zero4; q[i][2]=zero4; q[i][3]=zero4; }
    #pragma unroll 2
    for (int k0=0;k0<8;k0++){
      bf16x8 a0 = *(const bf16x8*)(sH + (0*16+nl)*264 + k0*32 + quad*8);
      bf16x8 a1 = *(const bf16x8*)(sH + (1*16+nl)*264 + k0*32 + quad*8);
      const u16* wb = eWabN + ((size_t)((k0+8)*16 + wv*4)*64 + lane)*8;
      bf16x8 b0 = *(const bf16x8*)(wb);
      bf16x8 b1 = *(const bf16x8*)(wb + 512);
      bf16x8 b2 = *(const bf16x8*)(wb + 1024);
      bf16x8 b3 = *(const bf16x8*)(wb + 1536);
      q[0][0]=__builtin_amdgcn_mfma_f32_16x16x32_bf16(a0,b0,q[0][0],0,0,0);
      q[0][1]=__builtin_amdgcn_mfma_f32_16x16x32_bf16(a0,b1,q[0][1],0,0,0);
      q[0][2]=__builtin_amdgcn_mfma_f32_16x16x32_bf16(a0,b2,q[0][2],0,0,0);
      q[0][3]=__builtin_amdgcn_mfma_f32_16x16x32_bf16(a0,b3,q[0][3],0,0,0);
      q[1][0]=__builtin_amdgcn_mfma_f32_16x16x32_bf16(a1,b0,q[1][0],0,0,0);
      q[1][1]=__builtin_amdgcn_mfma_f32_16x16x32_bf16(a1,b1,q[1][1],0,0,0);
      q[1][2]=__builtin_amdgcn_mfma_f32_16x16x32_bf16(a1,b2,q[1][2],0,0,0);
      q[1][3]=__builtin_amdgcn_mfma_f32_16x16x32_bf16(a1,b3,q[1][3],0,0,0);
    }
    #pragma unroll
    for (int mt=0;mt<2;mt++)
    #pragma unroll
    for (int nt=0;nt<4;nt++){
      int n = wv*64 + nt*16 + nl;
      #pragma unroll
      for (int r=0;r<4;r++){
        int node = blk*32 + mt*16 + quad*4 + r;
        QbE[(size_t)node*HID + n] = f2b(q[mt][nt][r]);
      }
    }
    if (blk < 32){
      #pragma unroll
      for (int i=0;i<2;i++){ q[i][0]=zero4; q[i][1]=zero4; q[i][2]=zero4; q[i][3]=zero4; }
      #pragma unroll 2
      for (int k0=0;k0<8;k0++){
        bf16x8 a0 = *(const bf16x8*)(sH + (0*16+nl)*264 + k0*32 + quad*8);
        bf16x8 a1 = *(const bf16x8*)(sH + (1*16+nl)*264 + k0*32 + quad*8);
        const u16* wb = eWabN + ((size_t)(k0*16 + wv*4)*64 + lane)*8;
        bf16x8 b0 = *(const bf16x8*)(wb);
        bf16x8 b1 = *(const bf16x8*)(wb + 512);
        bf16x8 b2 = *(const bf16x8*)(wb + 1024);
        bf16x8 b3 = *(const bf16x8*)(wb + 1536);
        q[0][0]=__builtin_amdgcn_mfma_f32_16x16x32_bf16(a0,b0,q[0][0],0,0,0);
        q[0][1]=__builtin_amdgcn_mfma_f32_16x16x32_bf16(a0,b1,q[0][1],0,0,0);
        q[0][2]=__builtin_amdgcn_mfma_f32_16x16x32_bf16(a0,b2,q[0][2],0,0,0);
        q[0][3]=__builtin_amdgcn_mfma_f32_16x16x32_bf16(a0,b3,q[0][3],0,0,0);
        q[1][0]=__builtin_amdgcn_mfma_f32_16x16x32_bf16(a1,b0,q[1][0],0,0,0);
        q[1][1]=__builtin_amdgcn_mfma_f32_16x16x32_bf16(a1,b1,q[1][1],0,0,0);
        q[1][2]=__builtin_amdgcn_mfma_f32_16x16x32_bf16(a1,b2,q[1][2],0,0,0);
        q[1][3]=__builtin_amdgcn_mfma_f32_16x16x32_bf16(a1,b3,q[1][3],0,0,0);
      }
      #pragma unroll
      for (int mt=0;mt<2;mt++)
      #pragma unroll
      for (int nt=0;nt<4;nt++){
        int n = wv*64 + nt*16 + nl;
        #pragma unroll
        for (int r=0;r<4;r++){
          int node = blk*32 + mt*16 + quad*4 + r;
          RE[(size_t)node*HID + n] = q[mt][nt][r];
        }
      }
    }
  }
  if (doOut && blk < 32){
    int mt = wv >> 1, ntw = wv & 1;
    f32x4 o = zero4;
    #pragma unroll 2
    for (int k0=0;k0<8;k0++){
      bf16x8 a = *(const bf16x8*)(sH + (mt*16+nl)*264 + k0*32 + quad*8);
      bf16x8 b = *(const bf16x8*)(WoutP + ((size_t)(k0*2 + ntw)*64 + lane)*8);
      o = __builtin_amdgcn_mfma_f32_16x16x32_bf16(a,b,o,0,0,0);
    }
    int n = ntw*16 + nl;
    float bb = bout[n];
    #pragma unroll
    for (int r=0;r<4;r++){
      int m = mt*16 + quad*4 + r;
      outH[(size_t)(blk*32+m)*32 + n] = o[r] + bb;
    }
  }
}

// ---- coord combine (sEA aliased; + fused x output) ----
__global__ __launch_bounds__(256) void k_comb_coord(
    const u16* __restrict__ Qb, const float* __restrict__ R,
    const float* __restrict__ xc, float* __restrict__ xn,
    const int* __restrict__ colIdx, const float* __restrict__ emb0,
    const u16* __restrict__ W1cP, const float* __restrict__ B1,
    const u16* __restrict__ W2p, const float* __restrict__ B2,
    const float* __restrict__ cW3,
    const float* __restrict__ posw, float* __restrict__ outX, int doOut, int l)
{
  __shared__ __align__(16) u16 sQ[48*264];
  __shared__ __align__(16) u16 sM1[48*264];
  __shared__ float sR[256];
  __shared__ int sCol[48];
  __shared__ float sCd[48*3];
  __shared__ float sS[48];
  __shared__ float sDot[48][4];
  u16* sM2 = sQ;
  u16* sEA = sM1;

  int row = blockIdx.x, tid = threadIdx.x;
  int lane = tid & 63, ng = tid >> 6;
  int quad = lane >> 4, nl = lane & 15;

  if (tid < 48) sCol[tid] = colIdx[(size_t)row*KNN + tid];
  sR[tid] = R[(size_t)row*HID + tid];
  __syncthreads();
  for (int t = tid; t < 48*32; t += 256){
    int e = t >> 5, q = t & 31;
    uint4 v = ((const uint4*)(Qb + (size_t)sCol[e]*HID))[q];
    *(uint4*)(sQ + e*264 + q*8) = v;
  }
  if (tid < 48){
    int cg = sCol[tid];
    float dx = xc[row*3+0]-xc[cg*3+0];
    float dy = xc[row*3+1]-xc[cg*3+1];
    float dz = xc[row*3+2]-xc[cg*3+2];
    float d = sqrtf(dx*dx+dy*dy+dz*dz + 1e-8f);
    float den = d + 1.0f;
    sCd[tid*3+0]=dx/den; sCd[tid*3+1]=dy/den; sCd[tid*3+2]=dz/den;
    u16* ea = sEA + tid*40;
    #pragma unroll
    for (int i=0;i<6;i++){
      float fr = freq_f(i);
      ea[i]   = f2b(sinf(d*fr));
      ea[6+i] = f2b(cosf(d*fr));
    }
    #pragma unroll
    for (int i=0;i<12;i++) ea[12+i] = f2b(emb0[((size_t)row*KNN + tid)*12 + i]);
    #pragma unroll
    for (int i=24;i<32;i++) ea[i] = 0;
  }
  __syncthreads();

  f32x4 zero4 = {0.f,0.f,0.f,0.f};
  f32x4 acc[3][4];
  #pragma unroll
  for (int i=0;i<3;i++){ acc[i][0]=zero4; acc[i][1]=zero4; acc[i][2]=zero4; acc[i][3]=zero4; }
  {
    const u16* Wc = W1cP + (size_t)l*32*HID;
    const u16* wb = Wc + ((size_t)(ng*4)*64 + lane)*8;
    bf16x8 b0 = *(const bf16x8*)(wb);
    bf16x8 b1 = *(const bf16x8*)(wb + 512);
    bf16x8 b2 = *(const bf16x8*)(wb + 1024);
    bf16x8 b3 = *(const bf16x8*)(wb + 1536);
    bf16x8 a0 = *(const bf16x8*)(sEA + (0*16+nl)*40 + quad*8);
    bf16x8 a1 = *(const bf16x8*)(sEA + (1*16+nl)*40 + quad*8);
    bf16x8 a2 = *(const bf16x8*)(sEA + (2*16+nl)*40 + quad*8);
    acc[0][0]=__builtin_amdgcn_mfma_f32_16x16x32_bf16(a0,b0,acc[0][0],0,0,0);
    acc[0][1]=__builtin_amdgcn_mfma_f32_16x16x32_bf16(a0,b1,acc[0][1],0,0,0);
    acc[0][2]=__builtin_amdgcn_mfma_f32_16x16x32_bf16(a0,b2,acc[0][2],0,0,0);
    acc[0][3]=__builtin_amdgcn_mfma_f32_16x16x32_bf16(a0,b3,acc[0][3],0,0,0);
    acc[1][0]=__builtin_amdgcn_mfma_f32_16x16x32_bf16(a1,b0,acc[1][0],0,0,0);
    acc[1][1]=__builtin_amdgcn_mfma_f32_16x16x32_bf16(a1,b1,acc[1][1],0,0,0);
    acc[1][2]=__builtin_amdgcn_mfma_f32_16x16x32_bf16(a1,b2,acc[1][2],0,0,0);
    acc[1][3]=__builtin_amdgcn_mfma_f32_16x16x32_bf16(a1,b3,acc[1][3],0,0,0);
    acc[2][0]=__builtin_amdgcn_mfma_f32_16x16x32_bf16(a2,b0,acc[2][0],0,0,0);
    acc[2][1]=__builtin_amdgcn_mfma_f32_16x16x32_bf16(a2,b1,acc[2][1],0,0,0);
    acc[2][2]=__builtin_amdgcn_mfma_f32_16x16x32_bf16(a2,b2,acc[2][2],0,0,0);
    acc[2][3]=__builtin_amdgcn_mfma_f32_16x16x32_bf16(a2,b3,acc[2][3],0,0,0);
  }
  __syncthreads();
  #pragma unroll
  for (int mt=0;mt<3;mt++)
  #pragma unroll
  for (int nt=0;nt<4;nt++){
    int n = ng*64 + nt*16 + nl;
    float bb = B1[l*HID + n] + sR[n];
    #pragma unroll
    for (int r=0;r<4;r++){
      int m = mt*16 + quad*4 + r;
      float v = acc[mt][nt][r] + bb + b2f(sQ[m*264 + n]);
      sM1[m*264 + n] = f2b(silu_f(v));
    }
  }
  __syncthreads();

  f32x4 acc2[3][4];
  #pragma unroll
  for (int i=0;i<3;i++){ acc2[i][0]=zero4; acc2[i][1]=zero4; acc2[i][2]=zero4; acc2[i][3]=zero4; }
  const u16* W2 = W2p + (size_t)l*HID*HID;
  #pragma unroll 2
  for (int k0=0;k0<8;k0++){
    bf16x8 a0 = *(const bf16x8*)(sM1 + (0*16+nl)*264 + k0*32 + quad*8);
    bf16x8 a1 = *(const bf16x8*)(sM1 + (1*16+nl)*264 + k0*32 + quad*8);
    bf16x8 a2 = *(const bf16x8*)(sM1 + (2*16+nl)*264 + k0*32 + quad*8);
    const u16* wb = W2 + ((size_t)(k0*16 + ng*4)*64 + lane)*8;
    bf16x8 b0 = *(const bf16x8*)(wb);
    bf16x8 b1 = *(const bf16x8*)(wb + 512);
    bf16x8 b2 = *(const bf16x8*)(wb + 1024);
    bf16x8 b3 = *(const bf16x8*)(wb + 1536);
    acc2[0][0]=__builtin_amdgcn_mfma_f32_16x16x32_bf16(a0,b0,acc2[0][0],0,0,0);
    acc2[0][1]=__builtin_amdgcn_mfma_f32_16x16x32_bf16(a0,b1,acc2[0][1],0,0,0);
    acc2[0][2]=__builtin_amdgcn_mfma_f32_16x16x32_bf16(a0,b2,acc2[0][2],0,0,0);
    acc2[0][3]=__builtin_amdgcn_mfma_f32_16x16x32_bf16(a0,b3,acc2[0][3],0,0,0);
    acc2[1][0]=__builtin_amdgcn_mfma_f32_16x16x32_bf16(a1,b0,acc2[1][0],0,0,0);
    acc2[1][1]=__builtin_amdgcn_mfma_f32_16x16x32_bf16(a1,b1,acc2[1][1],0,0,0);
    acc2[1][2]=__builtin_amdgcn_mfma_f32_16x16x32_bf16(a1,b2,acc2[1][2],0,0,0);
    acc2[1][3]=__builtin_amdgcn_mfma_f32_16x16x32_bf16(a1,b3,acc2[1][3],0,0,0);
    acc2[2][0]=__builtin_amdgcn_mfma_f32_16x16x32_bf16(a2,b0,acc2[2][0],0,0,0);
    acc2[2][1]=__builtin_amdgcn_mfma_f32_16x16x32_bf16(a2,b1,acc2[2][1],0,0,0);
    acc2[2][2]=__builtin_amdgcn_mfma_f32_16x16x32_bf16(a2,b2,acc2[2][2],0,0,0);
    acc2[2][3]=__builtin_amdgcn_mfma_f32_16x16x32_bf16(a2,b3,acc2[2][3],0,0,0);
  }
  #pragma unroll
  for (int mt=0;mt<3;mt++)
  #pragma unroll
  for (int nt=0;nt<4;nt++){
    int n = ng*64 + nt*16 + nl;
    float bb = B2[l*HID + n];
    #pragma unroll
    for (int r=0;r<4;r++){
      int m = mt*16 + quad*4 + r;
      sM2[m*264 + n] = f2b(silu_f(acc2[mt][nt][r] + bb));
    }
  }
  __syncthreads();
  if (tid < 192){
    int e = tid >> 2, qq = tid & 3;
    float s = 0.f; int nb = qq*64;
    #pragma unroll 4
    for (int n=0;n<64;n++){
      int nn = nb + ((n + e) & 63);
      s += b2f(sM2[e*264 + nn])*cW3[l*HID + nn];
    }
    sDot[e][qq] = s;
  }
  __syncthreads();
  if (tid < 48) sS[tid] = sDot[tid][0]+sDot[tid][1]+sDot[tid][2]+sDot[tid][3];
  __syncthreads();
  if (tid < 3){
    float u = 0.f;
    #pragma unroll 4
    for (int e=0;e<48;e++) u += sCd[e*3+tid]*sS[e];
    float nv = xc[row*3+tid] + u/5.0f;
    xn[row*3+tid] = nv;
    if (doOut) outX[row*3+tid] = nv*posw[0];
  }
}

extern "C" void kernel_launch(void* const* d_in, const int* in_sizes, int n_in,
                              void* d_out, int out_size, void* d_ws, size_t ws_size,
                              hipStream_t stream)
{
  const float* protPos = (const float*)d_in[0];
  const int*   protEle = (const int*)d_in[1];
  const int*   protAA  = (const int*)d_in[2];
  const int*   protBB  = (const int*)d_in[3];
  const float* XtPos   = (const float*)d_in[4];
  const float* XtFeat  = (const float*)d_in[5];
  const int*   tArr    = (const int*)d_in[6];
  const float* WtTime  = (const float*)d_in[7];
  const float* Wele    = (const float*)d_in[8];
  const float* Waa     = (const float*)d_in[9];
  const float* Wbb     = (const float*)d_in[10];
  const float* Win     = (const float*)d_in[11];
  const float* bin     = (const float*)d_in[12];
  const float* Wout    = (const float*)d_in[13];
  const float* bout    = (const float*)d_in[14];
  const float* eW1     = (const float*)d_in[15];
  const float* eB1     = (const float*)d_in[16];
  const float* eW2     = (const float*)d_in[17];
  const float* eB2     = (const float*)d_in[18];
  const float* attW    = (const float*)d_in[19];
  const float* attB    = (const float*)d_in[20];
  const float* nW1     = (const float*)d_in[21];
  const float* nB1     = (const float*)d_in[22];
  const float* nW2     = (const float*)d_in[23];
  const float* nB2     = (const float*)d_in[24];
  const float* cW1     = (const float*)d_in[25];
  const float* cB1     = (const float*)d_in[26];
  const float* cW2     = (const float*)d_in[27];
  const float* cB2     = (const float*)d_in[28];
  const float* cW3     = (const float*)d_in[29];
  const float* posw    = (const float*)d_in[30];

  float* fp = (float*)d_ws;
  float* X0   = fp;               fp += NTOT*3;
  float* X1   = fp;               fp += NTOT*3;
  float* h    = fp;               fp += (size_t)NTOT*HID;
  float* emb0 = fp;               fp += (size_t)ETOT*12;
  float* RC   = fp;               fp += (size_t)N_LIGC*HID;
  float* RE   = fp;               fp += (size_t)N_LIGC*HID;
  int*   col  = (int*)fp;         fp += ETOT;
  u16*   up   = (u16*)fp;
  u16* h_bf   = up;               up += (size_t)NTOT*HID;
  u16* agg_bf = up;               up += (size_t)N_LIGC*HID;
  u16* QbE    = up;               up += (size_t)NTOT*HID;
  u16* QbC    = up;               up += (size_t)NTOT*HID;
  u16* eW1abP = up;               up += (size_t)DEPTHC*512*HID;
  u16* eW1cP  = up;               up += (size_t)DEPTHC*32*HID;
  u16* eW2p   = up;               up += (size_t)DEPTHC*HID*HID;
  u16* nW1p   = up;               up += (size_t)DEPTHC*512*HID;
  u16* nW2p   = up;               up += (size_t)DEPTHC*HID*HID;
  u16* cW1abP = up;               up += (size_t)DEPTHC*512*HID;
  u16* cW1cP  = up;               up += (size_t)DEPTHC*32*HID;
  u16* cW2p   = up;               up += (size_t)DEPTHC*HID*HID;
  u16* WoutP  = up;               up += (size_t)256*32;

  k_packall<<<1484,256,0,stream>>>(eW1,eW2,nW1,nW2,cW1,cW2,Wout,
      eW1abP,eW1cP,eW2p,nW1p,nW2p,cW1abP,cW1cP,cW2p,WoutP);
  k_embed_hinit<<<NTOT/8,256,0,stream>>>(protPos,protEle,protAA,protBB,XtPos,XtFeat,
      tArr,WtTime,Wele,Waa,Wbb,Win,bin,X0,X1,h,h_bf);
  k_knn<<<N_LIGC,256,0,stream>>>(X0,col,emb0);
  k_pq<<<NTOT/32,256,0,stream>>>(h_bf,eW1abP,RE,QbE,0);

  float* xc = X0; float* xn = X1;
  float* outF = (float*)d_out;
  for (int l=0;l<DEPTHC;l++){
    k_comb_edge<<<N_LIGC,256,0,stream>>>(QbE,RE,xc,col,emb0,eW1cP,eB1,eW2p,eB2,attW,attB,agg_bf,l);
    const u16* eNext = eW1abP + (size_t)((l+1)%DEPTHC)*512*HID;
    k_node<<<NTOT/32,256,0,stream>>>(h,h_bf,agg_bf,nW1p,nB1,nW2p,nB2,
        cW1abP,QbC,RC, eNext,QbE,RE,(l<DEPTHC-1)?1:0,
        WoutP,bout, outF+3072, (l==DEPTHC-1)?1:0, l);
    k_comb_coord<<<N_LIGC,256,0,stream>>>(QbC,RC,xc,xn,col,emb0,cW1cP,cB1,cW2p,cB2,cW3,
        posw, outF, (l==DEPTHC-1)?1:0, l);
    float* t2=xc; xc=xn; xn=t2;
  }
}